// Round 5
// baseline (1346.141 us; speedup 1.0000x reference)
//
#include <hip/hip_runtime.h>
#include <math.h>

#define EPS 1e-5f

__device__ inline void wave_red2(float& s1, float& s2){
    for (int off = 32; off; off >>= 1){
        s1 += __shfl_down(s1, off, 64);
        s2 += __shfl_down(s2, off, 64);
    }
}

// ---------------------------------------------------------------------------
// Generic conv1x1 (out[b,j,hw] = sum_c in[b,c,hw]*w[j,c]) with optional
// per-channel (sum, sumsq) stats accumulation.
// ---------------------------------------------------------------------------
__global__ __launch_bounds__(256)
void conv1x1_k(const float* __restrict__ in, const float* __restrict__ w,
               float* __restrict__ out, float* __restrict__ stats,
               int Cin, int Cout, int HW, int B,
               int wStrideZ, int outStrideZ, int statsStrideZ)
{
    const float* wz = w + (size_t)blockIdx.z * wStrideZ;
    float* oz = out + (size_t)blockIdx.z * outStrideZ;
    float* sz = stats ? stats + (size_t)blockIdx.z * statsStrideZ : nullptr;
    int npos = B * HW;
    int total = Cout * npos;
    int item = blockIdx.x * blockDim.x + threadIdx.x;
    if (item >= total) return;
    int j = item / npos;
    int pos = item - j * npos;
    int b = pos / HW, hw = pos - b * HW;
    int ju = __builtin_amdgcn_readfirstlane(j);
    const float* ip = in + (size_t)b * Cin * HW + hw;
    const float* wr = wz + (size_t)ju * Cin;
    float a0 = 0.f, a1 = 0.f, a2 = 0.f, a3 = 0.f;
    int c = 0;
    #pragma unroll 2
    for (; c + 3 < Cin; c += 4){
        a0 += ip[(size_t)c * HW] * wr[c];
        a1 += ip[(size_t)(c + 1) * HW] * wr[c + 1];
        a2 += ip[(size_t)(c + 2) * HW] * wr[c + 2];
        a3 += ip[(size_t)(c + 3) * HW] * wr[c + 3];
    }
    for (; c < Cin; ++c) a0 += ip[(size_t)c * HW] * wr[c];
    float acc = (a0 + a1) + (a2 + a3);
    oz[(size_t)b * Cout * HW + (size_t)j * HW + hw] = acc;
    if (sz){
        float s1 = acc, s2 = acc * acc;
        wave_red2(s1, s2);
        if ((threadIdx.x & 63) == 0){
            atomicAdd(&sz[ju], s1);
            atomicAdd(&sz[Cout + ju], s2);
        }
    }
}

// ---------------------------------------------------------------------------
// Dual conv1x1 for branch-2 (t_loc & t_glb in one launch). HW=9, B=64.
// ---------------------------------------------------------------------------
__global__ __launch_bounds__(256)
void conv_dual(const float* __restrict__ in,
               const float* __restrict__ wA, const float* __restrict__ wB,
               float* __restrict__ outA, float* __restrict__ outB,
               float* __restrict__ stA, float* __restrict__ stB,
               int Cin, int Cout)
{
    const float* w = blockIdx.z ? wB : wA;
    float* out = blockIdx.z ? outB : outA;
    float* st  = blockIdx.z ? stB : stA;
    int total = Cout * 576;
    int item = blockIdx.x * 256 + threadIdx.x;
    if (item >= total) return;
    int j = item / 576, pos = item - j * 576;
    int b = pos / 9, hw = pos - b * 9;
    int ju = __builtin_amdgcn_readfirstlane(j);
    const float* ip = in + (size_t)b * Cin * 9 + hw;
    const float* wr = w + (size_t)ju * Cin;
    float a0 = 0.f, a1 = 0.f, a2 = 0.f, a3 = 0.f;
    int c = 0;
    #pragma unroll 2
    for (; c + 3 < Cin; c += 4){
        a0 += ip[c * 9] * wr[c];
        a1 += ip[(c + 1) * 9] * wr[c + 1];
        a2 += ip[(c + 2) * 9] * wr[c + 2];
        a3 += ip[(c + 3) * 9] * wr[c + 3];
    }
    for (; c < Cin; ++c) a0 += ip[c * 9] * wr[c];
    float acc = (a0 + a1) + (a2 + a3);
    out[(size_t)b * Cout * 9 + j * 9 + hw] = acc;
    float s1 = acc, s2 = acc * acc;
    wave_red2(s1, s2);
    if ((threadIdx.x & 63) == 0){
        atomicAdd(&st[ju], s1);
        atomicAdd(&st[Cout + ju], s2);
    }
}

// ---------------------------------------------------------------------------
// Branch-1 involution, SPLIT. Phase 1: wkgen — for each (b,g,ii) compute the
// dynamic kernel wk[kk][p] = sum_j relu(bn(t))[j][p] * w2[kk][j]. w2 staged
// in LDS (broadcast reads), t from global, pure VALU dot chains in the exact
// ascending-j order of the fused kernel (bit-exact).
// ---------------------------------------------------------------------------
template<int K>
__device__ void wkgen_dev(const float* __restrict__ t_raw,
                          const float* __restrict__ tstats,
                          const float* __restrict__ tg, const float* __restrict__ tb,
                          const float* __restrict__ w2,
                          float* __restrict__ wk,
                          float* lds, int b, int g)
{
    constexpr int KK = K * K;
    float* w2s = lds;             // KK*15 <= 1215
    float* scb = lds + 1215;      // 15
    float* shb = lds + 1230;      // 15
    int tid = threadIdx.x;

    if (tid < 15){
        const float invN = 1.f / 14400.f;
        float mean = tstats[tid] * invN;
        float var  = tstats[15 + tid] * invN - mean * mean;
        float s = tg[tid] * rsqrtf(var + EPS);
        scb[tid] = s; shb[tid] = tb[tid] - mean * s;
    }
    const float* w2g = w2 + (size_t)g * KK * 15;
    for (int i = tid; i < KK * 15; i += 256) w2s[i] = w2g[i];
    __syncthreads();
    if (tid >= 225) return;
    int p = tid;

    float treg[15];
    const float* trb = t_raw + (size_t)b * 3375 + p;
    #pragma unroll
    for (int j = 0; j < 15; ++j){
        float v = trb[j * 225] * scb[j] + shb[j];
        treg[j] = v > 0.f ? v : 0.f;
    }

    float* wkb = wk + ((size_t)(b * 2 + g) * KK) * 225 + p;
    #pragma unroll
    for (int kk0 = 0; kk0 < KK; kk0 += 3){
        const float* wr = w2s + kk0 * 15;
        float a0 = 0.f, a1 = 0.f, a2 = 0.f;
        #pragma unroll
        for (int j = 0; j < 15; ++j){
            float tv = treg[j];
            a0 += tv * wr[j];
            if (kk0 + 1 < KK) a1 += tv * wr[15 + j];
            if (kk0 + 2 < KK) a2 += tv * wr[30 + j];
        }
        wkb[kk0 * 225] = a0;
        if (kk0 + 1 < KK) wkb[(kk0 + 1) * 225] = a1;
        if (kk0 + 2 < KK) wkb[(kk0 + 2) * 225] = a2;
    }
}

__global__ __launch_bounds__(256)
void wkgen_all(const float* __restrict__ t_raw3, const float* __restrict__ tstats3,
               const float* __restrict__ tg3, const float* __restrict__ tb3,
               const float* __restrict__ w2_5, const float* __restrict__ w2_7,
               const float* __restrict__ w2_9, float* __restrict__ wk)
{
    __shared__ float lds[1245];
    int b = blockIdx.x, g = blockIdx.y, ii = blockIdx.z;
    if (ii == 0)
        wkgen_dev<5>(t_raw3,          tstats3,      tg3,      tb3,      w2_5, wk,           lds, b, g);
    else if (ii == 1)
        wkgen_dev<7>(t_raw3 + 216000, tstats3 + 30, tg3 + 15, tb3 + 15, w2_7, wk + 720000, lds, b, g);
    else
        wkgen_dev<9>(t_raw3 + 432000, tstats3 + 60, tg3 + 30, tb3 + 30, w2_9, wk + 2131200, lds, b, g);
}

// ---------------------------------------------------------------------------
// Phase 2: apply — pure gather-FMA. Per ki: batch K independent GLOBAL loads
// of wk (vmcnt counter, no interaction with LDS lgkm), then K taps of
// LDS-read + FMA into 8 register accumulators. Tap order identical to the
// fused kernel (bit-exact). No treg, no weight dots here.
// ---------------------------------------------------------------------------
template<int K>
__device__ void apply_dev(const float* __restrict__ in, const float* __restrict__ wk,
                          float* __restrict__ o_raw, float* __restrict__ ostats,
                          float* lds, int b, int g, int c0, int nch)
{
    constexpr int KK = K * K, P = (K - 1) / 2;
    float* in_s = lds;            // 8*225 linear [cc][225]
    int tid = threadIdx.x;

    const float* inb = in + (size_t)b * 6750 + (size_t)(g * 15 + c0) * 225;
    int stage = nch * 225;
    for (int i = tid; i < stage; i += 256) in_s[i] = inb[i];
    __syncthreads();

    bool act = tid < 225;
    int p = act ? tid : 224;
    int h = p / 15, w = p - h * 15;
    const float* wkb = wk + ((size_t)(b * 2 + g) * KK) * 225 + p;

    float acc[8];
    #pragma unroll
    for (int cc = 0; cc < 8; ++cc) acc[cc] = 0.f;

    for (int ki = 0; ki < K; ++ki){
        int hh = h + ki - P;
        bool hok = (unsigned)hh < 15u;
        float wkr[K];
        #pragma unroll
        for (int kj = 0; kj < K; ++kj)
            wkr[kj] = wkb[(ki * K + kj) * 225];   // K independent global loads
        #pragma unroll
        for (int kj = 0; kj < K; ++kj){
            int ww = w + kj - P;
            bool ok = hok && ((unsigned)ww < 15u);
            float sc2 = ok ? wkr[kj] : 0.f;
            int offr = ok ? hh * 15 + ww : 0;
            #pragma unroll
            for (int cc = 0; cc < 8; ++cc) acc[cc] += sc2 * in_s[cc * 225 + offr];
        }
    }

    float* ob = o_raw + (size_t)b * 6750 + (size_t)(g * 15 + c0) * 225;
    #pragma unroll
    for (int cc = 0; cc < 8; ++cc){
        if (cc < nch){                                // uniform guard; acc idx static
            float val = act ? acc[cc] : 0.f;
            if (act) ob[cc * 225 + p] = val;
            float s1 = val, s2 = val * val;
            wave_red2(s1, s2);
            if ((tid & 63) == 0){
                atomicAdd(&ostats[g * 15 + c0 + cc], s1);
                atomicAdd(&ostats[30 + g * 15 + c0 + cc], s2);
            }
        }
    }
}

__global__ __launch_bounds__(256)
void invol_apply_all(const float* __restrict__ in, const float* __restrict__ wk,
                     float* __restrict__ o_raw3, float* __restrict__ ostats3)
{
    __shared__ float lds[1800];
    int b = blockIdx.x;
    int g = blockIdx.y >> 1;
    int c0 = (blockIdx.y & 1) * 8;
    int nch = c0 ? 7 : 8;
    int ii = blockIdx.z;
    if (ii == 0)
        apply_dev<5>(in, wk,           o_raw3,          ostats3,       lds, b, g, c0, nch);
    else if (ii == 1)
        apply_dev<7>(in, wk + 720000,  o_raw3 + 432000, ostats3 + 60,  lds, b, g, c0, nch);
    else
        apply_dev<9>(in, wk + 2131200, o_raw3 + 864000, ostats3 + 120, lds, b, g, c0, nch);
}

// ---------------------------------------------------------------------------
// Branch-1 block end: out_new = conv1x1(concat(relu(bn(o_ii))), conv) + out_old
// ---------------------------------------------------------------------------
__global__ __launch_bounds__(256)
void blockend(const float* __restrict__ o0, const float* __restrict__ o1,
              const float* __restrict__ o2,
              const float* __restrict__ s0, const float* __restrict__ s1,
              const float* __restrict__ s2,
              const float* __restrict__ g, const float* __restrict__ bb,
              const float* __restrict__ conv,
              const float* __restrict__ oldout, float* __restrict__ newout)
{
    __shared__ float sc[90], sh[90];
    int tid = threadIdx.x;
    if (tid < 90){
        int ii = tid / 30, cc = tid - ii * 30;
        const float* st = ii == 0 ? s0 : (ii == 1 ? s1 : s2);
        const float invN = 1.f / 14400.f;
        float mean = st[cc] * invN;
        float var = st[30 + cc] * invN - mean * mean;
        float s = g[tid] * rsqrtf(var + EPS);
        sc[tid] = s; sh[tid] = bb[tid] - mean * s;
    }
    __syncthreads();
    int item = blockIdx.x * 256 + tid;
    if (item >= 432000) return;
    int c = item / 14400, pos = item - c * 14400;
    int b = pos / 225, hw = pos - b * 225;
    int cu = __builtin_amdgcn_readfirstlane(c);
    float acc = oldout[(size_t)b * 6750 + c * 225 + hw];
    const float* cr = conv + cu * 90;              // scalar loads
    const float* bases[3] = {o0, o1, o2};
    #pragma unroll
    for (int ii = 0; ii < 3; ++ii){
        const float* op = bases[ii] + (size_t)b * 6750 + hw;
        float sA = 0.f, sB = 0.f;
        #pragma unroll 5
        for (int cc = 0; cc < 30; cc += 2){
            float v = op[cc * 225] * sc[ii * 30 + cc] + sh[ii * 30 + cc];
            v = v > 0.f ? v : 0.f;
            sA += v * cr[ii * 30 + cc];
            float v2 = op[(cc + 1) * 225] * sc[ii * 30 + cc + 1] + sh[ii * 30 + cc + 1];
            v2 = v2 > 0.f ? v2 : 0.f;
            sB += v2 * cr[ii * 30 + cc + 1];
        }
        acc += sA + sB;
    }
    newout[(size_t)b * 6750 + c * 225 + hw] = acc;
}

// ---------------------------------------------------------------------------
// Fused cross-attention front: o = y * (loc(y) + glb(y)).
// ---------------------------------------------------------------------------
__global__ __launch_bounds__(256)
void crossatt_fused(const float* __restrict__ y,
                    const float* __restrict__ t_loc, const float* __restrict__ t_glb,
                    const float* __restrict__ s_tloc, const float* __restrict__ s_tglb,
                    const float* __restrict__ lg, const float* __restrict__ lb,
                    const float* __restrict__ gg, const float* __restrict__ gb,
                    const float* __restrict__ loc_w2, const float* __restrict__ glb_w2,
                    float* __restrict__ out)
{
    __shared__ float lsc[102], lsh[102], gsc[102], gsh[102];
    const float invN = 1.f / 576.f;
    for (int j = threadIdx.x; j < 102; j += 256){
        float m1 = s_tloc[j] * invN;
        float v1 = s_tloc[102 + j] * invN - m1 * m1;
        float a1 = lg[j] * rsqrtf(v1 + EPS);
        lsc[j] = a1; lsh[j] = lb[j] - m1 * a1;
        float m2 = s_tglb[j] * invN;
        float v2 = s_tglb[102 + j] * invN - m2 * m2;
        float a2 = gg[j] * rsqrtf(v2 + EPS);
        gsc[j] = a2; gsh[j] = gb[j] - m2 * a2;
    }
    __syncthreads();
    int item = blockIdx.x * 256 + threadIdx.x;
    if (item >= 204 * 576) return;
    int c = item / 576, pos = item - c * 576;
    int b = pos / 9, hw = pos - b * 9;
    int h = hw / 3, w = hw - h * 3;
    int cu = __builtin_amdgcn_readfirstlane(c);

    const float* tl = t_loc + (size_t)b * 918 + hw;
    const float* tg_ = t_glb + (size_t)b * 918 + hw;
    const float* wl = loc_w2 + (size_t)cu * 918;   // wave-uniform -> s_load
    float wk[9];
    #pragma unroll
    for (int kk = 0; kk < 9; ++kk) wk[kk] = 0.f;
    for (int j = 0; j < 102; ++j){
        float a = tl[j * 9] * lsc[j] + lsh[j];
        a = a > 0.f ? a : 0.f;
        float g2 = tg_[j * 9] * gsc[j] + gsh[j];
        g2 = g2 > 0.f ? g2 : 0.f;
        #pragma unroll
        for (int kk = 0; kk < 9; ++kk)
            wk[kk] += a * wl[kk * 102 + j] + g2 * glb_w2[kk * 102 + j];
    }
    const float* pb = y + (size_t)b * 1836 + c * 9;
    float acc = 0.f;
    #pragma unroll
    for (int ki = 0; ki < 3; ++ki){
        int hh = h + ki - 1;
        bool hok = (unsigned)hh < 3u;
        #pragma unroll
        for (int kj = 0; kj < 3; ++kj){
            int ww = w + kj - 1;
            bool ok = hok && ((unsigned)ww < 3u);
            float v = ok ? pb[hh * 3 + ww] : 0.f;
            acc += wk[ki * 3 + kj] * v;
        }
    }
    out[(size_t)b * 1836 + c * 9 + hw] = pb[hw] * acc;
}

// ---------------------------------------------------------------------------
// Fused groups==1 involution (wkgen + apply + stats) for c3/c4/c5.
// ---------------------------------------------------------------------------
__global__ __launch_bounds__(256)
void invol3_fused(const float* __restrict__ pin, const float* __restrict__ t_raw,
                  const float* __restrict__ tstats,
                  const float* __restrict__ tg, const float* __restrict__ tb,
                  const float* __restrict__ w2,
                  float* __restrict__ out, float* __restrict__ ostats,
                  int C, int Ct)
{
    __shared__ float tsc[102], tsh[102];
    const float invN = 1.f / 576.f;
    for (int j = threadIdx.x; j < Ct; j += 256){
        float mean = tstats[j] * invN;
        float var  = tstats[Ct + j] * invN - mean * mean;
        float s = tg[j] * rsqrtf(var + EPS);
        tsc[j] = s; tsh[j] = tb[j] - mean * s;
    }
    __syncthreads();
    int item = blockIdx.x * 256 + threadIdx.x;
    if (item >= C * 576) return;
    int c = item / 576, pos = item - c * 576;
    int b = pos / 9, hw = pos - b * 9;
    int h = hw / 3, w = hw - h * 3;

    const float* tp = t_raw + (size_t)b * Ct * 9 + hw;
    float wk[9];
    #pragma unroll
    for (int kk = 0; kk < 9; ++kk) wk[kk] = 0.f;
    for (int j = 0; j < Ct; ++j){
        float t = tp[j * 9] * tsc[j] + tsh[j];
        t = t > 0.f ? t : 0.f;
        #pragma unroll
        for (int kk = 0; kk < 9; ++kk) wk[kk] += t * w2[kk * Ct + j];
    }
    const float* pb = pin + (size_t)b * C * 9 + c * 9;
    float acc = 0.f;
    #pragma unroll
    for (int ki = 0; ki < 3; ++ki){
        int hh = h + ki - 1;
        bool hok = (unsigned)hh < 3u;
        #pragma unroll
        for (int kj = 0; kj < 3; ++kj){
            int ww = w + kj - 1;
            bool ok = hok && ((unsigned)ww < 3u);
            float v = ok ? pb[hh * 3 + ww] : 0.f;
            acc += wk[ki * 3 + kj] * v;
        }
    }
    out[(size_t)b * C * 9 + c * 9 + hw] = acc;
    float s1 = acc, s2 = acc * acc;
    wave_red2(s1, s2);
    if ((threadIdx.x & 63) == 0){
        int cu = __builtin_amdgcn_readfirstlane(c);
        atomicAdd(&ostats[cu], s1);
        atomicAdd(&ostats[C + cu], s2);
    }
}

// ---------------------------------------------------------------------------
// Fused BN+ReLU(+residual) -> conv1x1. 4 partial accumulators for ILP.
// ---------------------------------------------------------------------------
__global__ __launch_bounds__(256)
void bnconv(const float* __restrict__ in, const float* __restrict__ stats,
            const float* __restrict__ g, const float* __restrict__ bta,
            const float* __restrict__ idn, const float* __restrict__ w,
            float* __restrict__ out, int Cin, int Cout)
{
    __shared__ float sc[204], sh[204];
    for (int j = threadIdx.x; j < Cin; j += 256){
        const float invN = 1.f / 576.f;
        float mean = stats[j] * invN;
        float var = stats[Cin + j] * invN - mean * mean;
        float s = g[j] * rsqrtf(var + EPS);
        sc[j] = s; sh[j] = bta[j] - mean * s;
    }
    __syncthreads();
    int item = blockIdx.x * 256 + threadIdx.x;
    if (item >= Cout * 576) return;
    int j = item / 576, pos = item - j * 576;
    int b = pos / 9, hw = pos - b * 9;
    int ju = __builtin_amdgcn_readfirstlane(j);
    const float* ip = in + (size_t)b * Cin * 9 + hw;
    const float* ir = idn ? idn + (size_t)b * Cin * 9 + hw : nullptr;
    const float* wr = w + (size_t)ju * Cin;
    float a0 = 0.f, a1 = 0.f, a2 = 0.f, a3 = 0.f;
    int c = 0;
    #pragma unroll 2
    for (; c + 3 < Cin; c += 4){
        float v0 = ip[c * 9] * sc[c] + sh[c];             v0 = v0 > 0.f ? v0 : 0.f;
        float v1 = ip[(c + 1) * 9] * sc[c + 1] + sh[c + 1]; v1 = v1 > 0.f ? v1 : 0.f;
        float v2 = ip[(c + 2) * 9] * sc[c + 2] + sh[c + 2]; v2 = v2 > 0.f ? v2 : 0.f;
        float v3 = ip[(c + 3) * 9] * sc[c + 3] + sh[c + 3]; v3 = v3 > 0.f ? v3 : 0.f;
        if (ir){
            v0 += ir[c * 9]; v1 += ir[(c + 1) * 9];
            v2 += ir[(c + 2) * 9]; v3 += ir[(c + 3) * 9];
        }
        a0 += v0 * wr[c];
        a1 += v1 * wr[c + 1];
        a2 += v2 * wr[c + 2];
        a3 += v3 * wr[c + 3];
    }
    for (; c < Cin; ++c){
        float v = ip[c * 9] * sc[c] + sh[c];
        v = v > 0.f ? v : 0.f;
        if (ir) v += ir[c * 9];
        a0 += v * wr[c];
    }
    out[(size_t)b * Cout * 9 + j * 9 + hw] = (a0 + a1) + (a2 + a3);
}

// ---------------------------------------------------------------------------
// GlobalCovPooling: one workgroup per batch element, all in LDS. Faithful to
// the reference incl. ELEMENTWISE Y-update in Newton-Schulz.
// ---------------------------------------------------------------------------
template<int C, int N, int TB>
__global__ __launch_bounds__(TB)
void covpool(const float* __restrict__ in, float* __restrict__ feat)
{
    __shared__ float X[N * C];
    __shared__ float Ybuf[C * C], Mbuf[C * C], Zbuf[C * C], Z2buf[C * C];
    __shared__ float mu[C];
    __shared__ float scal[2];
    int b = blockIdx.x, tid = threadIdx.x;
    const float* ib = in + (size_t)b * C * N;
    for (int i = tid; i < N * C; i += TB){
        int n = i / C, c = i - n * C;
        X[i] = ib[(size_t)c * N + n];
    }
    __syncthreads();
    if (tid < C){
        float s0 = 0.f, s1 = 0.f, s2 = 0.f, s3 = 0.f;
        int n = 0;
        for (; n + 3 < N; n += 4){
            s0 += X[n * C + tid];
            s1 += X[(n + 1) * C + tid];
            s2 += X[(n + 2) * C + tid];
            s3 += X[(n + 3) * C + tid];
        }
        for (; n < N; ++n) s0 += X[n * C + tid];
        mu[tid] = ((s0 + s1) + (s2 + s3)) / (float)N;
    }
    __syncthreads();
    constexpr int CC = C * C;
    for (int i = tid; i < CC; i += TB){
        int c = i / C, d = i - c * C;
        float s0 = 0.f, s1 = 0.f, s2 = 0.f, s3 = 0.f;
        int n = 0;
        for (; n + 3 < N; n += 4){
            s0 += X[n * C + c] * X[n * C + d];
            s1 += X[(n + 1) * C + c] * X[(n + 1) * C + d];
            s2 += X[(n + 2) * C + c] * X[(n + 2) * C + d];
            s3 += X[(n + 3) * C + c] * X[(n + 3) * C + d];
        }
        for (; n < N; ++n) s0 += X[n * C + c] * X[n * C + d];
        Ybuf[i] = ((s0 + s1) + (s2 + s3)) / (float)N - mu[c] * mu[d];
    }
    __syncthreads();
    if (tid == 0){
        float tr = 0.f;
        for (int c = 0; c < C; ++c) tr += Ybuf[c * C + c];
        scal[0] = 1.f / tr;
    }
    __syncthreads();
    for (int i = tid; i < CC; i += TB){
        int c = i / C, d = i - c * C;
        Ybuf[i] *= scal[0];
        Zbuf[i] = (c == d) ? 1.f : 0.f;
    }
    __syncthreads();
    float* zs = Zbuf; float* zd = Z2buf;
    for (int it = 0; it < 6; ++it){
        for (int i = tid; i < CC; i += TB){
            int c = i / C, d = i - c * C;
            float sA = 0.f, sB = 0.f;
            #pragma unroll 3
            for (int e = 0; e < C; e += 2){
                sA += zs[c * C + e] * Ybuf[e * C + d];
                sB += zs[c * C + e + 1] * Ybuf[(e + 1) * C + d];
            }
            Mbuf[i] = ((c == d) ? 3.f : 0.f) - (sA + sB);
        }
        __syncthreads();
        for (int i = tid; i < CC; i += TB){
            int c = i / C, d = i - c * C;
            float sA = 0.f, sB = 0.f;
            #pragma unroll 3
            for (int e = 0; e < C; e += 2){
                sA += Mbuf[c * C + e] * zs[e * C + d];
                sB += Mbuf[c * C + e + 1] * zs[(e + 1) * C + d];
            }
            zd[i] = 0.5f * (sA + sB);
        }
        for (int i = tid; i < CC; i += TB) Ybuf[i] *= 0.5f * Mbuf[i];   // elementwise, as in source
        __syncthreads();
        float* t = zs; zs = zd; zd = t;
    }
    if (tid == 0){
        float tr = 0.f;
        for (int c = 0; c < C; ++c) tr += Ybuf[c * C + c];
        scal[1] = sqrtf(tr);
    }
    __syncthreads();
    if (tid < C){
        float s = 0.f;
        #pragma unroll 6
        for (int c = 0; c < C; ++c) s += Ybuf[c * C + tid];
        feat[(size_t)b * C + tid] = scal[1] * s / (float)C;
    }
}

// ---------------------------------------------------------------------------
// Head: concat feats, BN over batch, ReLU, linear, softmax. Single workgroup.
// ---------------------------------------------------------------------------
__global__ __launch_bounds__(256)
void head_k(const float* __restrict__ feat1, const float* __restrict__ feat2,
            const float* __restrict__ hg, const float* __restrict__ hb,
            const float* __restrict__ lw, const float* __restrict__ lb,
            float* __restrict__ out)
{
    __shared__ float f[46 * 64];
    int tid = threadIdx.x;
    for (int i = tid; i < 46 * 64; i += 256){
        int ch = i / 64, b = i - ch * 64;
        f[i] = ch < 30 ? feat1[b * 30 + ch] : feat2[b * 16 + (ch - 30)];
    }
    __syncthreads();
    if (tid < 46){
        float s = 0.f, s2 = 0.f;
        for (int b = 0; b < 64; ++b){ float v = f[tid * 64 + b]; s += v; s2 += v * v; }
        float mean = s / 64.f, var = s2 / 64.f - mean * mean;
        float sc = hg[tid] * rsqrtf(var + EPS), sh = hb[tid] - mean * sc;
        for (int b = 0; b < 64; ++b){
            float v = f[tid * 64 + b] * sc + sh;
            f[tid * 64 + b] = v > 0.f ? v : 0.f;
        }
    }
    __syncthreads();
    if (tid < 64){
        int b = tid;
        float l[16];
        float m = -1e30f;
        for (int o = 0; o < 16; ++o){
            float a = lb[o];
            for (int ch = 0; ch < 46; ++ch) a += f[ch * 64 + b] * lw[o * 46 + ch];
            l[o] = a; m = fmaxf(m, a);
        }
        float se = 0.f;
        for (int o = 0; o < 16; ++o){ l[o] = expf(l[o] - m); se += l[o]; }
        float inv = 1.f / se;
        for (int o = 0; o < 16; ++o) out[b * 16 + o] = l[o] * inv;
    }
}

extern "C" void kernel_launch(void* const* d_in, const int* in_sizes, int n_in,
                              void* d_out, int out_size, void* d_ws, size_t ws_size,
                              hipStream_t stream)
{
    (void)in_sizes; (void)n_in; (void)out_size; (void)ws_size;
    const float* x        = (const float*)d_in[0];
    const float* y        = (const float*)d_in[1];
    const float* blk_w1   = (const float*)d_in[2];
    const float* blk_ig   = (const float*)d_in[3];
    const float* blk_ib   = (const float*)d_in[4];
    const float* blk_w2_5 = (const float*)d_in[5];
    const float* blk_w2_7 = (const float*)d_in[6];
    const float* blk_w2_9 = (const float*)d_in[7];
    const float* blk_g    = (const float*)d_in[8];
    const float* blk_b    = (const float*)d_in[9];
    const float* blk_conv = (const float*)d_in[10];
    const float* loc_w1 = (const float*)d_in[11];
    const float* loc_g  = (const float*)d_in[12];
    const float* loc_b  = (const float*)d_in[13];
    const float* loc_w2 = (const float*)d_in[14];
    const float* glb_w1 = (const float*)d_in[15];
    const float* glb_g  = (const float*)d_in[16];
    const float* glb_b  = (const float*)d_in[17];
    const float* glb_w2 = (const float*)d_in[18];
    const float* c3_w1 = (const float*)d_in[19];
    const float* c3_g  = (const float*)d_in[20];
    const float* c3_b  = (const float*)d_in[21];
    const float* c3_w2 = (const float*)d_in[22];
    const float* c4_w1 = (const float*)d_in[23];
    const float* c4_g  = (const float*)d_in[24];
    const float* c4_b  = (const float*)d_in[25];
    const float* c4_w2 = (const float*)d_in[26];
    const float* c5_w1 = (const float*)d_in[27];
    const float* c5_g  = (const float*)d_in[28];
    const float* c5_b  = (const float*)d_in[29];
    const float* c5_w2 = (const float*)d_in[30];
    const float* p1 = (const float*)d_in[31];
    const float* p2 = (const float*)d_in[32];
    const float* p3 = (const float*)d_in[33];
    const float* bn1g = (const float*)d_in[34];
    const float* bn1b = (const float*)d_in[35];
    const float* bn2g = (const float*)d_in[36];
    const float* bn2b = (const float*)d_in[37];
    const float* bn3g = (const float*)d_in[38];
    const float* bn3b = (const float*)d_in[39];
    const float* hg = (const float*)d_in[40];
    const float* hb = (const float*)d_in[41];
    const float* lw = (const float*)d_in[42];
    const float* lb = (const float*)d_in[43];

    float* ws = (float*)d_ws;
    size_t off = 0;
    auto alloc = [&](size_t n){ float* p = ws + off; off += n; return p; };
    float* bufA    = alloc(432000);
    float* bufB    = alloc(432000);
    float* scratch = alloc(1944000);   // branch1 t_raw(3)+o_raw(3); branch2 aliases this
    float* feat1   = alloc(64 * 30);
    float* feat2   = alloc(64 * 16);
    float* stats   = alloc(2288);
    float* wkbuf   = alloc(4464000);   // dynamic kernels: 64*2*(25+49+81)*225

    float* t_raw = scratch;            // 3 x 216000
    float* o_raw = scratch + 648000;   // 3 x 432000

    hipMemsetAsync(stats, 0, 2288 * sizeof(float), stream);

    // ---- branch 1: 3 IVoubottleneck blocks ----
    const float* cur = x;
    float* dst = bufA;
    for (int bi = 0; bi < 3; ++bi){
        float* st_t = stats + bi * 90;          // 3 x (15 sum + 15 sumsq)
        float* st_o = stats + 270 + bi * 180;   // 3 x (30 sum + 30 sumsq)
        conv1x1_k<<<dim3(844, 1, 3), 256, 0, stream>>>(
            cur, blk_w1 + bi * 1350, t_raw, st_t, 30, 15, 225, 64, 450, 216000, 30);
        wkgen_all<<<dim3(64, 2, 3), 256, 0, stream>>>(
            t_raw, st_t, blk_ig + bi * 45, blk_ib + bi * 45,
            blk_w2_5 + bi * 750, blk_w2_7 + bi * 1470, blk_w2_9 + bi * 2430, wkbuf);
        invol_apply_all<<<dim3(64, 4, 3), 256, 0, stream>>>(cur, wkbuf, o_raw, st_o);
        blockend<<<1688, 256, 0, stream>>>(o_raw, o_raw + 432000, o_raw + 864000,
                                           st_o, st_o + 60, st_o + 120,
                                           blk_g + bi * 90, blk_b + bi * 90, blk_conv + bi * 2700,
                                           cur, dst);
        cur = dst;
        dst = (bi == 0) ? bufB : bufA;
    }
    covpool<30, 225, 1024><<<64, 1024, 0, stream>>>(cur, feat1);

    // ---- branch 2: cross attention (aliases scratch; branch-1 uses are done) ----
    float* t_loc = scratch;
    float* t_glb = t_loc + 58752;
    float* o_idn = t_glb + 58752;
    float* t3    = o_idn + 117504;
    float* o3    = t3 + 58752;
    float* o5    = o3 + 117504;
    float* t4    = o5 + 58752;
    float* o6    = t4 + 29376;
    float* o8    = o6 + 58752;
    float* t5    = o8 + 29376;
    float* o9    = t5 + 14400;
    float* o11   = o9 + 29376;

    float* s_tloc = stats + 810;
    float* s_tglb = s_tloc + 204;
    float* s_t3   = s_tglb + 204;
    float* s_o3   = s_t3 + 204;
    float* s_t4   = s_o3 + 408;
    float* s_o6   = s_t4 + 102;
    float* s_t5   = s_o6 + 204;
    float* s_o9   = s_t5 + 50;

    conv_dual<<<dim3(230, 1, 2), 256, 0, stream>>>(y, loc_w1, glb_w1, t_loc, t_glb,
                                                   s_tloc, s_tglb, 204, 102);
    crossatt_fused<<<459, 256, 0, stream>>>(y, t_loc, t_glb, s_tloc, s_tglb,
                                            loc_g, loc_b, glb_g, glb_b,
                                            loc_w2, glb_w2, o_idn);
    // c3
    conv1x1_k<<<230, 256, 0, stream>>>(o_idn, c3_w1, t3, s_t3, 204, 102, 9, 64, 0, 0, 0);
    invol3_fused<<<459, 256, 0, stream>>>(o_idn, t3, s_t3, c3_g, c3_b, c3_w2, o3, s_o3, 204, 102);
    bnconv<<<230, 256, 0, stream>>>(o3, s_o3, bn1g, bn1b, o_idn, p1, o5, 204, 102);
    // c4
    conv1x1_k<<<115, 256, 0, stream>>>(o5, c4_w1, t4, s_t4, 102, 51, 9, 64, 0, 0, 0);
    invol3_fused<<<230, 256, 0, stream>>>(o5, t4, s_t4, c4_g, c4_b, c4_w2, o6, s_o6, 102, 51);
    bnconv<<<115, 256, 0, stream>>>(o6, s_o6, bn2g, bn2b, nullptr, p2, o8, 102, 51);
    // c5
    conv1x1_k<<<57, 256, 0, stream>>>(o8, c5_w1, t5, s_t5, 51, 25, 9, 64, 0, 0, 0);
    invol3_fused<<<115, 256, 0, stream>>>(o8, t5, s_t5, c5_g, c5_b, c5_w2, o9, s_o9, 51, 25);
    bnconv<<<36, 256, 0, stream>>>(o9, s_o9, bn3g, bn3b, o8, p3, o11, 51, 16);
    covpool<16, 9, 256><<<64, 256, 0, stream>>>(o11, feat2);

    // ---- head ----
    head_k<<<1, 256, 0, stream>>>(feat1, feat2, hg, hb, lw, lb, (float*)d_out);
}

// Round 6
// 1291.951 us; speedup vs baseline: 1.0419x; 1.0419x over previous
//
#include <hip/hip_runtime.h>
#include <math.h>

#define EPS 1e-5f

__device__ inline void wave_red2(float& s1, float& s2){
    for (int off = 32; off; off >>= 1){
        s1 += __shfl_down(s1, off, 64);
        s2 += __shfl_down(s2, off, 64);
    }
}

// ---------------------------------------------------------------------------
// Generic conv1x1 (out[b,j,hw] = sum_c in[b,c,hw]*w[j,c]) with optional
// per-channel (sum, sumsq) stats accumulation.
// ---------------------------------------------------------------------------
__global__ __launch_bounds__(256)
void conv1x1_k(const float* __restrict__ in, const float* __restrict__ w,
               float* __restrict__ out, float* __restrict__ stats,
               int Cin, int Cout, int HW, int B,
               int wStrideZ, int outStrideZ, int statsStrideZ)
{
    const float* wz = w + (size_t)blockIdx.z * wStrideZ;
    float* oz = out + (size_t)blockIdx.z * outStrideZ;
    float* sz = stats ? stats + (size_t)blockIdx.z * statsStrideZ : nullptr;
    int npos = B * HW;
    int total = Cout * npos;
    int item = blockIdx.x * blockDim.x + threadIdx.x;
    if (item >= total) return;
    int j = item / npos;
    int pos = item - j * npos;
    int b = pos / HW, hw = pos - b * HW;
    int ju = __builtin_amdgcn_readfirstlane(j);
    const float* ip = in + (size_t)b * Cin * HW + hw;
    const float* wr = wz + (size_t)ju * Cin;
    float a0 = 0.f, a1 = 0.f, a2 = 0.f, a3 = 0.f;
    int c = 0;
    #pragma unroll 2
    for (; c + 3 < Cin; c += 4){
        a0 += ip[(size_t)c * HW] * wr[c];
        a1 += ip[(size_t)(c + 1) * HW] * wr[c + 1];
        a2 += ip[(size_t)(c + 2) * HW] * wr[c + 2];
        a3 += ip[(size_t)(c + 3) * HW] * wr[c + 3];
    }
    for (; c < Cin; ++c) a0 += ip[(size_t)c * HW] * wr[c];
    float acc = (a0 + a1) + (a2 + a3);
    oz[(size_t)b * Cout * HW + (size_t)j * HW + hw] = acc;
    if (sz){
        float s1 = acc, s2 = acc * acc;
        wave_red2(s1, s2);
        if ((threadIdx.x & 63) == 0){
            atomicAdd(&sz[ju], s1);
            atomicAdd(&sz[Cout + ju], s2);
        }
    }
}

// ---------------------------------------------------------------------------
// Dual conv1x1 for branch-2 (t_loc & t_glb in one launch). HW=9, B=64.
// ---------------------------------------------------------------------------
__global__ __launch_bounds__(256)
void conv_dual(const float* __restrict__ in,
               const float* __restrict__ wA, const float* __restrict__ wB,
               float* __restrict__ outA, float* __restrict__ outB,
               float* __restrict__ stA, float* __restrict__ stB,
               int Cin, int Cout)
{
    const float* w = blockIdx.z ? wB : wA;
    float* out = blockIdx.z ? outB : outA;
    float* st  = blockIdx.z ? stB : stA;
    int total = Cout * 576;
    int item = blockIdx.x * 256 + threadIdx.x;
    if (item >= total) return;
    int j = item / 576, pos = item - j * 576;
    int b = pos / 9, hw = pos - b * 9;
    int ju = __builtin_amdgcn_readfirstlane(j);
    const float* ip = in + (size_t)b * Cin * 9 + hw;
    const float* wr = w + (size_t)ju * Cin;
    float a0 = 0.f, a1 = 0.f, a2 = 0.f, a3 = 0.f;
    int c = 0;
    #pragma unroll 2
    for (; c + 3 < Cin; c += 4){
        a0 += ip[c * 9] * wr[c];
        a1 += ip[(c + 1) * 9] * wr[c + 1];
        a2 += ip[(c + 2) * 9] * wr[c + 2];
        a3 += ip[(c + 3) * 9] * wr[c + 3];
    }
    for (; c < Cin; ++c) a0 += ip[c * 9] * wr[c];
    float acc = (a0 + a1) + (a2 + a3);
    out[(size_t)b * Cout * 9 + j * 9 + hw] = acc;
    float s1 = acc, s2 = acc * acc;
    wave_red2(s1, s2);
    if ((threadIdx.x & 63) == 0){
        atomicAdd(&st[ju], s1);
        atomicAdd(&st[Cout + ju], s2);
    }
}

// ---------------------------------------------------------------------------
// Branch-1 involution phase 1: wkgen. Non-template, runtime K, rolled chunk
// loop (small code; no I$ blowout; no spill). Stored values bit-identical to
// the previous version (same chunk-of-3 ascending-j summation; stores guarded
// so tail chunks write exactly what they used to).
// ---------------------------------------------------------------------------
__global__ __launch_bounds__(256)
void wkgen_all(const float* __restrict__ t_raw3, const float* __restrict__ tstats3,
               const float* __restrict__ tg3, const float* __restrict__ tb3,
               const float* __restrict__ w2_5, const float* __restrict__ w2_7,
               const float* __restrict__ w2_9, float* __restrict__ wk)
{
    __shared__ float w2s[1215];
    __shared__ float scb[15], shb[15];
    int b = blockIdx.x, g = blockIdx.y, ii = blockIdx.z;
    int K  = ii == 0 ? 5 : (ii == 1 ? 7 : 9);
    int KK = K * K;
    const float* t_raw  = t_raw3  + ii * 216000;
    const float* tstats = tstats3 + ii * 30;
    const float* tg = tg3 + ii * 15;
    const float* tb = tb3 + ii * 15;
    const float* w2 = ii == 0 ? w2_5 : (ii == 1 ? w2_7 : w2_9);
    float* wkb0 = wk + (ii == 0 ? 0 : (ii == 1 ? 720000 : 2131200));

    int tid = threadIdx.x;
    if (tid < 15){
        const float invN = 1.f / 14400.f;
        float mean = tstats[tid] * invN;
        float var  = tstats[15 + tid] * invN - mean * mean;
        float s = tg[tid] * rsqrtf(var + EPS);
        scb[tid] = s; shb[tid] = tb[tid] - mean * s;
    }
    const float* w2g = w2 + (size_t)g * KK * 15;
    for (int i = tid; i < KK * 15; i += 256) w2s[i] = w2g[i];
    __syncthreads();
    if (tid >= 225) return;
    int p = tid;

    float treg[15];
    const float* trb = t_raw + (size_t)b * 3375 + p;
    #pragma unroll
    for (int j = 0; j < 15; ++j){
        float v = trb[j * 225] * scb[j] + shb[j];
        treg[j] = v > 0.f ? v : 0.f;
    }

    float* wkb = wkb0 + (size_t)(b * 2 + g) * KK * 225 + p;
    #pragma unroll 1
    for (int kk0 = 0; kk0 < KK; kk0 += 3){
        const float* wr = w2s + kk0 * 15;
        float a0 = 0.f, a1 = 0.f, a2 = 0.f;
        #pragma unroll
        for (int j = 0; j < 15; ++j){
            float tv = treg[j];
            a0 += tv * wr[j];
            a1 += tv * wr[15 + j];       // may read uninit LDS on tail chunk;
            a2 += tv * wr[30 + j];       // result discarded by guarded stores
        }
        wkb[kk0 * 225] = a0;
        if (kk0 + 1 < KK) wkb[(kk0 + 1) * 225] = a1;
        if (kk0 + 2 < KK) wkb[(kk0 + 2) * 225] = a2;
    }
}

// ---------------------------------------------------------------------------
// Phase 2: apply. Non-template, runtime K, rolled loops with depth-1 register
// prefetch of the next wk value (load latency hides under the 4 FMAs/tap).
// 4-way channel split (4/4/4/3) doubles grid -> 6 blocks/CU -> 75% occupancy
// ceiling. Tap order identical to all previous versions (bit-exact per
// channel). Live state ~40 VGPRs: no spill.
// ---------------------------------------------------------------------------
__global__ __launch_bounds__(256)
void invol_apply_all(const float* __restrict__ in, const float* __restrict__ wk,
                     float* __restrict__ o_raw3, float* __restrict__ ostats3)
{
    __shared__ float in_s[900];
    int b = blockIdx.x;
    int g = blockIdx.y >> 2;
    int c0 = (blockIdx.y & 3) * 4;
    int nch = (c0 == 12) ? 3 : 4;
    int ii = blockIdx.z;
    int K  = ii == 0 ? 5 : (ii == 1 ? 7 : 9);
    int KK = K * K;
    int P  = (K - 1) >> 1;
    const float* wkb0 = wk + (ii == 0 ? 0 : (ii == 1 ? 720000 : 2131200));
    float* o_raw  = o_raw3  + ii * 432000;
    float* ostats = ostats3 + ii * 60;

    int tid = threadIdx.x;
    const float* inb = in + (size_t)b * 6750 + (size_t)(g * 15 + c0) * 225;
    int stage = nch * 225;
    for (int i = tid; i < stage; i += 256) in_s[i] = inb[i];
    for (int i = stage + tid; i < 900; i += 256) in_s[i] = 0.f;
    __syncthreads();

    bool act = tid < 225;
    int p = act ? tid : 224;
    int h = p / 15, w = p - h * 15;
    const float* wkb = wkb0 + (size_t)(b * 2 + g) * KK * 225 + p;

    float acc0 = 0.f, acc1 = 0.f, acc2 = 0.f, acc3 = 0.f;
    #pragma unroll 1
    for (int ki = 0; ki < K; ++ki){
        int hh = h + ki - P;
        bool hok = (unsigned)hh < 15u;
        const float* wrow = wkb + ki * K * 225;
        float wkv_n = wrow[0];
        #pragma unroll 1
        for (int kj = 0; kj < K; ++kj){
            float wkv = wkv_n;
            if (kj + 1 < K) wkv_n = wrow[(kj + 1) * 225];   // prefetch next tap
            int ww = w + kj - P;
            bool ok = hok && ((unsigned)ww < 15u);
            float sc2 = ok ? wkv : 0.f;
            int offr = ok ? hh * 15 + ww : 0;
            acc0 += sc2 * in_s[offr];
            acc1 += sc2 * in_s[225 + offr];
            acc2 += sc2 * in_s[450 + offr];
            acc3 += sc2 * in_s[675 + offr];
        }
    }

    float* ob = o_raw + (size_t)b * 6750 + (size_t)(g * 15 + c0) * 225;
    float vals[4] = {acc0, acc1, acc2, acc3};
    #pragma unroll
    for (int cc = 0; cc < 4; ++cc){
        if (cc < nch){                                // uniform guard; static idx
            float val = act ? vals[cc] : 0.f;
            if (act) ob[cc * 225 + p] = val;
            float s1 = val, s2 = val * val;
            wave_red2(s1, s2);
            if ((tid & 63) == 0){
                atomicAdd(&ostats[g * 15 + c0 + cc], s1);
                atomicAdd(&ostats[30 + g * 15 + c0 + cc], s2);
            }
        }
    }
}

// ---------------------------------------------------------------------------
// Branch-1 block end: out_new = conv1x1(concat(relu(bn(o_ii))), conv) + out_old
// ---------------------------------------------------------------------------
__global__ __launch_bounds__(256)
void blockend(const float* __restrict__ o0, const float* __restrict__ o1,
              const float* __restrict__ o2,
              const float* __restrict__ s0, const float* __restrict__ s1,
              const float* __restrict__ s2,
              const float* __restrict__ g, const float* __restrict__ bb,
              const float* __restrict__ conv,
              const float* __restrict__ oldout, float* __restrict__ newout)
{
    __shared__ float sc[90], sh[90];
    int tid = threadIdx.x;
    if (tid < 90){
        int ii = tid / 30, cc = tid - ii * 30;
        const float* st = ii == 0 ? s0 : (ii == 1 ? s1 : s2);
        const float invN = 1.f / 14400.f;
        float mean = st[cc] * invN;
        float var = st[30 + cc] * invN - mean * mean;
        float s = g[tid] * rsqrtf(var + EPS);
        sc[tid] = s; sh[tid] = bb[tid] - mean * s;
    }
    __syncthreads();
    int item = blockIdx.x * 256 + tid;
    if (item >= 432000) return;
    int c = item / 14400, pos = item - c * 14400;
    int b = pos / 225, hw = pos - b * 225;
    int cu = __builtin_amdgcn_readfirstlane(c);
    float acc = oldout[(size_t)b * 6750 + c * 225 + hw];
    const float* cr = conv + cu * 90;              // scalar loads
    const float* bases[3] = {o0, o1, o2};
    #pragma unroll
    for (int ii = 0; ii < 3; ++ii){
        const float* op = bases[ii] + (size_t)b * 6750 + hw;
        float sA = 0.f, sB = 0.f;
        #pragma unroll 5
        for (int cc = 0; cc < 30; cc += 2){
            float v = op[cc * 225] * sc[ii * 30 + cc] + sh[ii * 30 + cc];
            v = v > 0.f ? v : 0.f;
            sA += v * cr[ii * 30 + cc];
            float v2 = op[(cc + 1) * 225] * sc[ii * 30 + cc + 1] + sh[ii * 30 + cc + 1];
            v2 = v2 > 0.f ? v2 : 0.f;
            sB += v2 * cr[ii * 30 + cc + 1];
        }
        acc += sA + sB;
    }
    newout[(size_t)b * 6750 + c * 225 + hw] = acc;
}

// ---------------------------------------------------------------------------
// Fused cross-attention front: o = y * (loc(y) + glb(y)).
// ---------------------------------------------------------------------------
__global__ __launch_bounds__(256)
void crossatt_fused(const float* __restrict__ y,
                    const float* __restrict__ t_loc, const float* __restrict__ t_glb,
                    const float* __restrict__ s_tloc, const float* __restrict__ s_tglb,
                    const float* __restrict__ lg, const float* __restrict__ lb,
                    const float* __restrict__ gg, const float* __restrict__ gb,
                    const float* __restrict__ loc_w2, const float* __restrict__ glb_w2,
                    float* __restrict__ out)
{
    __shared__ float lsc[102], lsh[102], gsc[102], gsh[102];
    const float invN = 1.f / 576.f;
    for (int j = threadIdx.x; j < 102; j += 256){
        float m1 = s_tloc[j] * invN;
        float v1 = s_tloc[102 + j] * invN - m1 * m1;
        float a1 = lg[j] * rsqrtf(v1 + EPS);
        lsc[j] = a1; lsh[j] = lb[j] - m1 * a1;
        float m2 = s_tglb[j] * invN;
        float v2 = s_tglb[102 + j] * invN - m2 * m2;
        float a2 = gg[j] * rsqrtf(v2 + EPS);
        gsc[j] = a2; gsh[j] = gb[j] - m2 * a2;
    }
    __syncthreads();
    int item = blockIdx.x * 256 + threadIdx.x;
    if (item >= 204 * 576) return;
    int c = item / 576, pos = item - c * 576;
    int b = pos / 9, hw = pos - b * 9;
    int h = hw / 3, w = hw - h * 3;
    int cu = __builtin_amdgcn_readfirstlane(c);

    const float* tl = t_loc + (size_t)b * 918 + hw;
    const float* tg_ = t_glb + (size_t)b * 918 + hw;
    const float* wl = loc_w2 + (size_t)cu * 918;   // wave-uniform -> s_load
    float wk[9];
    #pragma unroll
    for (int kk = 0; kk < 9; ++kk) wk[kk] = 0.f;
    for (int j = 0; j < 102; ++j){
        float a = tl[j * 9] * lsc[j] + lsh[j];
        a = a > 0.f ? a : 0.f;
        float g2 = tg_[j * 9] * gsc[j] + gsh[j];
        g2 = g2 > 0.f ? g2 : 0.f;
        #pragma unroll
        for (int kk = 0; kk < 9; ++kk)
            wk[kk] += a * wl[kk * 102 + j] + g2 * glb_w2[kk * 102 + j];
    }
    const float* pb = y + (size_t)b * 1836 + c * 9;
    float acc = 0.f;
    #pragma unroll
    for (int ki = 0; ki < 3; ++ki){
        int hh = h + ki - 1;
        bool hok = (unsigned)hh < 3u;
        #pragma unroll
        for (int kj = 0; kj < 3; ++kj){
            int ww = w + kj - 1;
            bool ok = hok && ((unsigned)ww < 3u);
            float v = ok ? pb[hh * 3 + ww] : 0.f;
            acc += wk[ki * 3 + kj] * v;
        }
    }
    out[(size_t)b * 1836 + c * 9 + hw] = pb[hw] * acc;
}

// ---------------------------------------------------------------------------
// Fused groups==1 involution (wkgen + apply + stats) for c3/c4/c5.
// ---------------------------------------------------------------------------
__global__ __launch_bounds__(256)
void invol3_fused(const float* __restrict__ pin, const float* __restrict__ t_raw,
                  const float* __restrict__ tstats,
                  const float* __restrict__ tg, const float* __restrict__ tb,
                  const float* __restrict__ w2,
                  float* __restrict__ out, float* __restrict__ ostats,
                  int C, int Ct)
{
    __shared__ float tsc[102], tsh[102];
    const float invN = 1.f / 576.f;
    for (int j = threadIdx.x; j < Ct; j += 256){
        float mean = tstats[j] * invN;
        float var  = tstats[Ct + j] * invN - mean * mean;
        float s = tg[j] * rsqrtf(var + EPS);
        tsc[j] = s; tsh[j] = tb[j] - mean * s;
    }
    __syncthreads();
    int item = blockIdx.x * 256 + threadIdx.x;
    if (item >= C * 576) return;
    int c = item / 576, pos = item - c * 576;
    int b = pos / 9, hw = pos - b * 9;
    int h = hw / 3, w = hw - h * 3;

    const float* tp = t_raw + (size_t)b * Ct * 9 + hw;
    float wk[9];
    #pragma unroll
    for (int kk = 0; kk < 9; ++kk) wk[kk] = 0.f;
    for (int j = 0; j < Ct; ++j){
        float t = tp[j * 9] * tsc[j] + tsh[j];
        t = t > 0.f ? t : 0.f;
        #pragma unroll
        for (int kk = 0; kk < 9; ++kk) wk[kk] += t * w2[kk * Ct + j];
    }
    const float* pb = pin + (size_t)b * C * 9 + c * 9;
    float acc = 0.f;
    #pragma unroll
    for (int ki = 0; ki < 3; ++ki){
        int hh = h + ki - 1;
        bool hok = (unsigned)hh < 3u;
        #pragma unroll
        for (int kj = 0; kj < 3; ++kj){
            int ww = w + kj - 1;
            bool ok = hok && ((unsigned)ww < 3u);
            float v = ok ? pb[hh * 3 + ww] : 0.f;
            acc += wk[ki * 3 + kj] * v;
        }
    }
    out[(size_t)b * C * 9 + c * 9 + hw] = acc;
    float s1 = acc, s2 = acc * acc;
    wave_red2(s1, s2);
    if ((threadIdx.x & 63) == 0){
        int cu = __builtin_amdgcn_readfirstlane(c);
        atomicAdd(&ostats[cu], s1);
        atomicAdd(&ostats[C + cu], s2);
    }
}

// ---------------------------------------------------------------------------
// Fused BN+ReLU(+residual) -> conv1x1. 4 partial accumulators for ILP.
// ---------------------------------------------------------------------------
__global__ __launch_bounds__(256)
void bnconv(const float* __restrict__ in, const float* __restrict__ stats,
            const float* __restrict__ g, const float* __restrict__ bta,
            const float* __restrict__ idn, const float* __restrict__ w,
            float* __restrict__ out, int Cin, int Cout)
{
    __shared__ float sc[204], sh[204];
    for (int j = threadIdx.x; j < Cin; j += 256){
        const float invN = 1.f / 576.f;
        float mean = stats[j] * invN;
        float var = stats[Cin + j] * invN - mean * mean;
        float s = g[j] * rsqrtf(var + EPS);
        sc[j] = s; sh[j] = bta[j] - mean * s;
    }
    __syncthreads();
    int item = blockIdx.x * 256 + threadIdx.x;
    if (item >= Cout * 576) return;
    int j = item / 576, pos = item - j * 576;
    int b = pos / 9, hw = pos - b * 9;
    int ju = __builtin_amdgcn_readfirstlane(j);
    const float* ip = in + (size_t)b * Cin * 9 + hw;
    const float* ir = idn ? idn + (size_t)b * Cin * 9 + hw : nullptr;
    const float* wr = w + (size_t)ju * Cin;
    float a0 = 0.f, a1 = 0.f, a2 = 0.f, a3 = 0.f;
    int c = 0;
    #pragma unroll 2
    for (; c + 3 < Cin; c += 4){
        float v0 = ip[c * 9] * sc[c] + sh[c];             v0 = v0 > 0.f ? v0 : 0.f;
        float v1 = ip[(c + 1) * 9] * sc[c + 1] + sh[c + 1]; v1 = v1 > 0.f ? v1 : 0.f;
        float v2 = ip[(c + 2) * 9] * sc[c + 2] + sh[c + 2]; v2 = v2 > 0.f ? v2 : 0.f;
        float v3 = ip[(c + 3) * 9] * sc[c + 3] + sh[c + 3]; v3 = v3 > 0.f ? v3 : 0.f;
        if (ir){
            v0 += ir[c * 9]; v1 += ir[(c + 1) * 9];
            v2 += ir[(c + 2) * 9]; v3 += ir[(c + 3) * 9];
        }
        a0 += v0 * wr[c];
        a1 += v1 * wr[c + 1];
        a2 += v2 * wr[c + 2];
        a3 += v3 * wr[c + 3];
    }
    for (; c < Cin; ++c){
        float v = ip[c * 9] * sc[c] + sh[c];
        v = v > 0.f ? v : 0.f;
        if (ir) v += ir[c * 9];
        a0 += v * wr[c];
    }
    out[(size_t)b * Cout * 9 + j * 9 + hw] = (a0 + a1) + (a2 + a3);
}

// ---------------------------------------------------------------------------
// GlobalCovPooling: one workgroup per batch element, all in LDS. Faithful to
// the reference incl. ELEMENTWISE Y-update in Newton-Schulz.
// ---------------------------------------------------------------------------
template<int C, int N, int TB>
__global__ __launch_bounds__(TB)
void covpool(const float* __restrict__ in, float* __restrict__ feat)
{
    __shared__ float X[N * C];
    __shared__ float Ybuf[C * C], Mbuf[C * C], Zbuf[C * C], Z2buf[C * C];
    __shared__ float mu[C];
    __shared__ float scal[2];
    int b = blockIdx.x, tid = threadIdx.x;
    const float* ib = in + (size_t)b * C * N;
    for (int i = tid; i < N * C; i += TB){
        int n = i / C, c = i - n * C;
        X[i] = ib[(size_t)c * N + n];
    }
    __syncthreads();
    if (tid < C){
        float s0 = 0.f, s1 = 0.f, s2 = 0.f, s3 = 0.f;
        int n = 0;
        for (; n + 3 < N; n += 4){
            s0 += X[n * C + tid];
            s1 += X[(n + 1) * C + tid];
            s2 += X[(n + 2) * C + tid];
            s3 += X[(n + 3) * C + tid];
        }
        for (; n < N; ++n) s0 += X[n * C + tid];
        mu[tid] = ((s0 + s1) + (s2 + s3)) / (float)N;
    }
    __syncthreads();
    constexpr int CC = C * C;
    for (int i = tid; i < CC; i += TB){
        int c = i / C, d = i - c * C;
        float s0 = 0.f, s1 = 0.f, s2 = 0.f, s3 = 0.f;
        int n = 0;
        for (; n + 3 < N; n += 4){
            s0 += X[n * C + c] * X[n * C + d];
            s1 += X[(n + 1) * C + c] * X[(n + 1) * C + d];
            s2 += X[(n + 2) * C + c] * X[(n + 2) * C + d];
            s3 += X[(n + 3) * C + c] * X[(n + 3) * C + d];
        }
        for (; n < N; ++n) s0 += X[n * C + c] * X[n * C + d];
        Ybuf[i] = ((s0 + s1) + (s2 + s3)) / (float)N - mu[c] * mu[d];
    }
    __syncthreads();
    if (tid == 0){
        float tr = 0.f;
        for (int c = 0; c < C; ++c) tr += Ybuf[c * C + c];
        scal[0] = 1.f / tr;
    }
    __syncthreads();
    for (int i = tid; i < CC; i += TB){
        int c = i / C, d = i - c * C;
        Ybuf[i] *= scal[0];
        Zbuf[i] = (c == d) ? 1.f : 0.f;
    }
    __syncthreads();
    float* zs = Zbuf; float* zd = Z2buf;
    for (int it = 0; it < 6; ++it){
        for (int i = tid; i < CC; i += TB){
            int c = i / C, d = i - c * C;
            float sA = 0.f, sB = 0.f;
            #pragma unroll 3
            for (int e = 0; e < C; e += 2){
                sA += zs[c * C + e] * Ybuf[e * C + d];
                sB += zs[c * C + e + 1] * Ybuf[(e + 1) * C + d];
            }
            Mbuf[i] = ((c == d) ? 3.f : 0.f) - (sA + sB);
        }
        __syncthreads();
        for (int i = tid; i < CC; i += TB){
            int c = i / C, d = i - c * C;
            float sA = 0.f, sB = 0.f;
            #pragma unroll 3
            for (int e = 0; e < C; e += 2){
                sA += Mbuf[c * C + e] * zs[e * C + d];
                sB += Mbuf[c * C + e + 1] * zs[(e + 1) * C + d];
            }
            zd[i] = 0.5f * (sA + sB);
        }
        for (int i = tid; i < CC; i += TB) Ybuf[i] *= 0.5f * Mbuf[i];   // elementwise, as in source
        __syncthreads();
        float* t = zs; zs = zd; zd = t;
    }
    if (tid == 0){
        float tr = 0.f;
        for (int c = 0; c < C; ++c) tr += Ybuf[c * C + c];
        scal[1] = sqrtf(tr);
    }
    __syncthreads();
    if (tid < C){
        float s = 0.f;
        #pragma unroll 6
        for (int c = 0; c < C; ++c) s += Ybuf[c * C + tid];
        feat[(size_t)b * C + tid] = scal[1] * s / (float)C;
    }
}

// ---------------------------------------------------------------------------
// Head: concat feats, BN over batch, ReLU, linear, softmax. Single workgroup.
// ---------------------------------------------------------------------------
__global__ __launch_bounds__(256)
void head_k(const float* __restrict__ feat1, const float* __restrict__ feat2,
            const float* __restrict__ hg, const float* __restrict__ hb,
            const float* __restrict__ lw, const float* __restrict__ lb,
            float* __restrict__ out)
{
    __shared__ float f[46 * 64];
    int tid = threadIdx.x;
    for (int i = tid; i < 46 * 64; i += 256){
        int ch = i / 64, b = i - ch * 64;
        f[i] = ch < 30 ? feat1[b * 30 + ch] : feat2[b * 16 + (ch - 30)];
    }
    __syncthreads();
    if (tid < 46){
        float s = 0.f, s2 = 0.f;
        for (int b = 0; b < 64; ++b){ float v = f[tid * 64 + b]; s += v; s2 += v * v; }
        float mean = s / 64.f, var = s2 / 64.f - mean * mean;
        float sc = hg[tid] * rsqrtf(var + EPS), sh = hb[tid] - mean * sc;
        for (int b = 0; b < 64; ++b){
            float v = f[tid * 64 + b] * sc + sh;
            f[tid * 64 + b] = v > 0.f ? v : 0.f;
        }
    }
    __syncthreads();
    if (tid < 64){
        int b = tid;
        float l[16];
        float m = -1e30f;
        for (int o = 0; o < 16; ++o){
            float a = lb[o];
            for (int ch = 0; ch < 46; ++ch) a += f[ch * 64 + b] * lw[o * 46 + ch];
            l[o] = a; m = fmaxf(m, a);
        }
        float se = 0.f;
        for (int o = 0; o < 16; ++o){ l[o] = expf(l[o] - m); se += l[o]; }
        float inv = 1.f / se;
        for (int o = 0; o < 16; ++o) out[b * 16 + o] = l[o] * inv;
    }
}

extern "C" void kernel_launch(void* const* d_in, const int* in_sizes, int n_in,
                              void* d_out, int out_size, void* d_ws, size_t ws_size,
                              hipStream_t stream)
{
    (void)in_sizes; (void)n_in; (void)out_size; (void)ws_size;
    const float* x        = (const float*)d_in[0];
    const float* y        = (const float*)d_in[1];
    const float* blk_w1   = (const float*)d_in[2];
    const float* blk_ig   = (const float*)d_in[3];
    const float* blk_ib   = (const float*)d_in[4];
    const float* blk_w2_5 = (const float*)d_in[5];
    const float* blk_w2_7 = (const float*)d_in[6];
    const float* blk_w2_9 = (const float*)d_in[7];
    const float* blk_g    = (const float*)d_in[8];
    const float* blk_b    = (const float*)d_in[9];
    const float* blk_conv = (const float*)d_in[10];
    const float* loc_w1 = (const float*)d_in[11];
    const float* loc_g  = (const float*)d_in[12];
    const float* loc_b  = (const float*)d_in[13];
    const float* loc_w2 = (const float*)d_in[14];
    const float* glb_w1 = (const float*)d_in[15];
    const float* glb_g  = (const float*)d_in[16];
    const float* glb_b  = (const float*)d_in[17];
    const float* glb_w2 = (const float*)d_in[18];
    const float* c3_w1 = (const float*)d_in[19];
    const float* c3_g  = (const float*)d_in[20];
    const float* c3_b  = (const float*)d_in[21];
    const float* c3_w2 = (const float*)d_in[22];
    const float* c4_w1 = (const float*)d_in[23];
    const float* c4_g  = (const float*)d_in[24];
    const float* c4_b  = (const float*)d_in[25];
    const float* c4_w2 = (const float*)d_in[26];
    const float* c5_w1 = (const float*)d_in[27];
    const float* c5_g  = (const float*)d_in[28];
    const float* c5_b  = (const float*)d_in[29];
    const float* c5_w2 = (const float*)d_in[30];
    const float* p1 = (const float*)d_in[31];
    const float* p2 = (const float*)d_in[32];
    const float* p3 = (const float*)d_in[33];
    const float* bn1g = (const float*)d_in[34];
    const float* bn1b = (const float*)d_in[35];
    const float* bn2g = (const float*)d_in[36];
    const float* bn2b = (const float*)d_in[37];
    const float* bn3g = (const float*)d_in[38];
    const float* bn3b = (const float*)d_in[39];
    const float* hg = (const float*)d_in[40];
    const float* hb = (const float*)d_in[41];
    const float* lw = (const float*)d_in[42];
    const float* lb = (const float*)d_in[43];

    float* ws = (float*)d_ws;
    size_t off = 0;
    auto alloc = [&](size_t n){ float* p = ws + off; off += n; return p; };
    float* bufA    = alloc(432000);
    float* bufB    = alloc(432000);
    float* scratch = alloc(1944000);   // branch1 t_raw(3)+o_raw(3); branch2 aliases this
    float* feat1   = alloc(64 * 30);
    float* feat2   = alloc(64 * 16);
    float* stats   = alloc(2288);
    float* wkbuf   = alloc(4464000);   // dynamic kernels: 64*2*(25+49+81)*225

    float* t_raw = scratch;            // 3 x 216000
    float* o_raw = scratch + 648000;   // 3 x 432000

    hipMemsetAsync(stats, 0, 2288 * sizeof(float), stream);

    // ---- branch 1: 3 IVoubottleneck blocks ----
    const float* cur = x;
    float* dst = bufA;
    for (int bi = 0; bi < 3; ++bi){
        float* st_t = stats + bi * 90;          // 3 x (15 sum + 15 sumsq)
        float* st_o = stats + 270 + bi * 180;   // 3 x (30 sum + 30 sumsq)
        conv1x1_k<<<dim3(844, 1, 3), 256, 0, stream>>>(
            cur, blk_w1 + bi * 1350, t_raw, st_t, 30, 15, 225, 64, 450, 216000, 30);
        wkgen_all<<<dim3(64, 2, 3), 256, 0, stream>>>(
            t_raw, st_t, blk_ig + bi * 45, blk_ib + bi * 45,
            blk_w2_5 + bi * 750, blk_w2_7 + bi * 1470, blk_w2_9 + bi * 2430, wkbuf);
        invol_apply_all<<<dim3(64, 8, 3), 256, 0, stream>>>(cur, wkbuf, o_raw, st_o);
        blockend<<<1688, 256, 0, stream>>>(o_raw, o_raw + 432000, o_raw + 864000,
                                           st_o, st_o + 60, st_o + 120,
                                           blk_g + bi * 90, blk_b + bi * 90, blk_conv + bi * 2700,
                                           cur, dst);
        cur = dst;
        dst = (bi == 0) ? bufB : bufA;
    }
    covpool<30, 225, 1024><<<64, 1024, 0, stream>>>(cur, feat1);

    // ---- branch 2: cross attention (aliases scratch; branch-1 uses are done) ----
    float* t_loc = scratch;
    float* t_glb = t_loc + 58752;
    float* o_idn = t_glb + 58752;
    float* t3    = o_idn + 117504;
    float* o3    = t3 + 58752;
    float* o5    = o3 + 117504;
    float* t4    = o5 + 58752;
    float* o6    = t4 + 29376;
    float* o8    = o6 + 58752;
    float* t5    = o8 + 29376;
    float* o9    = t5 + 14400;
    float* o11   = o9 + 29376;

    float* s_tloc = stats + 810;
    float* s_tglb = s_tloc + 204;
    float* s_t3   = s_tglb + 204;
    float* s_o3   = s_t3 + 204;
    float* s_t4   = s_o3 + 408;
    float* s_o6   = s_t4 + 102;
    float* s_t5   = s_o6 + 204;
    float* s_o9   = s_t5 + 50;

    conv_dual<<<dim3(230, 1, 2), 256, 0, stream>>>(y, loc_w1, glb_w1, t_loc, t_glb,
                                                   s_tloc, s_tglb, 204, 102);
    crossatt_fused<<<459, 256, 0, stream>>>(y, t_loc, t_glb, s_tloc, s_tglb,
                                            loc_g, loc_b, glb_g, glb_b,
                                            loc_w2, glb_w2, o_idn);
    // c3
    conv1x1_k<<<230, 256, 0, stream>>>(o_idn, c3_w1, t3, s_t3, 204, 102, 9, 64, 0, 0, 0);
    invol3_fused<<<459, 256, 0, stream>>>(o_idn, t3, s_t3, c3_g, c3_b, c3_w2, o3, s_o3, 204, 102);
    bnconv<<<230, 256, 0, stream>>>(o3, s_o3, bn1g, bn1b, o_idn, p1, o5, 204, 102);
    // c4
    conv1x1_k<<<115, 256, 0, stream>>>(o5, c4_w1, t4, s_t4, 102, 51, 9, 64, 0, 0, 0);
    invol3_fused<<<230, 256, 0, stream>>>(o5, t4, s_t4, c4_g, c4_b, c4_w2, o6, s_o6, 102, 51);
    bnconv<<<115, 256, 0, stream>>>(o6, s_o6, bn2g, bn2b, nullptr, p2, o8, 102, 51);
    // c5
    conv1x1_k<<<57, 256, 0, stream>>>(o8, c5_w1, t5, s_t5, 51, 25, 9, 64, 0, 0, 0);
    invol3_fused<<<115, 256, 0, stream>>>(o8, t5, s_t5, c5_g, c5_b, c5_w2, o9, s_o9, 51, 25);
    bnconv<<<36, 256, 0, stream>>>(o9, s_o9, bn3g, bn3b, o8, p3, o11, 51, 16);
    covpool<16, 9, 256><<<64, 256, 0, stream>>>(o11, feat2);

    // ---- head ----
    head_k<<<1, 256, 0, stream>>>(feat1, feat2, hg, hb, lw, lb, (float*)d_out);
}

// Round 7
// 1228.065 us; speedup vs baseline: 1.0961x; 1.0520x over previous
//
#include <hip/hip_runtime.h>
#include <math.h>

#define EPS 1e-5f

__device__ inline void wave_red2(float& s1, float& s2){
    for (int off = 32; off; off >>= 1){
        s1 += __shfl_down(s1, off, 64);
        s2 += __shfl_down(s2, off, 64);
    }
}

// ---------------------------------------------------------------------------
// Generic conv1x1 (out[b,j,hw] = sum_c in[b,c,hw]*w[j,c]) with optional
// per-channel (sum, sumsq) stats accumulation.
// ---------------------------------------------------------------------------
__global__ __launch_bounds__(256)
void conv1x1_k(const float* __restrict__ in, const float* __restrict__ w,
               float* __restrict__ out, float* __restrict__ stats,
               int Cin, int Cout, int HW, int B,
               int wStrideZ, int outStrideZ, int statsStrideZ)
{
    const float* wz = w + (size_t)blockIdx.z * wStrideZ;
    float* oz = out + (size_t)blockIdx.z * outStrideZ;
    float* sz = stats ? stats + (size_t)blockIdx.z * statsStrideZ : nullptr;
    int npos = B * HW;
    int total = Cout * npos;
    int item = blockIdx.x * blockDim.x + threadIdx.x;
    if (item >= total) return;
    int j = item / npos;
    int pos = item - j * npos;
    int b = pos / HW, hw = pos - b * HW;
    int ju = __builtin_amdgcn_readfirstlane(j);
    const float* ip = in + (size_t)b * Cin * HW + hw;
    const float* wr = wz + (size_t)ju * Cin;
    float a0 = 0.f, a1 = 0.f, a2 = 0.f, a3 = 0.f;
    int c = 0;
    #pragma unroll 2
    for (; c + 3 < Cin; c += 4){
        a0 += ip[(size_t)c * HW] * wr[c];
        a1 += ip[(size_t)(c + 1) * HW] * wr[c + 1];
        a2 += ip[(size_t)(c + 2) * HW] * wr[c + 2];
        a3 += ip[(size_t)(c + 3) * HW] * wr[c + 3];
    }
    for (; c < Cin; ++c) a0 += ip[(size_t)c * HW] * wr[c];
    float acc = (a0 + a1) + (a2 + a3);
    oz[(size_t)b * Cout * HW + (size_t)j * HW + hw] = acc;
    if (sz){
        float s1 = acc, s2 = acc * acc;
        wave_red2(s1, s2);
        if ((threadIdx.x & 63) == 0){
            atomicAdd(&sz[ju], s1);
            atomicAdd(&sz[Cout + ju], s2);
        }
    }
}

// ---------------------------------------------------------------------------
// Dual conv1x1 for branch-2 (t_loc & t_glb in one launch). HW=9, B=64.
// ---------------------------------------------------------------------------
__global__ __launch_bounds__(256)
void conv_dual(const float* __restrict__ in,
               const float* __restrict__ wA, const float* __restrict__ wB,
               float* __restrict__ outA, float* __restrict__ outB,
               float* __restrict__ stA, float* __restrict__ stB,
               int Cin, int Cout)
{
    const float* w = blockIdx.z ? wB : wA;
    float* out = blockIdx.z ? outB : outA;
    float* st  = blockIdx.z ? stB : stA;
    int total = Cout * 576;
    int item = blockIdx.x * 256 + threadIdx.x;
    if (item >= total) return;
    int j = item / 576, pos = item - j * 576;
    int b = pos / 9, hw = pos - b * 9;
    int ju = __builtin_amdgcn_readfirstlane(j);
    const float* ip = in + (size_t)b * Cin * 9 + hw;
    const float* wr = w + (size_t)ju * Cin;
    float a0 = 0.f, a1 = 0.f, a2 = 0.f, a3 = 0.f;
    int c = 0;
    #pragma unroll 2
    for (; c + 3 < Cin; c += 4){
        a0 += ip[c * 9] * wr[c];
        a1 += ip[(c + 1) * 9] * wr[c + 1];
        a2 += ip[(c + 2) * 9] * wr[c + 2];
        a3 += ip[(c + 3) * 9] * wr[c + 3];
    }
    for (; c < Cin; ++c) a0 += ip[c * 9] * wr[c];
    float acc = (a0 + a1) + (a2 + a3);
    out[(size_t)b * Cout * 9 + j * 9 + hw] = acc;
    float s1 = acc, s2 = acc * acc;
    wave_red2(s1, s2);
    if ((threadIdx.x & 63) == 0){
        atomicAdd(&st[ju], s1);
        atomicAdd(&st[Cout + ju], s2);
    }
}

// ---------------------------------------------------------------------------
// Branch-1 involution phase 1: wkgen (unchanged from round 6).
// ---------------------------------------------------------------------------
__global__ __launch_bounds__(256)
void wkgen_all(const float* __restrict__ t_raw3, const float* __restrict__ tstats3,
               const float* __restrict__ tg3, const float* __restrict__ tb3,
               const float* __restrict__ w2_5, const float* __restrict__ w2_7,
               const float* __restrict__ w2_9, float* __restrict__ wk)
{
    __shared__ float w2s[1215];
    __shared__ float scb[15], shb[15];
    int b = blockIdx.x, g = blockIdx.y, ii = blockIdx.z;
    int K  = ii == 0 ? 5 : (ii == 1 ? 7 : 9);
    int KK = K * K;
    const float* t_raw  = t_raw3  + ii * 216000;
    const float* tstats = tstats3 + ii * 30;
    const float* tg = tg3 + ii * 15;
    const float* tb = tb3 + ii * 15;
    const float* w2 = ii == 0 ? w2_5 : (ii == 1 ? w2_7 : w2_9);
    float* wkb0 = wk + (ii == 0 ? 0 : (ii == 1 ? 720000 : 2131200));

    int tid = threadIdx.x;
    if (tid < 15){
        const float invN = 1.f / 14400.f;
        float mean = tstats[tid] * invN;
        float var  = tstats[15 + tid] * invN - mean * mean;
        float s = tg[tid] * rsqrtf(var + EPS);
        scb[tid] = s; shb[tid] = tb[tid] - mean * s;
    }
    const float* w2g = w2 + (size_t)g * KK * 15;
    for (int i = tid; i < KK * 15; i += 256) w2s[i] = w2g[i];
    __syncthreads();
    if (tid >= 225) return;
    int p = tid;

    float treg[15];
    const float* trb = t_raw + (size_t)b * 3375 + p;
    #pragma unroll
    for (int j = 0; j < 15; ++j){
        float v = trb[j * 225] * scb[j] + shb[j];
        treg[j] = v > 0.f ? v : 0.f;
    }

    float* wkb = wkb0 + (size_t)(b * 2 + g) * KK * 225 + p;
    #pragma unroll 1
    for (int kk0 = 0; kk0 < KK; kk0 += 3){
        const float* wr = w2s + kk0 * 15;
        float a0 = 0.f, a1 = 0.f, a2 = 0.f;
        #pragma unroll
        for (int j = 0; j < 15; ++j){
            float tv = treg[j];
            a0 += tv * wr[j];
            a1 += tv * wr[15 + j];       // may read uninit LDS on tail chunk;
            a2 += tv * wr[30 + j];       // result discarded by guarded stores
        }
        wkb[kk0 * 225] = a0;
        if (kk0 + 1 < KK) wkb[(kk0 + 1) * 225] = a1;
        if (kk0 + 2 < KK) wkb[(kk0 + 2) * 225] = a2;
    }
}

// ---------------------------------------------------------------------------
// Phase 2: apply. Round-7 change: per ki ROW, issue all K wk loads into
// wkr[K] (static indices -> registers, K independent loads in flight, ONE
// waitcnt per row) instead of the rolled depth-1 chain (81 serial load
// rounds for K=9 -> 9). Only the row-level loops are unrolled; ki stays
// rolled so live state ~40 VGPR (no round-5 spill). Tap order per channel
// unchanged -> bit-exact.
// ---------------------------------------------------------------------------
template<int K>
__device__ __forceinline__
void apply_devK(const float* __restrict__ in, const float* __restrict__ wkb0,
                float* __restrict__ o_raw, float* __restrict__ ostats,
                float* in_s, int b, int g, int c0, int nch)
{
    constexpr int KK = K * K, P = (K - 1) / 2;
    int tid = threadIdx.x;
    const float* inb = in + (size_t)b * 6750 + (size_t)(g * 15 + c0) * 225;
    int stage = nch * 225;
    for (int i = tid; i < stage; i += 256) in_s[i] = inb[i];
    for (int i = stage + tid; i < 900; i += 256) in_s[i] = 0.f;
    __syncthreads();

    bool act = tid < 225;
    int p = act ? tid : 224;
    int h = p / 15, w = p - h * 15;
    const float* wkb = wkb0 + (size_t)(b * 2 + g) * KK * 225 + p;

    float acc0 = 0.f, acc1 = 0.f, acc2 = 0.f, acc3 = 0.f;
    #pragma unroll 1
    for (int ki = 0; ki < K; ++ki){
        int hh = h + ki - P;
        bool hok = (unsigned)hh < 15u;
        const float* wrow = wkb + ki * K * 225;
        float wkr[K];
        #pragma unroll
        for (int kj = 0; kj < K; ++kj)
            wkr[kj] = wrow[kj * 225];          // K independent loads in flight
        #pragma unroll
        for (int kj = 0; kj < K; ++kj){
            int ww = w + kj - P;
            bool ok = hok && ((unsigned)ww < 15u);
            float sc2 = ok ? wkr[kj] : 0.f;
            int offr = ok ? hh * 15 + ww : 0;
            acc0 += sc2 * in_s[offr];
            acc1 += sc2 * in_s[225 + offr];
            acc2 += sc2 * in_s[450 + offr];
            acc3 += sc2 * in_s[675 + offr];
        }
    }

    float* ob = o_raw + (size_t)b * 6750 + (size_t)(g * 15 + c0) * 225;
    float vals[4] = {acc0, acc1, acc2, acc3};
    #pragma unroll
    for (int cc = 0; cc < 4; ++cc){
        if (cc < nch){                                // uniform guard; static idx
            float val = act ? vals[cc] : 0.f;
            if (act) ob[cc * 225 + p] = val;
            float s1 = val, s2 = val * val;
            wave_red2(s1, s2);
            if ((tid & 63) == 0){
                atomicAdd(&ostats[g * 15 + c0 + cc], s1);
                atomicAdd(&ostats[30 + g * 15 + c0 + cc], s2);
            }
        }
    }
}

__global__ __launch_bounds__(256)
void invol_apply_all(const float* __restrict__ in, const float* __restrict__ wk,
                     float* __restrict__ o_raw3, float* __restrict__ ostats3)
{
    __shared__ float in_s[900];
    int b = blockIdx.x;
    int g = blockIdx.y >> 2;
    int c0 = (blockIdx.y & 3) * 4;
    int nch = (c0 == 12) ? 3 : 4;
    int ii = blockIdx.z;
    if (ii == 0)
        apply_devK<5>(in, wk,           o_raw3,          ostats3,       in_s, b, g, c0, nch);
    else if (ii == 1)
        apply_devK<7>(in, wk + 720000,  o_raw3 + 432000, ostats3 + 60,  in_s, b, g, c0, nch);
    else
        apply_devK<9>(in, wk + 2131200, o_raw3 + 864000, ostats3 + 120, in_s, b, g, c0, nch);
}

// ---------------------------------------------------------------------------
// Branch-1 block end: out_new = conv1x1(concat(relu(bn(o_ii))), conv) + out_old
// ---------------------------------------------------------------------------
__global__ __launch_bounds__(256)
void blockend(const float* __restrict__ o0, const float* __restrict__ o1,
              const float* __restrict__ o2,
              const float* __restrict__ s0, const float* __restrict__ s1,
              const float* __restrict__ s2,
              const float* __restrict__ g, const float* __restrict__ bb,
              const float* __restrict__ conv,
              const float* __restrict__ oldout, float* __restrict__ newout)
{
    __shared__ float sc[90], sh[90];
    int tid = threadIdx.x;
    if (tid < 90){
        int ii = tid / 30, cc = tid - ii * 30;
        const float* st = ii == 0 ? s0 : (ii == 1 ? s1 : s2);
        const float invN = 1.f / 14400.f;
        float mean = st[cc] * invN;
        float var = st[30 + cc] * invN - mean * mean;
        float s = g[tid] * rsqrtf(var + EPS);
        sc[tid] = s; sh[tid] = bb[tid] - mean * s;
    }
    __syncthreads();
    int item = blockIdx.x * 256 + tid;
    if (item >= 432000) return;
    int c = item / 14400, pos = item - c * 14400;
    int b = pos / 225, hw = pos - b * 225;
    int cu = __builtin_amdgcn_readfirstlane(c);
    float acc = oldout[(size_t)b * 6750 + c * 225 + hw];
    const float* cr = conv + cu * 90;              // scalar loads
    const float* bases[3] = {o0, o1, o2};
    #pragma unroll
    for (int ii = 0; ii < 3; ++ii){
        const float* op = bases[ii] + (size_t)b * 6750 + hw;
        float sA = 0.f, sB = 0.f;
        #pragma unroll 5
        for (int cc = 0; cc < 30; cc += 2){
            float v = op[cc * 225] * sc[ii * 30 + cc] + sh[ii * 30 + cc];
            v = v > 0.f ? v : 0.f;
            sA += v * cr[ii * 30 + cc];
            float v2 = op[(cc + 1) * 225] * sc[ii * 30 + cc + 1] + sh[ii * 30 + cc + 1];
            v2 = v2 > 0.f ? v2 : 0.f;
            sB += v2 * cr[ii * 30 + cc + 1];
        }
        acc += sA + sB;
    }
    newout[(size_t)b * 6750 + c * 225 + hw] = acc;
}

// ---------------------------------------------------------------------------
// Fused cross-attention front: o = y * (loc(y) + glb(y)).
// ---------------------------------------------------------------------------
__global__ __launch_bounds__(256)
void crossatt_fused(const float* __restrict__ y,
                    const float* __restrict__ t_loc, const float* __restrict__ t_glb,
                    const float* __restrict__ s_tloc, const float* __restrict__ s_tglb,
                    const float* __restrict__ lg, const float* __restrict__ lb,
                    const float* __restrict__ gg, const float* __restrict__ gb,
                    const float* __restrict__ loc_w2, const float* __restrict__ glb_w2,
                    float* __restrict__ out)
{
    __shared__ float lsc[102], lsh[102], gsc[102], gsh[102];
    const float invN = 1.f / 576.f;
    for (int j = threadIdx.x; j < 102; j += 256){
        float m1 = s_tloc[j] * invN;
        float v1 = s_tloc[102 + j] * invN - m1 * m1;
        float a1 = lg[j] * rsqrtf(v1 + EPS);
        lsc[j] = a1; lsh[j] = lb[j] - m1 * a1;
        float m2 = s_tglb[j] * invN;
        float v2 = s_tglb[102 + j] * invN - m2 * m2;
        float a2 = gg[j] * rsqrtf(v2 + EPS);
        gsc[j] = a2; gsh[j] = gb[j] - m2 * a2;
    }
    __syncthreads();
    int item = blockIdx.x * 256 + threadIdx.x;
    if (item >= 204 * 576) return;
    int c = item / 576, pos = item - c * 576;
    int b = pos / 9, hw = pos - b * 9;
    int h = hw / 3, w = hw - h * 3;
    int cu = __builtin_amdgcn_readfirstlane(c);

    const float* tl = t_loc + (size_t)b * 918 + hw;
    const float* tg_ = t_glb + (size_t)b * 918 + hw;
    const float* wl = loc_w2 + (size_t)cu * 918;   // wave-uniform -> s_load
    float wk[9];
    #pragma unroll
    for (int kk = 0; kk < 9; ++kk) wk[kk] = 0.f;
    for (int j = 0; j < 102; ++j){
        float a = tl[j * 9] * lsc[j] + lsh[j];
        a = a > 0.f ? a : 0.f;
        float g2 = tg_[j * 9] * gsc[j] + gsh[j];
        g2 = g2 > 0.f ? g2 : 0.f;
        #pragma unroll
        for (int kk = 0; kk < 9; ++kk)
            wk[kk] += a * wl[kk * 102 + j] + g2 * glb_w2[kk * 102 + j];
    }
    const float* pb = y + (size_t)b * 1836 + c * 9;
    float acc = 0.f;
    #pragma unroll
    for (int ki = 0; ki < 3; ++ki){
        int hh = h + ki - 1;
        bool hok = (unsigned)hh < 3u;
        #pragma unroll
        for (int kj = 0; kj < 3; ++kj){
            int ww = w + kj - 1;
            bool ok = hok && ((unsigned)ww < 3u);
            float v = ok ? pb[hh * 3 + ww] : 0.f;
            acc += wk[ki * 3 + kj] * v;
        }
    }
    out[(size_t)b * 1836 + c * 9 + hw] = pb[hw] * acc;
}

// ---------------------------------------------------------------------------
// Fused groups==1 involution (wkgen + apply + stats) for c3/c4/c5.
// ---------------------------------------------------------------------------
__global__ __launch_bounds__(256)
void invol3_fused(const float* __restrict__ pin, const float* __restrict__ t_raw,
                  const float* __restrict__ tstats,
                  const float* __restrict__ tg, const float* __restrict__ tb,
                  const float* __restrict__ w2,
                  float* __restrict__ out, float* __restrict__ ostats,
                  int C, int Ct)
{
    __shared__ float tsc[102], tsh[102];
    const float invN = 1.f / 576.f;
    for (int j = threadIdx.x; j < Ct; j += 256){
        float mean = tstats[j] * invN;
        float var  = tstats[Ct + j] * invN - mean * mean;
        float s = tg[j] * rsqrtf(var + EPS);
        tsc[j] = s; tsh[j] = tb[j] - mean * s;
    }
    __syncthreads();
    int item = blockIdx.x * 256 + threadIdx.x;
    if (item >= C * 576) return;
    int c = item / 576, pos = item - c * 576;
    int b = pos / 9, hw = pos - b * 9;
    int h = hw / 3, w = hw - h * 3;

    const float* tp = t_raw + (size_t)b * Ct * 9 + hw;
    float wk[9];
    #pragma unroll
    for (int kk = 0; kk < 9; ++kk) wk[kk] = 0.f;
    for (int j = 0; j < Ct; ++j){
        float t = tp[j * 9] * tsc[j] + tsh[j];
        t = t > 0.f ? t : 0.f;
        #pragma unroll
        for (int kk = 0; kk < 9; ++kk) wk[kk] += t * w2[kk * Ct + j];
    }
    const float* pb = pin + (size_t)b * C * 9 + c * 9;
    float acc = 0.f;
    #pragma unroll
    for (int ki = 0; ki < 3; ++ki){
        int hh = h + ki - 1;
        bool hok = (unsigned)hh < 3u;
        #pragma unroll
        for (int kj = 0; kj < 3; ++kj){
            int ww = w + kj - 1;
            bool ok = hok && ((unsigned)ww < 3u);
            float v = ok ? pb[hh * 3 + ww] : 0.f;
            acc += wk[ki * 3 + kj] * v;
        }
    }
    out[(size_t)b * C * 9 + c * 9 + hw] = acc;
    float s1 = acc, s2 = acc * acc;
    wave_red2(s1, s2);
    if ((threadIdx.x & 63) == 0){
        int cu = __builtin_amdgcn_readfirstlane(c);
        atomicAdd(&ostats[cu], s1);
        atomicAdd(&ostats[C + cu], s2);
    }
}

// ---------------------------------------------------------------------------
// Fused BN+ReLU(+residual) -> conv1x1. 4 partial accumulators for ILP.
// ---------------------------------------------------------------------------
__global__ __launch_bounds__(256)
void bnconv(const float* __restrict__ in, const float* __restrict__ stats,
            const float* __restrict__ g, const float* __restrict__ bta,
            const float* __restrict__ idn, const float* __restrict__ w,
            float* __restrict__ out, int Cin, int Cout)
{
    __shared__ float sc[204], sh[204];
    for (int j = threadIdx.x; j < Cin; j += 256){
        const float invN = 1.f / 576.f;
        float mean = stats[j] * invN;
        float var = stats[Cin + j] * invN - mean * mean;
        float s = g[j] * rsqrtf(var + EPS);
        sc[j] = s; sh[j] = bta[j] - mean * s;
    }
    __syncthreads();
    int item = blockIdx.x * 256 + threadIdx.x;
    if (item >= Cout * 576) return;
    int j = item / 576, pos = item - j * 576;
    int b = pos / 9, hw = pos - b * 9;
    int ju = __builtin_amdgcn_readfirstlane(j);
    const float* ip = in + (size_t)b * Cin * 9 + hw;
    const float* ir = idn ? idn + (size_t)b * Cin * 9 + hw : nullptr;
    const float* wr = w + (size_t)ju * Cin;
    float a0 = 0.f, a1 = 0.f, a2 = 0.f, a3 = 0.f;
    int c = 0;
    #pragma unroll 2
    for (; c + 3 < Cin; c += 4){
        float v0 = ip[c * 9] * sc[c] + sh[c];             v0 = v0 > 0.f ? v0 : 0.f;
        float v1 = ip[(c + 1) * 9] * sc[c + 1] + sh[c + 1]; v1 = v1 > 0.f ? v1 : 0.f;
        float v2 = ip[(c + 2) * 9] * sc[c + 2] + sh[c + 2]; v2 = v2 > 0.f ? v2 : 0.f;
        float v3 = ip[(c + 3) * 9] * sc[c + 3] + sh[c + 3]; v3 = v3 > 0.f ? v3 : 0.f;
        if (ir){
            v0 += ir[c * 9]; v1 += ir[(c + 1) * 9];
            v2 += ir[(c + 2) * 9]; v3 += ir[(c + 3) * 9];
        }
        a0 += v0 * wr[c];
        a1 += v1 * wr[c + 1];
        a2 += v2 * wr[c + 2];
        a3 += v3 * wr[c + 3];
    }
    for (; c < Cin; ++c){
        float v = ip[c * 9] * sc[c] + sh[c];
        v = v > 0.f ? v : 0.f;
        if (ir) v += ir[c * 9];
        a0 += v * wr[c];
    }
    out[(size_t)b * Cout * 9 + j * 9 + hw] = (a0 + a1) + (a2 + a3);
}

// ---------------------------------------------------------------------------
// GlobalCovPooling: one workgroup per batch element, all in LDS. Faithful to
// the reference incl. ELEMENTWISE Y-update in Newton-Schulz.
// ---------------------------------------------------------------------------
template<int C, int N, int TB>
__global__ __launch_bounds__(TB)
void covpool(const float* __restrict__ in, float* __restrict__ feat)
{
    __shared__ float X[N * C];
    __shared__ float Ybuf[C * C], Mbuf[C * C], Zbuf[C * C], Z2buf[C * C];
    __shared__ float mu[C];
    __shared__ float scal[2];
    int b = blockIdx.x, tid = threadIdx.x;
    const float* ib = in + (size_t)b * C * N;
    for (int i = tid; i < N * C; i += TB){
        int n = i / C, c = i - n * C;
        X[i] = ib[(size_t)c * N + n];
    }
    __syncthreads();
    if (tid < C){
        float s0 = 0.f, s1 = 0.f, s2 = 0.f, s3 = 0.f;
        int n = 0;
        for (; n + 3 < N; n += 4){
            s0 += X[n * C + tid];
            s1 += X[(n + 1) * C + tid];
            s2 += X[(n + 2) * C + tid];
            s3 += X[(n + 3) * C + tid];
        }
        for (; n < N; ++n) s0 += X[n * C + tid];
        mu[tid] = ((s0 + s1) + (s2 + s3)) / (float)N;
    }
    __syncthreads();
    constexpr int CC = C * C;
    for (int i = tid; i < CC; i += TB){
        int c = i / C, d = i - c * C;
        float s0 = 0.f, s1 = 0.f, s2 = 0.f, s3 = 0.f;
        int n = 0;
        for (; n + 3 < N; n += 4){
            s0 += X[n * C + c] * X[n * C + d];
            s1 += X[(n + 1) * C + c] * X[(n + 1) * C + d];
            s2 += X[(n + 2) * C + c] * X[(n + 2) * C + d];
            s3 += X[(n + 3) * C + c] * X[(n + 3) * C + d];
        }
        for (; n < N; ++n) s0 += X[n * C + c] * X[n * C + d];
        Ybuf[i] = ((s0 + s1) + (s2 + s3)) / (float)N - mu[c] * mu[d];
    }
    __syncthreads();
    if (tid == 0){
        float tr = 0.f;
        for (int c = 0; c < C; ++c) tr += Ybuf[c * C + c];
        scal[0] = 1.f / tr;
    }
    __syncthreads();
    for (int i = tid; i < CC; i += TB){
        int c = i / C, d = i - c * C;
        Ybuf[i] *= scal[0];
        Zbuf[i] = (c == d) ? 1.f : 0.f;
    }
    __syncthreads();
    float* zs = Zbuf; float* zd = Z2buf;
    for (int it = 0; it < 6; ++it){
        for (int i = tid; i < CC; i += TB){
            int c = i / C, d = i - c * C;
            float sA = 0.f, sB = 0.f;
            #pragma unroll 3
            for (int e = 0; e < C; e += 2){
                sA += zs[c * C + e] * Ybuf[e * C + d];
                sB += zs[c * C + e + 1] * Ybuf[(e + 1) * C + d];
            }
            Mbuf[i] = ((c == d) ? 3.f : 0.f) - (sA + sB);
        }
        __syncthreads();
        for (int i = tid; i < CC; i += TB){
            int c = i / C, d = i - c * C;
            float sA = 0.f, sB = 0.f;
            #pragma unroll 3
            for (int e = 0; e < C; e += 2){
                sA += Mbuf[c * C + e] * zs[e * C + d];
                sB += Mbuf[c * C + e + 1] * zs[(e + 1) * C + d];
            }
            zd[i] = 0.5f * (sA + sB);
        }
        for (int i = tid; i < CC; i += TB) Ybuf[i] *= 0.5f * Mbuf[i];   // elementwise, as in source
        __syncthreads();
        float* t = zs; zs = zd; zd = t;
    }
    if (tid == 0){
        float tr = 0.f;
        for (int c = 0; c < C; ++c) tr += Ybuf[c * C + c];
        scal[1] = sqrtf(tr);
    }
    __syncthreads();
    if (tid < C){
        float s = 0.f;
        #pragma unroll 6
        for (int c = 0; c < C; ++c) s += Ybuf[c * C + tid];
        feat[(size_t)b * C + tid] = scal[1] * s / (float)C;
    }
}

// ---------------------------------------------------------------------------
// Head: concat feats, BN over batch, ReLU, linear, softmax. Single workgroup.
// ---------------------------------------------------------------------------
__global__ __launch_bounds__(256)
void head_k(const float* __restrict__ feat1, const float* __restrict__ feat2,
            const float* __restrict__ hg, const float* __restrict__ hb,
            const float* __restrict__ lw, const float* __restrict__ lb,
            float* __restrict__ out)
{
    __shared__ float f[46 * 64];
    int tid = threadIdx.x;
    for (int i = tid; i < 46 * 64; i += 256){
        int ch = i / 64, b = i - ch * 64;
        f[i] = ch < 30 ? feat1[b * 30 + ch] : feat2[b * 16 + (ch - 30)];
    }
    __syncthreads();
    if (tid < 46){
        float s = 0.f, s2 = 0.f;
        for (int b = 0; b < 64; ++b){ float v = f[tid * 64 + b]; s += v; s2 += v * v; }
        float mean = s / 64.f, var = s2 / 64.f - mean * mean;
        float sc = hg[tid] * rsqrtf(var + EPS), sh = hb[tid] - mean * sc;
        for (int b = 0; b < 64; ++b){
            float v = f[tid * 64 + b] * sc + sh;
            f[tid * 64 + b] = v > 0.f ? v : 0.f;
        }
    }
    __syncthreads();
    if (tid < 64){
        int b = tid;
        float l[16];
        float m = -1e30f;
        for (int o = 0; o < 16; ++o){
            float a = lb[o];
            for (int ch = 0; ch < 46; ++ch) a += f[ch * 64 + b] * lw[o * 46 + ch];
            l[o] = a; m = fmaxf(m, a);
        }
        float se = 0.f;
        for (int o = 0; o < 16; ++o){ l[o] = expf(l[o] - m); se += l[o]; }
        float inv = 1.f / se;
        for (int o = 0; o < 16; ++o) out[b * 16 + o] = l[o] * inv;
    }
}

extern "C" void kernel_launch(void* const* d_in, const int* in_sizes, int n_in,
                              void* d_out, int out_size, void* d_ws, size_t ws_size,
                              hipStream_t stream)
{
    (void)in_sizes; (void)n_in; (void)out_size; (void)ws_size;
    const float* x        = (const float*)d_in[0];
    const float* y        = (const float*)d_in[1];
    const float* blk_w1   = (const float*)d_in[2];
    const float* blk_ig   = (const float*)d_in[3];
    const float* blk_ib   = (const float*)d_in[4];
    const float* blk_w2_5 = (const float*)d_in[5];
    const float* blk_w2_7 = (const float*)d_in[6];
    const float* blk_w2_9 = (const float*)d_in[7];
    const float* blk_g    = (const float*)d_in[8];
    const float* blk_b    = (const float*)d_in[9];
    const float* blk_conv = (const float*)d_in[10];
    const float* loc_w1 = (const float*)d_in[11];
    const float* loc_g  = (const float*)d_in[12];
    const float* loc_b  = (const float*)d_in[13];
    const float* loc_w2 = (const float*)d_in[14];
    const float* glb_w1 = (const float*)d_in[15];
    const float* glb_g  = (const float*)d_in[16];
    const float* glb_b  = (const float*)d_in[17];
    const float* glb_w2 = (const float*)d_in[18];
    const float* c3_w1 = (const float*)d_in[19];
    const float* c3_g  = (const float*)d_in[20];
    const float* c3_b  = (const float*)d_in[21];
    const float* c3_w2 = (const float*)d_in[22];
    const float* c4_w1 = (const float*)d_in[23];
    const float* c4_g  = (const float*)d_in[24];
    const float* c4_b  = (const float*)d_in[25];
    const float* c4_w2 = (const float*)d_in[26];
    const float* c5_w1 = (const float*)d_in[27];
    const float* c5_g  = (const float*)d_in[28];
    const float* c5_b  = (const float*)d_in[29];
    const float* c5_w2 = (const float*)d_in[30];
    const float* p1 = (const float*)d_in[31];
    const float* p2 = (const float*)d_in[32];
    const float* p3 = (const float*)d_in[33];
    const float* bn1g = (const float*)d_in[34];
    const float* bn1b = (const float*)d_in[35];
    const float* bn2g = (const float*)d_in[36];
    const float* bn2b = (const float*)d_in[37];
    const float* bn3g = (const float*)d_in[38];
    const float* bn3b = (const float*)d_in[39];
    const float* hg = (const float*)d_in[40];
    const float* hb = (const float*)d_in[41];
    const float* lw = (const float*)d_in[42];
    const float* lb = (const float*)d_in[43];

    float* ws = (float*)d_ws;
    size_t off = 0;
    auto alloc = [&](size_t n){ float* p = ws + off; off += n; return p; };
    float* bufA    = alloc(432000);
    float* bufB    = alloc(432000);
    float* scratch = alloc(1944000);   // branch1 t_raw(3)+o_raw(3); branch2 aliases this
    float* feat1   = alloc(64 * 30);
    float* feat2   = alloc(64 * 16);
    float* stats   = alloc(2288);
    float* wkbuf   = alloc(4464000);   // dynamic kernels: 64*2*(25+49+81)*225

    float* t_raw = scratch;            // 3 x 216000
    float* o_raw = scratch + 648000;   // 3 x 432000

    hipMemsetAsync(stats, 0, 2288 * sizeof(float), stream);

    // ---- branch 1: 3 IVoubottleneck blocks ----
    const float* cur = x;
    float* dst = bufA;
    for (int bi = 0; bi < 3; ++bi){
        float* st_t = stats + bi * 90;          // 3 x (15 sum + 15 sumsq)
        float* st_o = stats + 270 + bi * 180;   // 3 x (30 sum + 30 sumsq)
        conv1x1_k<<<dim3(844, 1, 3), 256, 0, stream>>>(
            cur, blk_w1 + bi * 1350, t_raw, st_t, 30, 15, 225, 64, 450, 216000, 30);
        wkgen_all<<<dim3(64, 2, 3), 256, 0, stream>>>(
            t_raw, st_t, blk_ig + bi * 45, blk_ib + bi * 45,
            blk_w2_5 + bi * 750, blk_w2_7 + bi * 1470, blk_w2_9 + bi * 2430, wkbuf);
        invol_apply_all<<<dim3(64, 8, 3), 256, 0, stream>>>(cur, wkbuf, o_raw, st_o);
        blockend<<<1688, 256, 0, stream>>>(o_raw, o_raw + 432000, o_raw + 864000,
                                           st_o, st_o + 60, st_o + 120,
                                           blk_g + bi * 90, blk_b + bi * 90, blk_conv + bi * 2700,
                                           cur, dst);
        cur = dst;
        dst = (bi == 0) ? bufB : bufA;
    }
    covpool<30, 225, 1024><<<64, 1024, 0, stream>>>(cur, feat1);

    // ---- branch 2: cross attention (aliases scratch; branch-1 uses are done) ----
    float* t_loc = scratch;
    float* t_glb = t_loc + 58752;
    float* o_idn = t_glb + 58752;
    float* t3    = o_idn + 117504;
    float* o3    = t3 + 58752;
    float* o5    = o3 + 117504;
    float* t4    = o5 + 58752;
    float* o6    = t4 + 29376;
    float* o8    = o6 + 58752;
    float* t5    = o8 + 29376;
    float* o9    = t5 + 14400;
    float* o11   = o9 + 29376;

    float* s_tloc = stats + 810;
    float* s_tglb = s_tloc + 204;
    float* s_t3   = s_tglb + 204;
    float* s_o3   = s_t3 + 204;
    float* s_t4   = s_o3 + 408;
    float* s_o6   = s_t4 + 102;
    float* s_t5   = s_o6 + 204;
    float* s_o9   = s_t5 + 50;

    conv_dual<<<dim3(230, 1, 2), 256, 0, stream>>>(y, loc_w1, glb_w1, t_loc, t_glb,
                                                   s_tloc, s_tglb, 204, 102);
    crossatt_fused<<<459, 256, 0, stream>>>(y, t_loc, t_glb, s_tloc, s_tglb,
                                            loc_g, loc_b, glb_g, glb_b,
                                            loc_w2, glb_w2, o_idn);
    // c3
    conv1x1_k<<<230, 256, 0, stream>>>(o_idn, c3_w1, t3, s_t3, 204, 102, 9, 64, 0, 0, 0);
    invol3_fused<<<459, 256, 0, stream>>>(o_idn, t3, s_t3, c3_g, c3_b, c3_w2, o3, s_o3, 204, 102);
    bnconv<<<230, 256, 0, stream>>>(o3, s_o3, bn1g, bn1b, o_idn, p1, o5, 204, 102);
    // c4
    conv1x1_k<<<115, 256, 0, stream>>>(o5, c4_w1, t4, s_t4, 102, 51, 9, 64, 0, 0, 0);
    invol3_fused<<<230, 256, 0, stream>>>(o5, t4, s_t4, c4_g, c4_b, c4_w2, o6, s_o6, 102, 51);
    bnconv<<<115, 256, 0, stream>>>(o6, s_o6, bn2g, bn2b, nullptr, p2, o8, 102, 51);
    // c5
    conv1x1_k<<<57, 256, 0, stream>>>(o8, c5_w1, t5, s_t5, 51, 25, 9, 64, 0, 0, 0);
    invol3_fused<<<115, 256, 0, stream>>>(o8, t5, s_t5, c5_g, c5_b, c5_w2, o9, s_o9, 51, 25);
    bnconv<<<36, 256, 0, stream>>>(o9, s_o9, bn3g, bn3b, o8, p3, o11, 51, 16);
    covpool<16, 9, 256><<<64, 256, 0, stream>>>(o11, feat2);

    // ---- head ----
    head_k<<<1, 256, 0, stream>>>(feat1, feat2, hg, hb, lw, lb, (float*)d_out);
}

// Round 9
// 1194.561 us; speedup vs baseline: 1.1269x; 1.0280x over previous
//
#include <hip/hip_runtime.h>
#include <math.h>

#define EPS 1e-5f

__device__ inline void wave_red2(float& s1, float& s2){
    for (int off = 32; off; off >>= 1){
        s1 += __shfl_down(s1, off, 64);
        s2 += __shfl_down(s2, off, 64);
    }
}

// ---------------------------------------------------------------------------
// conv1x1 (out[b,j,hw] = sum_c in[b,c,hw]*w[j,c]) + optional stats.
// Device version; bx replaces blockIdx.x. Body identical to round-2 kernel.
// ---------------------------------------------------------------------------
__device__ __forceinline__
void dev_conv1x1(const float* __restrict__ in, const float* __restrict__ w,
                 float* __restrict__ out, float* __restrict__ stats,
                 int Cin, int Cout, int HW, int B, int bx)
{
    int npos = B * HW;
    int total = Cout * npos;
    int item = bx * 256 + threadIdx.x;
    if (item >= total) return;
    int j = item / npos;
    int pos = item - j * npos;
    int b = pos / HW, hw = pos - b * HW;
    int ju = __builtin_amdgcn_readfirstlane(j);
    const float* ip = in + (size_t)b * Cin * HW + hw;
    const float* wr = w + (size_t)ju * Cin;
    float a0 = 0.f, a1 = 0.f, a2 = 0.f, a3 = 0.f;
    int c = 0;
    #pragma unroll 2
    for (; c + 3 < Cin; c += 4){
        a0 += ip[(size_t)c * HW] * wr[c];
        a1 += ip[(size_t)(c + 1) * HW] * wr[c + 1];
        a2 += ip[(size_t)(c + 2) * HW] * wr[c + 2];
        a3 += ip[(size_t)(c + 3) * HW] * wr[c + 3];
    }
    for (; c < Cin; ++c) a0 += ip[(size_t)c * HW] * wr[c];
    float acc = (a0 + a1) + (a2 + a3);
    out[(size_t)b * Cout * HW + (size_t)j * HW + hw] = acc;
    if (stats){
        float s1 = acc, s2 = acc * acc;
        wave_red2(s1, s2);
        if ((threadIdx.x & 63) == 0){
            atomicAdd(&stats[ju], s1);
            atomicAdd(&stats[Cout + ju], s2);
        }
    }
}

// ---------------------------------------------------------------------------
// Branch-1 fused involution (round-2 version: best measured, 139 us).
// acc[] kept in VGPRs via constant-bound epilogue loop + uniform nch guard.
// ---------------------------------------------------------------------------
template<int K>
__device__ void dev_invol_b1(const float* __restrict__ in, const float* __restrict__ t_raw,
                             const float* __restrict__ tstats,
                             const float* __restrict__ tg, const float* __restrict__ tb,
                             const float* __restrict__ w2,
                             float* __restrict__ o_raw, float* __restrict__ ostats,
                             float* lds, int b, int g, int c0, int nch)
{
    constexpr int KK = K * K, P = (K - 1) / 2;
    float* in_s = lds;            // 8*225
    float* scb  = lds + 1800;     // 15
    float* shb  = lds + 1815;     // 15
    int tid = threadIdx.x;

    if (tid < 15){
        const float invN = 1.f / 14400.f;
        float mean = tstats[tid] * invN;
        float var  = tstats[15 + tid] * invN - mean * mean;
        float s = tg[tid] * rsqrtf(var + EPS);
        scb[tid] = s; shb[tid] = tb[tid] - mean * s;
    }
    const float* w2g = w2 + (size_t)g * KK * 15;   // block-uniform base
    const float* inb = in + (size_t)b * 6750 + (size_t)(g * 15 + c0) * 225;
    int stage = nch * 225;
    for (int i = tid; i < stage; i += 256) in_s[i] = inb[i];
    __syncthreads();

    bool act = tid < 225;
    int p = act ? tid : 224;
    int h = p / 15, w = p - h * 15;

    float treg[15];
    const float* trb = t_raw + (size_t)b * 3375 + p;
    #pragma unroll
    for (int j = 0; j < 15; ++j){
        float v = trb[j * 225] * scb[j] + shb[j];
        treg[j] = v > 0.f ? v : 0.f;
    }

    float acc[8];
    #pragma unroll
    for (int cc = 0; cc < 8; ++cc) acc[cc] = 0.f;

    for (int ki = 0; ki < K; ++ki){
        int hh = h + ki - P;
        bool hok = (unsigned)hh < 15u;
        const float* w2row = w2g + ki * K * 15;
        #pragma unroll
        for (int kj0 = 0; kj0 < K; kj0 += 3){
            const float* wr = w2row + kj0 * 15;
            float a0 = 0.f, a1 = 0.f, a2 = 0.f;
            #pragma unroll
            for (int j = 0; j < 15; ++j){
                float tv = treg[j];
                a0 += tv * wr[j];
                if (kj0 + 1 < K) a1 += tv * wr[15 + j];
                if (kj0 + 2 < K) a2 += tv * wr[30 + j];
            }
            float wv[3] = {a0, a1, a2};
            #pragma unroll
            for (int t = 0; t < 3; ++t){
                int kj = kj0 + t;
                if (kj >= K) break;
                int ww = w + kj - P;
                bool ok = hok && ((unsigned)ww < 15u);
                float sc2 = ok ? wv[t] : 0.f;
                int offr = ok ? hh * 15 + ww : 0;
                #pragma unroll
                for (int cc = 0; cc < 8; ++cc) acc[cc] += sc2 * in_s[cc * 225 + offr];
            }
        }
    }

    float* ob = o_raw + (size_t)b * 6750 + (size_t)(g * 15 + c0) * 225;
    #pragma unroll
    for (int cc = 0; cc < 8; ++cc){
        if (cc < nch){
            float val = act ? acc[cc] : 0.f;
            if (act) ob[cc * 225 + p] = val;
            float s1 = val, s2 = val * val;
            wave_red2(s1, s2);
            if ((tid & 63) == 0){
                atomicAdd(&ostats[g * 15 + c0 + cc], s1);
                atomicAdd(&ostats[30 + g * 15 + c0 + cc], s2);
            }
        }
    }
}

// ---------------------------------------------------------------------------
// blockend device version (body identical).
// ---------------------------------------------------------------------------
__device__ __forceinline__
void dev_blockend(const float* __restrict__ o0, const float* __restrict__ o1,
                  const float* __restrict__ o2,
                  const float* __restrict__ s0, const float* __restrict__ s1,
                  const float* __restrict__ s2,
                  const float* __restrict__ g, const float* __restrict__ bb,
                  const float* __restrict__ conv,
                  const float* __restrict__ oldout, float* __restrict__ newout, int bx)
{
    __shared__ float sc[90], sh[90];
    int tid = threadIdx.x;
    if (tid < 90){
        int ii = tid / 30, cc = tid - ii * 30;
        const float* st = ii == 0 ? s0 : (ii == 1 ? s1 : s2);
        const float invN = 1.f / 14400.f;
        float mean = st[cc] * invN;
        float var = st[30 + cc] * invN - mean * mean;
        float s = g[tid] * rsqrtf(var + EPS);
        sc[tid] = s; sh[tid] = bb[tid] - mean * s;
    }
    __syncthreads();
    int item = bx * 256 + tid;
    if (item >= 432000) return;
    int c = item / 14400, pos = item - c * 14400;
    int b = pos / 225, hw = pos - b * 225;
    int cu = __builtin_amdgcn_readfirstlane(c);
    float acc = oldout[(size_t)b * 6750 + c * 225 + hw];
    const float* cr = conv + cu * 90;
    const float* bases[3] = {o0, o1, o2};
    #pragma unroll
    for (int ii = 0; ii < 3; ++ii){
        const float* op = bases[ii] + (size_t)b * 6750 + hw;
        float sA = 0.f, sB = 0.f;
        #pragma unroll 5
        for (int cc = 0; cc < 30; cc += 2){
            float v = op[cc * 225] * sc[ii * 30 + cc] + sh[ii * 30 + cc];
            v = v > 0.f ? v : 0.f;
            sA += v * cr[ii * 30 + cc];
            float v2 = op[(cc + 1) * 225] * sc[ii * 30 + cc + 1] + sh[ii * 30 + cc + 1];
            v2 = v2 > 0.f ? v2 : 0.f;
            sB += v2 * cr[ii * 30 + cc + 1];
        }
        acc += sA + sB;
    }
    newout[(size_t)b * 6750 + c * 225 + hw] = acc;
}

// ---------------------------------------------------------------------------
// cross-attention front device version (body identical).
// ---------------------------------------------------------------------------
__device__ __forceinline__
void dev_crossatt(const float* __restrict__ y,
                  const float* __restrict__ t_loc, const float* __restrict__ t_glb,
                  const float* __restrict__ s_tloc, const float* __restrict__ s_tglb,
                  const float* __restrict__ lg, const float* __restrict__ lb,
                  const float* __restrict__ gg, const float* __restrict__ gb,
                  const float* __restrict__ loc_w2, const float* __restrict__ glb_w2,
                  float* __restrict__ out, int bx)
{
    __shared__ float lsc[102], lsh[102], gsc[102], gsh[102];
    const float invN = 1.f / 576.f;
    for (int j = threadIdx.x; j < 102; j += 256){
        float m1 = s_tloc[j] * invN;
        float v1 = s_tloc[102 + j] * invN - m1 * m1;
        float a1 = lg[j] * rsqrtf(v1 + EPS);
        lsc[j] = a1; lsh[j] = lb[j] - m1 * a1;
        float m2 = s_tglb[j] * invN;
        float v2 = s_tglb[102 + j] * invN - m2 * m2;
        float a2 = gg[j] * rsqrtf(v2 + EPS);
        gsc[j] = a2; gsh[j] = gb[j] - m2 * a2;
    }
    __syncthreads();
    int item = bx * 256 + threadIdx.x;
    if (item >= 204 * 576) return;
    int c = item / 576, pos = item - c * 576;
    int b = pos / 9, hw = pos - b * 9;
    int h = hw / 3, w = hw - h * 3;
    int cu = __builtin_amdgcn_readfirstlane(c);

    const float* tl = t_loc + (size_t)b * 918 + hw;
    const float* tg_ = t_glb + (size_t)b * 918 + hw;
    const float* wl = loc_w2 + (size_t)cu * 918;
    float wk[9];
    #pragma unroll
    for (int kk = 0; kk < 9; ++kk) wk[kk] = 0.f;
    for (int j = 0; j < 102; ++j){
        float a = tl[j * 9] * lsc[j] + lsh[j];
        a = a > 0.f ? a : 0.f;
        float g2 = tg_[j * 9] * gsc[j] + gsh[j];
        g2 = g2 > 0.f ? g2 : 0.f;
        #pragma unroll
        for (int kk = 0; kk < 9; ++kk)
            wk[kk] += a * wl[kk * 102 + j] + g2 * glb_w2[kk * 102 + j];
    }
    const float* pb = y + (size_t)b * 1836 + c * 9;
    float acc = 0.f;
    #pragma unroll
    for (int ki = 0; ki < 3; ++ki){
        int hh = h + ki - 1;
        bool hok = (unsigned)hh < 3u;
        #pragma unroll
        for (int kj = 0; kj < 3; ++kj){
            int ww = w + kj - 1;
            bool ok = hok && ((unsigned)ww < 3u);
            float v = ok ? pb[hh * 3 + ww] : 0.f;
            acc += wk[ki * 3 + kj] * v;
        }
    }
    out[(size_t)b * 1836 + c * 9 + hw] = pb[hw] * acc;
}

// ---------------------------------------------------------------------------
// groups==1 involution device version (body identical).
// ---------------------------------------------------------------------------
__device__ __forceinline__
void dev_invol3(const float* __restrict__ pin, const float* __restrict__ t_raw,
                const float* __restrict__ tstats,
                const float* __restrict__ tg, const float* __restrict__ tb,
                const float* __restrict__ w2,
                float* __restrict__ out, float* __restrict__ ostats,
                int C, int Ct, int bx)
{
    __shared__ float tsc[102], tsh[102];
    const float invN = 1.f / 576.f;
    for (int j = threadIdx.x; j < Ct; j += 256){
        float mean = tstats[j] * invN;
        float var  = tstats[Ct + j] * invN - mean * mean;
        float s = tg[j] * rsqrtf(var + EPS);
        tsc[j] = s; tsh[j] = tb[j] - mean * s;
    }
    __syncthreads();
    int item = bx * 256 + threadIdx.x;
    if (item >= C * 576) return;
    int c = item / 576, pos = item - c * 576;
    int b = pos / 9, hw = pos - b * 9;
    int h = hw / 3, w = hw - h * 3;

    const float* tp = t_raw + (size_t)b * Ct * 9 + hw;
    float wk[9];
    #pragma unroll
    for (int kk = 0; kk < 9; ++kk) wk[kk] = 0.f;
    for (int j = 0; j < Ct; ++j){
        float t = tp[j * 9] * tsc[j] + tsh[j];
        t = t > 0.f ? t : 0.f;
        #pragma unroll
        for (int kk = 0; kk < 9; ++kk) wk[kk] += t * w2[kk * Ct + j];
    }
    const float* pb = pin + (size_t)b * C * 9 + c * 9;
    float acc = 0.f;
    #pragma unroll
    for (int ki = 0; ki < 3; ++ki){
        int hh = h + ki - 1;
        bool hok = (unsigned)hh < 3u;
        #pragma unroll
        for (int kj = 0; kj < 3; ++kj){
            int ww = w + kj - 1;
            bool ok = hok && ((unsigned)ww < 3u);
            float v = ok ? pb[hh * 3 + ww] : 0.f;
            acc += wk[ki * 3 + kj] * v;
        }
    }
    out[(size_t)b * C * 9 + c * 9 + hw] = acc;
    float s1 = acc, s2 = acc * acc;
    wave_red2(s1, s2);
    if ((threadIdx.x & 63) == 0){
        int cu = __builtin_amdgcn_readfirstlane(c);
        atomicAdd(&ostats[cu], s1);
        atomicAdd(&ostats[C + cu], s2);
    }
}

// ---------------------------------------------------------------------------
// BN+ReLU(+residual)->conv1x1 device version (body identical).
// ---------------------------------------------------------------------------
__device__ __forceinline__
void dev_bnconv(const float* __restrict__ in, const float* __restrict__ stats,
                const float* __restrict__ g, const float* __restrict__ bta,
                const float* __restrict__ idn, const float* __restrict__ w,
                float* __restrict__ out, int Cin, int Cout, int bx)
{
    __shared__ float sc[204], sh[204];
    for (int j = threadIdx.x; j < Cin; j += 256){
        const float invN = 1.f / 576.f;
        float mean = stats[j] * invN;
        float var = stats[Cin + j] * invN - mean * mean;
        float s = g[j] * rsqrtf(var + EPS);
        sc[j] = s; sh[j] = bta[j] - mean * s;
    }
    __syncthreads();
    int item = bx * 256 + threadIdx.x;
    if (item >= Cout * 576) return;
    int j = item / 576, pos = item - j * 576;
    int b = pos / 9, hw = pos - b * 9;
    int ju = __builtin_amdgcn_readfirstlane(j);
    const float* ip = in + (size_t)b * Cin * 9 + hw;
    const float* ir = idn ? idn + (size_t)b * Cin * 9 + hw : nullptr;
    const float* wr = w + (size_t)ju * Cin;
    float a0 = 0.f, a1 = 0.f, a2 = 0.f, a3 = 0.f;
    int c = 0;
    #pragma unroll 2
    for (; c + 3 < Cin; c += 4){
        float v0 = ip[c * 9] * sc[c] + sh[c];             v0 = v0 > 0.f ? v0 : 0.f;
        float v1 = ip[(c + 1) * 9] * sc[c + 1] + sh[c + 1]; v1 = v1 > 0.f ? v1 : 0.f;
        float v2 = ip[(c + 2) * 9] * sc[c + 2] + sh[c + 2]; v2 = v2 > 0.f ? v2 : 0.f;
        float v3 = ip[(c + 3) * 9] * sc[c + 3] + sh[c + 3]; v3 = v3 > 0.f ? v3 : 0.f;
        if (ir){
            v0 += ir[c * 9]; v1 += ir[(c + 1) * 9];
            v2 += ir[(c + 2) * 9]; v3 += ir[(c + 3) * 9];
        }
        a0 += v0 * wr[c];
        a1 += v1 * wr[c + 1];
        a2 += v2 * wr[c + 2];
        a3 += v3 * wr[c + 3];
    }
    for (; c < Cin; ++c){
        float v = ip[c * 9] * sc[c] + sh[c];
        v = v > 0.f ? v : 0.f;
        if (ir) v += ir[c * 9];
        a0 += v * wr[c];
    }
    out[(size_t)b * Cout * 9 + j * 9 + hw] = (a0 + a1) + (a2 + a3);
}

// ---------------------------------------------------------------------------
// GlobalCovPooling device version (math identical; thread map via TB only).
// ---------------------------------------------------------------------------
template<int C, int N, int TB>
__device__ void dev_covpool(const float* __restrict__ in, float* __restrict__ feat, int b)
{
    __shared__ float X[N * C];
    __shared__ float Ybuf[C * C], Mbuf[C * C], Zbuf[C * C], Z2buf[C * C];
    __shared__ float mu[C];
    __shared__ float scal[2];
    int tid = threadIdx.x;
    const float* ib = in + (size_t)b * C * N;
    for (int i = tid; i < N * C; i += TB){
        int n = i / C, c = i - n * C;
        X[i] = ib[(size_t)c * N + n];
    }
    __syncthreads();
    if (tid < C){
        float s0 = 0.f, s1 = 0.f, s2 = 0.f, s3 = 0.f;
        int n = 0;
        for (; n + 3 < N; n += 4){
            s0 += X[n * C + tid];
            s1 += X[(n + 1) * C + tid];
            s2 += X[(n + 2) * C + tid];
            s3 += X[(n + 3) * C + tid];
        }
        for (; n < N; ++n) s0 += X[n * C + tid];
        mu[tid] = ((s0 + s1) + (s2 + s3)) / (float)N;
    }
    __syncthreads();
    constexpr int CC = C * C;
    for (int i = tid; i < CC; i += TB){
        int c = i / C, d = i - c * C;
        float s0 = 0.f, s1 = 0.f, s2 = 0.f, s3 = 0.f;
        int n = 0;
        for (; n + 3 < N; n += 4){
            s0 += X[n * C + c] * X[n * C + d];
            s1 += X[(n + 1) * C + c] * X[(n + 1) * C + d];
            s2 += X[(n + 2) * C + c] * X[(n + 2) * C + d];
            s3 += X[(n + 3) * C + c] * X[(n + 3) * C + d];
        }
        for (; n < N; ++n) s0 += X[n * C + c] * X[n * C + d];
        Ybuf[i] = ((s0 + s1) + (s2 + s3)) / (float)N - mu[c] * mu[d];
    }
    __syncthreads();
    if (tid == 0){
        float tr = 0.f;
        for (int c = 0; c < C; ++c) tr += Ybuf[c * C + c];
        scal[0] = 1.f / tr;
    }
    __syncthreads();
    for (int i = tid; i < CC; i += TB){
        int c = i / C, d = i - c * C;
        Ybuf[i] *= scal[0];
        Zbuf[i] = (c == d) ? 1.f : 0.f;
    }
    __syncthreads();
    float* zs = Zbuf; float* zd = Z2buf;
    for (int it = 0; it < 6; ++it){
        for (int i = tid; i < CC; i += TB){
            int c = i / C, d = i - c * C;
            float sA = 0.f, sB = 0.f;
            #pragma unroll 3
            for (int e = 0; e < C; e += 2){
                sA += zs[c * C + e] * Ybuf[e * C + d];
                sB += zs[c * C + e + 1] * Ybuf[(e + 1) * C + d];
            }
            Mbuf[i] = ((c == d) ? 3.f : 0.f) - (sA + sB);
        }
        __syncthreads();
        for (int i = tid; i < CC; i += TB){
            int c = i / C, d = i - c * C;
            float sA = 0.f, sB = 0.f;
            #pragma unroll 3
            for (int e = 0; e < C; e += 2){
                sA += Mbuf[c * C + e] * zs[e * C + d];
                sB += Mbuf[c * C + e + 1] * zs[(e + 1) * C + d];
            }
            zd[i] = 0.5f * (sA + sB);
        }
        for (int i = tid; i < CC; i += TB) Ybuf[i] *= 0.5f * Mbuf[i];
        __syncthreads();
        float* t = zs; zs = zd; zd = t;
    }
    if (tid == 0){
        float tr = 0.f;
        for (int c = 0; c < C; ++c) tr += Ybuf[c * C + c];
        scal[1] = sqrtf(tr);
    }
    __syncthreads();
    if (tid < C){
        float s = 0.f;
        #pragma unroll 6
        for (int c = 0; c < C; ++c) s += Ybuf[c * C + tid];
        feat[(size_t)b * C + tid] = scal[1] * s / (float)C;
    }
}

// ===========================================================================
// Paired-step wrappers: blockIdx.z selects role; branch-1 (A) and branch-2
// (B) are independent DAG chains, so co-running their steps is race-free.
// Branch-2 buffers are in a DEDICATED ws region (no aliasing with branch-1).
// ===========================================================================

// L1: A = branch1 conv1x1 (b0, z=0..2)  ||  B = conv_dual (z=3)
__global__ __launch_bounds__(256)
void step_conv_convdual(const float* xin, const float* w1, float* t_raw, float* st_t,
                        const float* yin, const float* locw1, const float* glbw1,
                        float* t_loc, float* t_glb, float* s_tloc, float* s_tglb)
{
    int z = blockIdx.z, bx = blockIdx.x;
    if (z < 3){
        dev_conv1x1(xin, w1 + z * 450, t_raw + (size_t)z * 216000, st_t + z * 30,
                    30, 15, 225, 64, bx);
    } else {
        int f = (z - 3) * 844 + bx;
        if (f >= 460) return;
        int zz = f / 230, b2 = f - zz * 230;
        dev_conv1x1(yin, zz ? glbw1 : locw1, zz ? t_glb : t_loc,
                    zz ? s_tglb : s_tloc, 204, 102, 9, 64, b2);
    }
}

// L2: A = fused invol (z=0..2)  ||  B = crossatt (z=3..4 flat)
__global__ __launch_bounds__(256)
void step_invol_crossatt(const float* cur, const float* t_raw3, const float* tstats3,
                         const float* tg3, const float* tb3,
                         const float* w25, const float* w27, const float* w29,
                         float* o_raw3, float* ostats3,
                         const float* yin, const float* t_loc, const float* t_glb,
                         const float* s_tloc, const float* s_tglb,
                         const float* lg, const float* lbp, const float* gg, const float* gb,
                         const float* locw2, const float* glbw2, float* o_idn)
{
    __shared__ float lds[1830];
    int z = blockIdx.z;
    if (z < 3){
        int b = blockIdx.x, g = (int)blockIdx.y >> 1, c0 = ((int)blockIdx.y & 1) * 8;
        int nch = c0 ? 7 : 8;
        if (z == 0)
            dev_invol_b1<5>(cur, t_raw3,          tstats3,      tg3,      tb3,      w25, o_raw3,          ostats3,       lds, b, g, c0, nch);
        else if (z == 1)
            dev_invol_b1<7>(cur, t_raw3 + 216000, tstats3 + 30, tg3 + 15, tb3 + 15, w27, o_raw3 + 432000, ostats3 + 60,  lds, b, g, c0, nch);
        else
            dev_invol_b1<9>(cur, t_raw3 + 432000, tstats3 + 60, tg3 + 30, tb3 + 30, w29, o_raw3 + 864000, ostats3 + 120, lds, b, g, c0, nch);
    } else {
        int f = (z - 3) * 256 + (int)blockIdx.y * 64 + (int)blockIdx.x;
        if (f >= 459) return;
        dev_crossatt(yin, t_loc, t_glb, s_tloc, s_tglb, lg, lbp, gg, gb,
                     locw2, glbw2, o_idn, f);
    }
}

// L3/L6/L9: A = blockend  ||  B = branch2 conv1x1 (nB blocks)
__global__ __launch_bounds__(256)
void step_be_conv(const float* o0, const float* o1, const float* o2,
                  const float* s0, const float* s1, const float* s2,
                  const float* g, const float* bb, const float* conv,
                  const float* oldout, float* newout,
                  const float* bin, const float* bw, float* bout, float* bstats,
                  int bCin, int bCout, int nB)
{
    if (blockIdx.z == 0){
        dev_blockend(o0, o1, o2, s0, s1, s2, g, bb, conv, oldout, newout, blockIdx.x);
    } else {
        if ((int)blockIdx.x >= nB) return;
        dev_conv1x1(bin, bw, bout, bstats, bCin, bCout, 9, 64, blockIdx.x);
    }
}

// L4/L7: A = branch1 conv1x1 (z=0..2)  ||  B = invol3 (z=3)
__global__ __launch_bounds__(256)
void step_conv_inv3(const float* cur, const float* w1, float* t_raw, float* st_t,
                    const float* pin, const float* traw2, const float* tst2,
                    const float* tg2, const float* tb2, const float* w2,
                    float* out2, float* ost2, int C, int Ct, int nB)
{
    int z = blockIdx.z, bx = blockIdx.x;
    if (z < 3){
        dev_conv1x1(cur, w1 + z * 450, t_raw + (size_t)z * 216000, st_t + z * 30,
                    30, 15, 225, 64, bx);
    } else {
        if (bx >= nB) return;
        dev_invol3(pin, traw2, tst2, tg2, tb2, w2, out2, ost2, C, Ct, bx);
    }
}

// L5/L8: A = fused invol (z=0..2)  ||  B = bnconv (z=3 flat)
__global__ __launch_bounds__(256)
void step_invol_bnconv(const float* cur, const float* t_raw3, const float* tstats3,
                       const float* tg3, const float* tb3,
                       const float* w25, const float* w27, const float* w29,
                       float* o_raw3, float* ostats3,
                       const float* bin, const float* bstats,
                       const float* bg, const float* bbp, const float* bidn,
                       const float* bw, float* bout, int bCin, int bCout, int nB)
{
    __shared__ float lds[1830];
    int z = blockIdx.z;
    if (z < 3){
        int b = blockIdx.x, g = (int)blockIdx.y >> 1, c0 = ((int)blockIdx.y & 1) * 8;
        int nch = c0 ? 7 : 8;
        if (z == 0)
            dev_invol_b1<5>(cur, t_raw3,          tstats3,      tg3,      tb3,      w25, o_raw3,          ostats3,       lds, b, g, c0, nch);
        else if (z == 1)
            dev_invol_b1<7>(cur, t_raw3 + 216000, tstats3 + 30, tg3 + 15, tb3 + 15, w27, o_raw3 + 432000, ostats3 + 60,  lds, b, g, c0, nch);
        else
            dev_invol_b1<9>(cur, t_raw3 + 432000, tstats3 + 60, tg3 + 30, tb3 + 30, w29, o_raw3 + 864000, ostats3 + 120, lds, b, g, c0, nch);
    } else {
        int f = (int)blockIdx.y * 64 + (int)blockIdx.x;
        if (f >= nB) return;
        dev_bnconv(bin, bstats, bg, bbp, bidn, bw, bout, bCin, bCout, f);
    }
}

// L10: A = covpool30 (z=0)  ||  B = invol3 c5 (z=1)
__global__ __launch_bounds__(256)
void step_cov_inv3(const float* cin, float* feat,
                   const float* pin, const float* traw2, const float* tst2,
                   const float* tg2, const float* tb2, const float* w2,
                   float* out2, float* ost2, int C, int Ct, int nB)
{
    if (blockIdx.z == 0){
        if (blockIdx.x >= 64) return;
        dev_covpool<30, 225, 256>(cin, feat, blockIdx.x);
    } else {
        if ((int)blockIdx.x >= nB) return;
        dev_invol3(pin, traw2, tst2, tg2, tb2, w2, out2, ost2, C, Ct, blockIdx.x);
    }
}

// Standalone wrappers
__global__ __launch_bounds__(256)
void bnconv_g(const float* in, const float* stats, const float* g, const float* bta,
              const float* idn, const float* w, float* out, int Cin, int Cout)
{
    dev_bnconv(in, stats, g, bta, idn, w, out, Cin, Cout, blockIdx.x);
}

template<int C, int N, int TB>
__global__ __launch_bounds__(TB)
void covpool_g(const float* __restrict__ in, float* __restrict__ feat)
{
    dev_covpool<C, N, TB>(in, feat, blockIdx.x);
}

// ---------------------------------------------------------------------------
// Head: concat feats, BN over batch, ReLU, linear, softmax. Single workgroup.
// ---------------------------------------------------------------------------
__global__ __launch_bounds__(256)
void head_k(const float* __restrict__ feat1, const float* __restrict__ feat2,
            const float* __restrict__ hg, const float* __restrict__ hb,
            const float* __restrict__ lw, const float* __restrict__ lb,
            float* __restrict__ out)
{
    __shared__ float f[46 * 64];
    int tid = threadIdx.x;
    for (int i = tid; i < 46 * 64; i += 256){
        int ch = i / 64, b = i - ch * 64;
        f[i] = ch < 30 ? feat1[b * 30 + ch] : feat2[b * 16 + (ch - 30)];
    }
    __syncthreads();
    if (tid < 46){
        float s = 0.f, s2 = 0.f;
        for (int b = 0; b < 64; ++b){ float v = f[tid * 64 + b]; s += v; s2 += v * v; }
        float mean = s / 64.f, var = s2 / 64.f - mean * mean;
        float sc = hg[tid] * rsqrtf(var + EPS), sh = hb[tid] - mean * sc;
        for (int b = 0; b < 64; ++b){
            float v = f[tid * 64 + b] * sc + sh;
            f[tid * 64 + b] = v > 0.f ? v : 0.f;
        }
    }
    __syncthreads();
    if (tid < 64){
        int b = tid;
        float l[16];
        float m = -1e30f;
        for (int o = 0; o < 16; ++o){
            float a = lb[o];
            for (int ch = 0; ch < 46; ++ch) a += f[ch * 64 + b] * lw[o * 46 + ch];
            l[o] = a; m = fmaxf(m, a);
        }
        float se = 0.f;
        for (int o = 0; o < 16; ++o){ l[o] = expf(l[o] - m); se += l[o]; }
        float inv = 1.f / se;
        for (int o = 0; o < 16; ++o) out[b * 16 + o] = l[o] * inv;
    }
}

extern "C" void kernel_launch(void* const* d_in, const int* in_sizes, int n_in,
                              void* d_out, int out_size, void* d_ws, size_t ws_size,
                              hipStream_t stream)
{
    (void)in_sizes; (void)n_in; (void)out_size; (void)ws_size;
    const float* x        = (const float*)d_in[0];
    const float* y        = (const float*)d_in[1];
    const float* blk_w1   = (const float*)d_in[2];
    const float* blk_ig   = (const float*)d_in[3];
    const float* blk_ib   = (const float*)d_in[4];
    const float* blk_w2_5 = (const float*)d_in[5];
    const float* blk_w2_7 = (const float*)d_in[6];
    const float* blk_w2_9 = (const float*)d_in[7];
    const float* blk_g    = (const float*)d_in[8];
    const float* blk_b    = (const float*)d_in[9];
    const float* blk_conv = (const float*)d_in[10];
    const float* loc_w1 = (const float*)d_in[11];
    const float* loc_g  = (const float*)d_in[12];
    const float* loc_b  = (const float*)d_in[13];
    const float* loc_w2 = (const float*)d_in[14];
    const float* glb_w1 = (const float*)d_in[15];
    const float* glb_g  = (const float*)d_in[16];
    const float* glb_b  = (const float*)d_in[17];
    const float* glb_w2 = (const float*)d_in[18];
    const float* c3_w1 = (const float*)d_in[19];
    const float* c3_g  = (const float*)d_in[20];
    const float* c3_b  = (const float*)d_in[21];
    const float* c3_w2 = (const float*)d_in[22];
    const float* c4_w1 = (const float*)d_in[23];
    const float* c4_g  = (const float*)d_in[24];
    const float* c4_b  = (const float*)d_in[25];
    const float* c4_w2 = (const float*)d_in[26];
    const float* c5_w1 = (const float*)d_in[27];
    const float* c5_g  = (const float*)d_in[28];
    const float* c5_b  = (const float*)d_in[29];
    const float* c5_w2 = (const float*)d_in[30];
    const float* p1 = (const float*)d_in[31];
    const float* p2 = (const float*)d_in[32];
    const float* p3 = (const float*)d_in[33];
    const float* bn1g = (const float*)d_in[34];
    const float* bn1b = (const float*)d_in[35];
    const float* bn2g = (const float*)d_in[36];
    const float* bn2b = (const float*)d_in[37];
    const float* bn3g = (const float*)d_in[38];
    const float* bn3b = (const float*)d_in[39];
    const float* hg = (const float*)d_in[40];
    const float* hb = (const float*)d_in[41];
    const float* lw = (const float*)d_in[42];
    const float* lb = (const float*)d_in[43];

    float* ws = (float*)d_ws;
    size_t off = 0;
    auto alloc = [&](size_t n){ float* p = ws + off; off += n; return p; };
    float* bufA    = alloc(432000);
    float* bufB    = alloc(432000);
    float* scratch = alloc(1944000);   // branch1 only: t_raw(3) + o_raw(3)
    float* b2ws    = alloc(650000);    // branch2 DEDICATED region (needs 640512)
    float* feat1   = alloc(64 * 30);
    float* feat2   = alloc(64 * 16);
    float* stats   = alloc(2288);

    float* t_raw = scratch;            // 3 x 216000
    float* o_raw = scratch + 648000;   // 3 x 432000

    // branch2 buffers inside b2ws (sizes = C*576 of each producer)
    float* t_loc = b2ws;               // 58752
    float* t_glb = t_loc + 58752;      // 58752
    float* o_idn = t_glb + 58752;      // 117504
    float* t3    = o_idn + 117504;     // 58752
    float* o3    = t3 + 58752;         // 117504
    float* o5    = o3 + 117504;        // 58752
    float* t4    = o5 + 58752;         // 29376
    float* o6    = t4 + 29376;         // 58752  (invol3-c4 out, C=102 — R8 bug was 29376)
    float* o8    = o6 + 58752;         // 29376
    float* t5    = o8 + 29376;         // 14400
    float* o9    = t5 + 14400;         // 29376
    float* o11   = o9 + 29376;         // 9216

    float* s_tloc = stats + 810;
    float* s_tglb = s_tloc + 204;
    float* s_t3   = s_tglb + 204;
    float* s_o3   = s_t3 + 204;
    float* s_t4   = s_o3 + 408;
    float* s_o6   = s_t4 + 102;
    float* s_t5   = s_o6 + 204;
    float* s_o9   = s_t5 + 50;

    hipMemsetAsync(stats, 0, 2288 * sizeof(float), stream);

    // ---- paired schedule: branch1 chain (A) || branch2 chain (B) ----
    // L1: conv(b0) || conv_dual
    step_conv_convdual<<<dim3(844, 1, 4), 256, 0, stream>>>(
        x, blk_w1, t_raw, stats, y, loc_w1, glb_w1, t_loc, t_glb, s_tloc, s_tglb);
    // L2: invol(b0) || crossatt
    step_invol_crossatt<<<dim3(64, 4, 5), 256, 0, stream>>>(
        x, t_raw, stats, blk_ig, blk_ib, blk_w2_5, blk_w2_7, blk_w2_9,
        o_raw, stats + 270,
        y, t_loc, t_glb, s_tloc, s_tglb, loc_g, loc_b, glb_g, glb_b,
        loc_w2, glb_w2, o_idn);
    // L3: blockend(b0: x->bufA) || conv(c3)
    step_be_conv<<<dim3(1688, 1, 2), 256, 0, stream>>>(
        o_raw, o_raw + 432000, o_raw + 864000,
        stats + 270, stats + 330, stats + 390,
        blk_g, blk_b, blk_conv, x, bufA,
        o_idn, c3_w1, t3, s_t3, 204, 102, 230);
    // L4: conv(b1) || invol3(c3)
    step_conv_inv3<<<dim3(844, 1, 4), 256, 0, stream>>>(
        bufA, blk_w1 + 1350, t_raw, stats + 90,
        o_idn, t3, s_t3, c3_g, c3_b, c3_w2, o3, s_o3, 204, 102, 459);
    // L5: invol(b1) || bnconv(c3)
    step_invol_bnconv<<<dim3(64, 4, 4), 256, 0, stream>>>(
        bufA, t_raw, stats + 90, blk_ig + 45, blk_ib + 45,
        blk_w2_5 + 750, blk_w2_7 + 1470, blk_w2_9 + 2430,
        o_raw, stats + 450,
        o3, s_o3, bn1g, bn1b, o_idn, p1, o5, 204, 102, 230);
    // L6: blockend(b1: bufA->bufB) || conv(c4)
    step_be_conv<<<dim3(1688, 1, 2), 256, 0, stream>>>(
        o_raw, o_raw + 432000, o_raw + 864000,
        stats + 450, stats + 510, stats + 570,
        blk_g + 90, blk_b + 90, blk_conv + 2700, bufA, bufB,
        o5, c4_w1, t4, s_t4, 102, 51, 115);
    // L7: conv(b2) || invol3(c4)
    step_conv_inv3<<<dim3(844, 1, 4), 256, 0, stream>>>(
        bufB, blk_w1 + 2700, t_raw, stats + 180,
        o5, t4, s_t4, c4_g, c4_b, c4_w2, o6, s_o6, 102, 51, 230);
    // L8: invol(b2) || bnconv(c4)
    step_invol_bnconv<<<dim3(64, 4, 4), 256, 0, stream>>>(
        bufB, t_raw, stats + 180, blk_ig + 90, blk_ib + 90,
        blk_w2_5 + 1500, blk_w2_7 + 2940, blk_w2_9 + 4860,
        o_raw, stats + 630,
        o6, s_o6, bn2g, bn2b, nullptr, p2, o8, 102, 51, 115);
    // L9: blockend(b2: bufB->bufA) || conv(c5)
    step_be_conv<<<dim3(1688, 1, 2), 256, 0, stream>>>(
        o_raw, o_raw + 432000, o_raw + 864000,
        stats + 630, stats + 690, stats + 750,
        blk_g + 180, blk_b + 180, blk_conv + 5400, bufB, bufA,
        o8, c5_w1, t5, s_t5, 51, 25, 57);
    // L10: covpool1(bufA) || invol3(c5)
    step_cov_inv3<<<dim3(115, 1, 2), 256, 0, stream>>>(
        bufA, feat1,
        o8, t5, s_t5, c5_g, c5_b, c5_w2, o9, s_o9, 51, 25, 115);
    // L11: bnconv(c5)
    bnconv_g<<<36, 256, 0, stream>>>(o9, s_o9, bn3g, bn3b, o8, p3, o11, 51, 16);
    // L12: covpool2
    covpool_g<16, 9, 256><<<64, 256, 0, stream>>>(o11, feat2);
    // L13: head
    head_k<<<1, 256, 0, stream>>>(feat1, feat2, hg, hb, lw, lb, (float*)d_out);
}

// Round 10
// 1104.537 us; speedup vs baseline: 1.2187x; 1.0815x over previous
//
#include <hip/hip_runtime.h>
#include <math.h>

#define EPS 1e-5f

__device__ inline void wave_red2(float& s1, float& s2){
    for (int off = 32; off; off >>= 1){
        s1 += __shfl_down(s1, off, 64);
        s2 += __shfl_down(s2, off, 64);
    }
}

// ---------------------------------------------------------------------------
// conv1x1 + optional stats (device form).
// ---------------------------------------------------------------------------
__device__ __forceinline__
void dev_conv1x1(const float* __restrict__ in, const float* __restrict__ w,
                 float* __restrict__ out, float* __restrict__ stats,
                 int Cin, int Cout, int HW, int B, int bx)
{
    int npos = B * HW;
    int total = Cout * npos;
    int item = bx * 256 + threadIdx.x;
    if (item >= total) return;
    int j = item / npos;
    int pos = item - j * npos;
    int b = pos / HW, hw = pos - b * HW;
    int ju = __builtin_amdgcn_readfirstlane(j);
    const float* ip = in + (size_t)b * Cin * HW + hw;
    const float* wr = w + (size_t)ju * Cin;
    float a0 = 0.f, a1 = 0.f, a2 = 0.f, a3 = 0.f;
    int c = 0;
    #pragma unroll 2
    for (; c + 3 < Cin; c += 4){
        a0 += ip[(size_t)c * HW] * wr[c];
        a1 += ip[(size_t)(c + 1) * HW] * wr[c + 1];
        a2 += ip[(size_t)(c + 2) * HW] * wr[c + 2];
        a3 += ip[(size_t)(c + 3) * HW] * wr[c + 3];
    }
    for (; c < Cin; ++c) a0 += ip[(size_t)c * HW] * wr[c];
    float acc = (a0 + a1) + (a2 + a3);
    out[(size_t)b * Cout * HW + (size_t)j * HW + hw] = acc;
    if (stats){
        float s1 = acc, s2 = acc * acc;
        wave_red2(s1, s2);
        if ((threadIdx.x & 63) == 0){
            atomicAdd(&stats[ju], s1);
            atomicAdd(&stats[Cout + ju], s2);
        }
    }
}

// ---------------------------------------------------------------------------
// Branch-1 fused involution, MERGED channel halves (round 10): one block per
// (b,g) computes the wkv dots ONCE (they were previously duplicated by the
// two half-blocks) and applies to all 15 channels. Per-channel tap/summation
// order identical to the half version -> bit-exact. Stats partials are the
// same addend set per address.
// ---------------------------------------------------------------------------
template<int K>
__device__ void dev_invol_b1_full(const float* __restrict__ in, const float* __restrict__ t_raw,
                                  const float* __restrict__ tstats,
                                  const float* __restrict__ tg, const float* __restrict__ tb,
                                  const float* __restrict__ w2,
                                  float* __restrict__ o_raw, float* __restrict__ ostats,
                                  float* lds, int b, int g)
{
    constexpr int KK = K * K, P = (K - 1) / 2;
    float* in_s = lds;            // 15*225 = 3375
    float* scb  = lds + 3375;     // 15
    float* shb  = lds + 3390;     // 15
    int tid = threadIdx.x;

    if (tid < 15){
        const float invN = 1.f / 14400.f;
        float mean = tstats[tid] * invN;
        float var  = tstats[15 + tid] * invN - mean * mean;
        float s = tg[tid] * rsqrtf(var + EPS);
        scb[tid] = s; shb[tid] = tb[tid] - mean * s;
    }
    const float* w2g = w2 + (size_t)g * KK * 15;   // block-uniform base
    const float* inb = in + (size_t)b * 6750 + (size_t)g * 15 * 225;
    for (int i = tid; i < 3375; i += 256) in_s[i] = inb[i];
    __syncthreads();

    bool act = tid < 225;
    int p = act ? tid : 224;
    int h = p / 15, w = p - h * 15;

    float treg[15];
    const float* trb = t_raw + (size_t)b * 3375 + p;
    #pragma unroll
    for (int j = 0; j < 15; ++j){
        float v = trb[j * 225] * scb[j] + shb[j];
        treg[j] = v > 0.f ? v : 0.f;
    }

    float acc[15];
    #pragma unroll
    for (int cc = 0; cc < 15; ++cc) acc[cc] = 0.f;

    for (int ki = 0; ki < K; ++ki){
        int hh = h + ki - P;
        bool hok = (unsigned)hh < 15u;
        const float* w2row = w2g + ki * K * 15;
        #pragma unroll
        for (int kj0 = 0; kj0 < K; kj0 += 3){
            const float* wr = w2row + kj0 * 15;
            float a0 = 0.f, a1 = 0.f, a2 = 0.f;
            #pragma unroll
            for (int j = 0; j < 15; ++j){
                float tv = treg[j];
                a0 += tv * wr[j];
                if (kj0 + 1 < K) a1 += tv * wr[15 + j];
                if (kj0 + 2 < K) a2 += tv * wr[30 + j];
            }
            float wv[3] = {a0, a1, a2};
            #pragma unroll
            for (int t = 0; t < 3; ++t){
                int kj = kj0 + t;
                if (kj >= K) break;
                int ww = w + kj - P;
                bool ok = hok && ((unsigned)ww < 15u);
                float sc2 = ok ? wv[t] : 0.f;
                int offr = ok ? hh * 15 + ww : 0;
                #pragma unroll
                for (int cc = 0; cc < 15; ++cc) acc[cc] += sc2 * in_s[cc * 225 + offr];
            }
        }
    }

    float* ob = o_raw + (size_t)b * 6750 + (size_t)g * 15 * 225;
    #pragma unroll
    for (int cc = 0; cc < 15; ++cc){
        float val = act ? acc[cc] : 0.f;
        if (act) ob[cc * 225 + p] = val;
        float s1 = val, s2 = val * val;
        wave_red2(s1, s2);
        if ((tid & 63) == 0){
            atomicAdd(&ostats[g * 15 + cc], s1);
            atomicAdd(&ostats[30 + g * 15 + cc], s2);
        }
    }
}

__global__ __launch_bounds__(256)
void invol_b1m(const float* __restrict__ in, const float* __restrict__ t_raw3,
               const float* __restrict__ tstats3,
               const float* __restrict__ tg3, const float* __restrict__ tb3,
               const float* __restrict__ w2_5, const float* __restrict__ w2_7,
               const float* __restrict__ w2_9,
               float* __restrict__ o_raw3, float* __restrict__ ostats3)
{
    __shared__ float lds[3405];
    int b = blockIdx.x, g = blockIdx.y, ii = blockIdx.z;
    if (ii == 0)
        dev_invol_b1_full<5>(in, t_raw3,          tstats3,      tg3,      tb3,      w2_5, o_raw3,          ostats3,       lds, b, g);
    else if (ii == 1)
        dev_invol_b1_full<7>(in, t_raw3 + 216000, tstats3 + 30, tg3 + 15, tb3 + 15, w2_7, o_raw3 + 432000, ostats3 + 60,  lds, b, g);
    else
        dev_invol_b1_full<9>(in, t_raw3 + 432000, tstats3 + 60, tg3 + 30, tb3 + 30, w2_9, o_raw3 + 864000, ostats3 + 120, lds, b, g);
}

// ---------------------------------------------------------------------------
// blockend (device form).
// ---------------------------------------------------------------------------
__device__ __forceinline__
void dev_blockend(const float* __restrict__ o0, const float* __restrict__ o1,
                  const float* __restrict__ o2,
                  const float* __restrict__ s0, const float* __restrict__ s1,
                  const float* __restrict__ s2,
                  const float* __restrict__ g, const float* __restrict__ bb,
                  const float* __restrict__ conv,
                  const float* __restrict__ oldout, float* __restrict__ newout, int bx)
{
    __shared__ float sc[90], sh[90];
    int tid = threadIdx.x;
    if (tid < 90){
        int ii = tid / 30, cc = tid - ii * 30;
        const float* st = ii == 0 ? s0 : (ii == 1 ? s1 : s2);
        const float invN = 1.f / 14400.f;
        float mean = st[cc] * invN;
        float var = st[30 + cc] * invN - mean * mean;
        float s = g[tid] * rsqrtf(var + EPS);
        sc[tid] = s; sh[tid] = bb[tid] - mean * s;
    }
    __syncthreads();
    int item = bx * 256 + tid;
    if (item >= 432000) return;
    int c = item / 14400, pos = item - c * 14400;
    int b = pos / 225, hw = pos - b * 225;
    int cu = __builtin_amdgcn_readfirstlane(c);
    float acc = oldout[(size_t)b * 6750 + c * 225 + hw];
    const float* cr = conv + cu * 90;
    const float* bases[3] = {o0, o1, o2};
    #pragma unroll
    for (int ii = 0; ii < 3; ++ii){
        const float* op = bases[ii] + (size_t)b * 6750 + hw;
        float sA = 0.f, sB = 0.f;
        #pragma unroll 5
        for (int cc = 0; cc < 30; cc += 2){
            float v = op[cc * 225] * sc[ii * 30 + cc] + sh[ii * 30 + cc];
            v = v > 0.f ? v : 0.f;
            sA += v * cr[ii * 30 + cc];
            float v2 = op[(cc + 1) * 225] * sc[ii * 30 + cc + 1] + sh[ii * 30 + cc + 1];
            v2 = v2 > 0.f ? v2 : 0.f;
            sB += v2 * cr[ii * 30 + cc + 1];
        }
        acc += sA + sB;
    }
    newout[(size_t)b * 6750 + c * 225 + hw] = acc;
}

// ---------------------------------------------------------------------------
// cross-attention front (device form).
// ---------------------------------------------------------------------------
__device__ __forceinline__
void dev_crossatt(const float* __restrict__ y,
                  const float* __restrict__ t_loc, const float* __restrict__ t_glb,
                  const float* __restrict__ s_tloc, const float* __restrict__ s_tglb,
                  const float* __restrict__ lg, const float* __restrict__ lb,
                  const float* __restrict__ gg, const float* __restrict__ gb,
                  const float* __restrict__ loc_w2, const float* __restrict__ glb_w2,
                  float* __restrict__ out, int bx)
{
    __shared__ float lsc[102], lsh[102], gsc[102], gsh[102];
    const float invN = 1.f / 576.f;
    for (int j = threadIdx.x; j < 102; j += 256){
        float m1 = s_tloc[j] * invN;
        float v1 = s_tloc[102 + j] * invN - m1 * m1;
        float a1 = lg[j] * rsqrtf(v1 + EPS);
        lsc[j] = a1; lsh[j] = lb[j] - m1 * a1;
        float m2 = s_tglb[j] * invN;
        float v2 = s_tglb[102 + j] * invN - m2 * m2;
        float a2 = gg[j] * rsqrtf(v2 + EPS);
        gsc[j] = a2; gsh[j] = gb[j] - m2 * a2;
    }
    __syncthreads();
    int item = bx * 256 + threadIdx.x;
    if (item >= 204 * 576) return;
    int c = item / 576, pos = item - c * 576;
    int b = pos / 9, hw = pos - b * 9;
    int h = hw / 3, w = hw - h * 3;
    int cu = __builtin_amdgcn_readfirstlane(c);

    const float* tl = t_loc + (size_t)b * 918 + hw;
    const float* tg_ = t_glb + (size_t)b * 918 + hw;
    const float* wl = loc_w2 + (size_t)cu * 918;
    float wk[9];
    #pragma unroll
    for (int kk = 0; kk < 9; ++kk) wk[kk] = 0.f;
    for (int j = 0; j < 102; ++j){
        float a = tl[j * 9] * lsc[j] + lsh[j];
        a = a > 0.f ? a : 0.f;
        float g2 = tg_[j * 9] * gsc[j] + gsh[j];
        g2 = g2 > 0.f ? g2 : 0.f;
        #pragma unroll
        for (int kk = 0; kk < 9; ++kk)
            wk[kk] += a * wl[kk * 102 + j] + g2 * glb_w2[kk * 102 + j];
    }
    const float* pb = y + (size_t)b * 1836 + c * 9;
    float acc = 0.f;
    #pragma unroll
    for (int ki = 0; ki < 3; ++ki){
        int hh = h + ki - 1;
        bool hok = (unsigned)hh < 3u;
        #pragma unroll
        for (int kj = 0; kj < 3; ++kj){
            int ww = w + kj - 1;
            bool ok = hok && ((unsigned)ww < 3u);
            float v = ok ? pb[hh * 3 + ww] : 0.f;
            acc += wk[ki * 3 + kj] * v;
        }
    }
    out[(size_t)b * 1836 + c * 9 + hw] = pb[hw] * acc;
}

__global__ __launch_bounds__(256)
void crossatt_g(const float* y, const float* t_loc, const float* t_glb,
                const float* s_tloc, const float* s_tglb,
                const float* lg, const float* lb, const float* gg, const float* gb,
                const float* loc_w2, const float* glb_w2, float* out)
{
    dev_crossatt(y, t_loc, t_glb, s_tloc, s_tglb, lg, lb, gg, gb,
                 loc_w2, glb_w2, out, blockIdx.x);
}

// ---------------------------------------------------------------------------
// groups==1 involution (device form).
// ---------------------------------------------------------------------------
__device__ __forceinline__
void dev_invol3(const float* __restrict__ pin, const float* __restrict__ t_raw,
                const float* __restrict__ tstats,
                const float* __restrict__ tg, const float* __restrict__ tb,
                const float* __restrict__ w2,
                float* __restrict__ out, float* __restrict__ ostats,
                int C, int Ct, int bx)
{
    __shared__ float tsc[102], tsh[102];
    const float invN = 1.f / 576.f;
    for (int j = threadIdx.x; j < Ct; j += 256){
        float mean = tstats[j] * invN;
        float var  = tstats[Ct + j] * invN - mean * mean;
        float s = tg[j] * rsqrtf(var + EPS);
        tsc[j] = s; tsh[j] = tb[j] - mean * s;
    }
    __syncthreads();
    int item = bx * 256 + threadIdx.x;
    if (item >= C * 576) return;
    int c = item / 576, pos = item - c * 576;
    int b = pos / 9, hw = pos - b * 9;
    int h = hw / 3, w = hw - h * 3;

    const float* tp = t_raw + (size_t)b * Ct * 9 + hw;
    float wk[9];
    #pragma unroll
    for (int kk = 0; kk < 9; ++kk) wk[kk] = 0.f;
    for (int j = 0; j < Ct; ++j){
        float t = tp[j * 9] * tsc[j] + tsh[j];
        t = t > 0.f ? t : 0.f;
        #pragma unroll
        for (int kk = 0; kk < 9; ++kk) wk[kk] += t * w2[kk * Ct + j];
    }
    const float* pb = pin + (size_t)b * C * 9 + c * 9;
    float acc = 0.f;
    #pragma unroll
    for (int ki = 0; ki < 3; ++ki){
        int hh = h + ki - 1;
        bool hok = (unsigned)hh < 3u;
        #pragma unroll
        for (int kj = 0; kj < 3; ++kj){
            int ww = w + kj - 1;
            bool ok = hok && ((unsigned)ww < 3u);
            float v = ok ? pb[hh * 3 + ww] : 0.f;
            acc += wk[ki * 3 + kj] * v;
        }
    }
    out[(size_t)b * C * 9 + c * 9 + hw] = acc;
    float s1 = acc, s2 = acc * acc;
    wave_red2(s1, s2);
    if ((threadIdx.x & 63) == 0){
        int cu = __builtin_amdgcn_readfirstlane(c);
        atomicAdd(&ostats[cu], s1);
        atomicAdd(&ostats[C + cu], s2);
    }
}

// ---------------------------------------------------------------------------
// BN+ReLU(+residual)->conv1x1 (device form).
// ---------------------------------------------------------------------------
__device__ __forceinline__
void dev_bnconv(const float* __restrict__ in, const float* __restrict__ stats,
                const float* __restrict__ g, const float* __restrict__ bta,
                const float* __restrict__ idn, const float* __restrict__ w,
                float* __restrict__ out, int Cin, int Cout, int bx)
{
    __shared__ float sc[204], sh[204];
    for (int j = threadIdx.x; j < Cin; j += 256){
        const float invN = 1.f / 576.f;
        float mean = stats[j] * invN;
        float var = stats[Cin + j] * invN - mean * mean;
        float s = g[j] * rsqrtf(var + EPS);
        sc[j] = s; sh[j] = bta[j] - mean * s;
    }
    __syncthreads();
    int item = bx * 256 + threadIdx.x;
    if (item >= Cout * 576) return;
    int j = item / 576, pos = item - j * 576;
    int b = pos / 9, hw = pos - b * 9;
    int ju = __builtin_amdgcn_readfirstlane(j);
    const float* ip = in + (size_t)b * Cin * 9 + hw;
    const float* ir = idn ? idn + (size_t)b * Cin * 9 + hw : nullptr;
    const float* wr = w + (size_t)ju * Cin;
    float a0 = 0.f, a1 = 0.f, a2 = 0.f, a3 = 0.f;
    int c = 0;
    #pragma unroll 2
    for (; c + 3 < Cin; c += 4){
        float v0 = ip[c * 9] * sc[c] + sh[c];             v0 = v0 > 0.f ? v0 : 0.f;
        float v1 = ip[(c + 1) * 9] * sc[c + 1] + sh[c + 1]; v1 = v1 > 0.f ? v1 : 0.f;
        float v2 = ip[(c + 2) * 9] * sc[c + 2] + sh[c + 2]; v2 = v2 > 0.f ? v2 : 0.f;
        float v3 = ip[(c + 3) * 9] * sc[c + 3] + sh[c + 3]; v3 = v3 > 0.f ? v3 : 0.f;
        if (ir){
            v0 += ir[c * 9]; v1 += ir[(c + 1) * 9];
            v2 += ir[(c + 2) * 9]; v3 += ir[(c + 3) * 9];
        }
        a0 += v0 * wr[c];
        a1 += v1 * wr[c + 1];
        a2 += v2 * wr[c + 2];
        a3 += v3 * wr[c + 3];
    }
    for (; c < Cin; ++c){
        float v = ip[c * 9] * sc[c] + sh[c];
        v = v > 0.f ? v : 0.f;
        if (ir) v += ir[c * 9];
        a0 += v * wr[c];
    }
    out[(size_t)b * Cout * 9 + j * 9 + hw] = (a0 + a1) + (a2 + a3);
}

// ---------------------------------------------------------------------------
// GlobalCovPooling (device form; math identical).
// ---------------------------------------------------------------------------
template<int C, int N, int TB>
__device__ void dev_covpool(const float* __restrict__ in, float* __restrict__ feat, int b)
{
    __shared__ float X[N * C];
    __shared__ float Ybuf[C * C], Mbuf[C * C], Zbuf[C * C], Z2buf[C * C];
    __shared__ float mu[C];
    __shared__ float scal[2];
    int tid = threadIdx.x;
    const float* ib = in + (size_t)b * C * N;
    for (int i = tid; i < N * C; i += TB){
        int n = i / C, c = i - n * C;
        X[i] = ib[(size_t)c * N + n];
    }
    __syncthreads();
    if (tid < C){
        float s0 = 0.f, s1 = 0.f, s2 = 0.f, s3 = 0.f;
        int n = 0;
        for (; n + 3 < N; n += 4){
            s0 += X[n * C + tid];
            s1 += X[(n + 1) * C + tid];
            s2 += X[(n + 2) * C + tid];
            s3 += X[(n + 3) * C + tid];
        }
        for (; n < N; ++n) s0 += X[n * C + tid];
        mu[tid] = ((s0 + s1) + (s2 + s3)) / (float)N;
    }
    __syncthreads();
    constexpr int CC = C * C;
    for (int i = tid; i < CC; i += TB){
        int c = i / C, d = i - c * C;
        float s0 = 0.f, s1 = 0.f, s2 = 0.f, s3 = 0.f;
        int n = 0;
        for (; n + 3 < N; n += 4){
            s0 += X[n * C + c] * X[n * C + d];
            s1 += X[(n + 1) * C + c] * X[(n + 1) * C + d];
            s2 += X[(n + 2) * C + c] * X[(n + 2) * C + d];
            s3 += X[(n + 3) * C + c] * X[(n + 3) * C + d];
        }
        for (; n < N; ++n) s0 += X[n * C + c] * X[n * C + d];
        Ybuf[i] = ((s0 + s1) + (s2 + s3)) / (float)N - mu[c] * mu[d];
    }
    __syncthreads();
    if (tid == 0){
        float tr = 0.f;
        for (int c = 0; c < C; ++c) tr += Ybuf[c * C + c];
        scal[0] = 1.f / tr;
    }
    __syncthreads();
    for (int i = tid; i < CC; i += TB){
        int c = i / C, d = i - c * C;
        Ybuf[i] *= scal[0];
        Zbuf[i] = (c == d) ? 1.f : 0.f;
    }
    __syncthreads();
    float* zs = Zbuf; float* zd = Z2buf;
    for (int it = 0; it < 6; ++it){
        for (int i = tid; i < CC; i += TB){
            int c = i / C, d = i - c * C;
            float sA = 0.f, sB = 0.f;
            #pragma unroll 3
            for (int e = 0; e < C; e += 2){
                sA += zs[c * C + e] * Ybuf[e * C + d];
                sB += zs[c * C + e + 1] * Ybuf[(e + 1) * C + d];
            }
            Mbuf[i] = ((c == d) ? 3.f : 0.f) - (sA + sB);
        }
        __syncthreads();
        for (int i = tid; i < CC; i += TB){
            int c = i / C, d = i - c * C;
            float sA = 0.f, sB = 0.f;
            #pragma unroll 3
            for (int e = 0; e < C; e += 2){
                sA += Mbuf[c * C + e] * zs[e * C + d];
                sB += Mbuf[c * C + e + 1] * zs[(e + 1) * C + d];
            }
            zd[i] = 0.5f * (sA + sB);
        }
        for (int i = tid; i < CC; i += TB) Ybuf[i] *= 0.5f * Mbuf[i];
        __syncthreads();
        float* t = zs; zs = zd; zd = t;
    }
    if (tid == 0){
        float tr = 0.f;
        for (int c = 0; c < C; ++c) tr += Ybuf[c * C + c];
        scal[1] = sqrtf(tr);
    }
    __syncthreads();
    if (tid < C){
        float s = 0.f;
        #pragma unroll 6
        for (int c = 0; c < C; ++c) s += Ybuf[c * C + tid];
        feat[(size_t)b * C + tid] = scal[1] * s / (float)C;
    }
}

// ===========================================================================
// Paired-step wrappers (only the resource-cheap pairs retained).
// ===========================================================================

// L1: A = branch1 conv1x1 (b0, z=0..2)  ||  B = conv_dual (z=3)
__global__ __launch_bounds__(256)
void step_conv_convdual(const float* xin, const float* w1, float* t_raw, float* st_t,
                        const float* yin, const float* locw1, const float* glbw1,
                        float* t_loc, float* t_glb, float* s_tloc, float* s_tglb)
{
    int z = blockIdx.z, bx = blockIdx.x;
    if (z < 3){
        dev_conv1x1(xin, w1 + z * 450, t_raw + (size_t)z * 216000, st_t + z * 30,
                    30, 15, 225, 64, bx);
    } else {
        int f = bx;
        if (f >= 460) return;
        int zz = f / 230, b2 = f - zz * 230;
        dev_conv1x1(yin, zz ? glbw1 : locw1, zz ? t_glb : t_loc,
                    zz ? s_tglb : s_tloc, 204, 102, 9, 64, b2);
    }
}

// L3/L6/L9: A = blockend  ||  B = branch2 conv1x1 (nB blocks)
__global__ __launch_bounds__(256)
void step_be_conv(const float* o0, const float* o1, const float* o2,
                  const float* s0, const float* s1, const float* s2,
                  const float* g, const float* bb, const float* conv,
                  const float* oldout, float* newout,
                  const float* bin, const float* bw, float* bout, float* bstats,
                  int bCin, int bCout, int nB)
{
    if (blockIdx.z == 0){
        dev_blockend(o0, o1, o2, s0, s1, s2, g, bb, conv, oldout, newout, blockIdx.x);
    } else {
        if ((int)blockIdx.x >= nB) return;
        dev_conv1x1(bin, bw, bout, bstats, bCin, bCout, 9, 64, blockIdx.x);
    }
}

// L4/L7: A = branch1 conv1x1 (z=0..2)  ||  B = invol3 (z=3)
__global__ __launch_bounds__(256)
void step_conv_inv3(const float* cur, const float* w1, float* t_raw, float* st_t,
                    const float* pin, const float* traw2, const float* tst2,
                    const float* tg2, const float* tb2, const float* w2,
                    float* out2, float* ost2, int C, int Ct, int nB)
{
    int z = blockIdx.z, bx = blockIdx.x;
    if (z < 3){
        dev_conv1x1(cur, w1 + z * 450, t_raw + (size_t)z * 216000, st_t + z * 30,
                    30, 15, 225, 64, bx);
    } else {
        if (bx >= nB) return;
        dev_invol3(pin, traw2, tst2, tg2, tb2, w2, out2, ost2, C, Ct, bx);
    }
}

// L10: A = covpool30 (z=0)  ||  B = invol3 c5 (z=1)
__global__ __launch_bounds__(256)
void step_cov_inv3(const float* cin, float* feat,
                   const float* pin, const float* traw2, const float* tst2,
                   const float* tg2, const float* tb2, const float* w2,
                   float* out2, float* ost2, int C, int Ct, int nB)
{
    if (blockIdx.z == 0){
        if (blockIdx.x >= 64) return;
        dev_covpool<30, 225, 256>(cin, feat, blockIdx.x);
    } else {
        if ((int)blockIdx.x >= nB) return;
        dev_invol3(pin, traw2, tst2, tg2, tb2, w2, out2, ost2, C, Ct, blockIdx.x);
    }
}

// Standalone wrappers
__global__ __launch_bounds__(256)
void bnconv_g(const float* in, const float* stats, const float* g, const float* bta,
              const float* idn, const float* w, float* out, int Cin, int Cout)
{
    dev_bnconv(in, stats, g, bta, idn, w, out, Cin, Cout, blockIdx.x);
}

template<int C, int N, int TB>
__global__ __launch_bounds__(TB)
void covpool_g(const float* __restrict__ in, float* __restrict__ feat)
{
    dev_covpool<C, N, TB>(in, feat, blockIdx.x);
}

// ---------------------------------------------------------------------------
// Head: concat feats, BN over batch, ReLU, linear, softmax. Single workgroup.
// ---------------------------------------------------------------------------
__global__ __launch_bounds__(256)
void head_k(const float* __restrict__ feat1, const float* __restrict__ feat2,
            const float* __restrict__ hg, const float* __restrict__ hb,
            const float* __restrict__ lw, const float* __restrict__ lb,
            float* __restrict__ out)
{
    __shared__ float f[46 * 64];
    int tid = threadIdx.x;
    for (int i = tid; i < 46 * 64; i += 256){
        int ch = i / 64, b = i - ch * 64;
        f[i] = ch < 30 ? feat1[b * 30 + ch] : feat2[b * 16 + (ch - 30)];
    }
    __syncthreads();
    if (tid < 46){
        float s = 0.f, s2 = 0.f;
        for (int b = 0; b < 64; ++b){ float v = f[tid * 64 + b]; s += v; s2 += v * v; }
        float mean = s / 64.f, var = s2 / 64.f - mean * mean;
        float sc = hg[tid] * rsqrtf(var + EPS), sh = hb[tid] - mean * sc;
        for (int b = 0; b < 64; ++b){
            float v = f[tid * 64 + b] * sc + sh;
            f[tid * 64 + b] = v > 0.f ? v : 0.f;
        }
    }
    __syncthreads();
    if (tid < 64){
        int b = tid;
        float l[16];
        float m = -1e30f;
        for (int o = 0; o < 16; ++o){
            float a = lb[o];
            for (int ch = 0; ch < 46; ++ch) a += f[ch * 64 + b] * lw[o * 46 + ch];
            l[o] = a; m = fmaxf(m, a);
        }
        float se = 0.f;
        for (int o = 0; o < 16; ++o){ l[o] = expf(l[o] - m); se += l[o]; }
        float inv = 1.f / se;
        for (int o = 0; o < 16; ++o) out[b * 16 + o] = l[o] * inv;
    }
}

extern "C" void kernel_launch(void* const* d_in, const int* in_sizes, int n_in,
                              void* d_out, int out_size, void* d_ws, size_t ws_size,
                              hipStream_t stream)
{
    (void)in_sizes; (void)n_in; (void)out_size; (void)ws_size;
    const float* x        = (const float*)d_in[0];
    const float* y        = (const float*)d_in[1];
    const float* blk_w1   = (const float*)d_in[2];
    const float* blk_ig   = (const float*)d_in[3];
    const float* blk_ib   = (const float*)d_in[4];
    const float* blk_w2_5 = (const float*)d_in[5];
    const float* blk_w2_7 = (const float*)d_in[6];
    const float* blk_w2_9 = (const float*)d_in[7];
    const float* blk_g    = (const float*)d_in[8];
    const float* blk_b    = (const float*)d_in[9];
    const float* blk_conv = (const float*)d_in[10];
    const float* loc_w1 = (const float*)d_in[11];
    const float* loc_g  = (const float*)d_in[12];
    const float* loc_b  = (const float*)d_in[13];
    const float* loc_w2 = (const float*)d_in[14];
    const float* glb_w1 = (const float*)d_in[15];
    const float* glb_g  = (const float*)d_in[16];
    const float* glb_b  = (const float*)d_in[17];
    const float* glb_w2 = (const float*)d_in[18];
    const float* c3_w1 = (const float*)d_in[19];
    const float* c3_g  = (const float*)d_in[20];
    const float* c3_b  = (const float*)d_in[21];
    const float* c3_w2 = (const float*)d_in[22];
    const float* c4_w1 = (const float*)d_in[23];
    const float* c4_g  = (const float*)d_in[24];
    const float* c4_b  = (const float*)d_in[25];
    const float* c4_w2 = (const float*)d_in[26];
    const float* c5_w1 = (const float*)d_in[27];
    const float* c5_g  = (const float*)d_in[28];
    const float* c5_b  = (const float*)d_in[29];
    const float* c5_w2 = (const float*)d_in[30];
    const float* p1 = (const float*)d_in[31];
    const float* p2 = (const float*)d_in[32];
    const float* p3 = (const float*)d_in[33];
    const float* bn1g = (const float*)d_in[34];
    const float* bn1b = (const float*)d_in[35];
    const float* bn2g = (const float*)d_in[36];
    const float* bn2b = (const float*)d_in[37];
    const float* bn3g = (const float*)d_in[38];
    const float* bn3b = (const float*)d_in[39];
    const float* hg = (const float*)d_in[40];
    const float* hb = (const float*)d_in[41];
    const float* lw = (const float*)d_in[42];
    const float* lb = (const float*)d_in[43];

    float* ws = (float*)d_ws;
    size_t off = 0;
    auto alloc = [&](size_t n){ float* p = ws + off; off += n; return p; };
    float* bufA    = alloc(432000);
    float* bufB    = alloc(432000);
    float* scratch = alloc(1944000);   // branch1 only: t_raw(3) + o_raw(3)
    float* b2ws    = alloc(650000);    // branch2 DEDICATED region (needs 640512)
    float* feat1   = alloc(64 * 30);
    float* feat2   = alloc(64 * 16);
    float* stats   = alloc(2288);

    float* t_raw = scratch;            // 3 x 216000
    float* o_raw = scratch + 648000;   // 3 x 432000

    // branch2 buffers inside b2ws (sizes = C*576 of each producer)
    float* t_loc = b2ws;               // 58752
    float* t_glb = t_loc + 58752;      // 58752
    float* o_idn = t_glb + 58752;      // 117504
    float* t3    = o_idn + 117504;     // 58752
    float* o3    = t3 + 58752;         // 117504
    float* o5    = o3 + 117504;        // 58752
    float* t4    = o5 + 58752;         // 29376
    float* o6    = t4 + 29376;         // 58752
    float* o8    = o6 + 58752;         // 29376
    float* t5    = o8 + 29376;         // 14400
    float* o9    = t5 + 14400;         // 29376
    float* o11   = o9 + 29376;         // 9216

    float* s_tloc = stats + 810;
    float* s_tglb = s_tloc + 204;
    float* s_t3   = s_tglb + 204;
    float* s_o3   = s_t3 + 204;
    float* s_t4   = s_o3 + 408;
    float* s_o6   = s_t4 + 102;
    float* s_t5   = s_o6 + 204;
    float* s_o9   = s_t5 + 50;

    hipMemsetAsync(stats, 0, 2288 * sizeof(float), stream);

    // L1: conv(b0) || conv_dual
    step_conv_convdual<<<dim3(844, 1, 4), 256, 0, stream>>>(
        x, blk_w1, t_raw, stats, y, loc_w1, glb_w1, t_loc, t_glb, s_tloc, s_tglb);
    // L2a: merged invol (b0) — standalone, own VGPR budget
    invol_b1m<<<dim3(64, 2, 3), 256, 0, stream>>>(
        x, t_raw, stats, blk_ig, blk_ib, blk_w2_5, blk_w2_7, blk_w2_9,
        o_raw, stats + 270);
    // L2b: crossatt — standalone
    crossatt_g<<<459, 256, 0, stream>>>(
        y, t_loc, t_glb, s_tloc, s_tglb, loc_g, loc_b, glb_g, glb_b,
        loc_w2, glb_w2, o_idn);
    // L3: blockend(b0: x->bufA) || conv(c3)
    step_be_conv<<<dim3(1688, 1, 2), 256, 0, stream>>>(
        o_raw, o_raw + 432000, o_raw + 864000,
        stats + 270, stats + 330, stats + 390,
        blk_g, blk_b, blk_conv, x, bufA,
        o_idn, c3_w1, t3, s_t3, 204, 102, 230);
    // L4: conv(b1) || invol3(c3)
    step_conv_inv3<<<dim3(844, 1, 4), 256, 0, stream>>>(
        bufA, blk_w1 + 1350, t_raw, stats + 90,
        o_idn, t3, s_t3, c3_g, c3_b, c3_w2, o3, s_o3, 204, 102, 459);
    // L5a: merged invol (b1)
    invol_b1m<<<dim3(64, 2, 3), 256, 0, stream>>>(
        bufA, t_raw, stats + 90, blk_ig + 45, blk_ib + 45,
        blk_w2_5 + 750, blk_w2_7 + 1470, blk_w2_9 + 2430,
        o_raw, stats + 450);
    // L5b: bnconv(c3)
    bnconv_g<<<230, 256, 0, stream>>>(o3, s_o3, bn1g, bn1b, o_idn, p1, o5, 204, 102);
    // L6: blockend(b1: bufA->bufB) || conv(c4)
    step_be_conv<<<dim3(1688, 1, 2), 256, 0, stream>>>(
        o_raw, o_raw + 432000, o_raw + 864000,
        stats + 450, stats + 510, stats + 570,
        blk_g + 90, blk_b + 90, blk_conv + 2700, bufA, bufB,
        o5, c4_w1, t4, s_t4, 102, 51, 115);
    // L7: conv(b2) || invol3(c4)
    step_conv_inv3<<<dim3(844, 1, 4), 256, 0, stream>>>(
        bufB, blk_w1 + 2700, t_raw, stats + 180,
        o5, t4, s_t4, c4_g, c4_b, c4_w2, o6, s_o6, 102, 51, 230);
    // L8a: merged invol (b2)
    invol_b1m<<<dim3(64, 2, 3), 256, 0, stream>>>(
        bufB, t_raw, stats + 180, blk_ig + 90, blk_ib + 90,
        blk_w2_5 + 1500, blk_w2_7 + 2940, blk_w2_9 + 4860,
        o_raw, stats + 630);
    // L8b: bnconv(c4)
    bnconv_g<<<115, 256, 0, stream>>>(o6, s_o6, bn2g, bn2b, nullptr, p2, o8, 102, 51);
    // L9: blockend(b2: bufB->bufA) || conv(c5)
    step_be_conv<<<dim3(1688, 1, 2), 256, 0, stream>>>(
        o_raw, o_raw + 432000, o_raw + 864000,
        stats + 630, stats + 690, stats + 750,
        blk_g + 180, blk_b + 180, blk_conv + 5400, bufB, bufA,
        o8, c5_w1, t5, s_t5, 51, 25, 57);
    // L10: covpool1(bufA) || invol3(c5)
    step_cov_inv3<<<dim3(115, 1, 2), 256, 0, stream>>>(
        bufA, feat1,
        o8, t5, s_t5, c5_g, c5_b, c5_w2, o9, s_o9, 51, 25, 115);
    // L11: bnconv(c5)
    bnconv_g<<<36, 256, 0, stream>>>(o9, s_o9, bn3g, bn3b, o8, p3, o11, 51, 16);
    // L12: covpool2
    covpool_g<16, 9, 256><<<64, 256, 0, stream>>>(o11, feat2);
    // L13: head
    head_k<<<1, 256, 0, stream>>>(feat1, feat2, hg, hb, lw, lb, (float*)d_out);
}

// Round 11
// 1053.918 us; speedup vs baseline: 1.2773x; 1.0480x over previous
//
#include <hip/hip_runtime.h>
#include <math.h>

#define EPS 1e-5f

__device__ inline void wave_red2(float& s1, float& s2){
    for (int off = 32; off; off >>= 1){
        s1 += __shfl_down(s1, off, 64);
        s2 += __shfl_down(s2, off, 64);
    }
}

// ---------------------------------------------------------------------------
// conv1x1 + optional stats (generic device form, unchanged — branch-2 users).
// ---------------------------------------------------------------------------
__device__ __forceinline__
void dev_conv1x1(const float* __restrict__ in, const float* __restrict__ w,
                 float* __restrict__ out, float* __restrict__ stats,
                 int Cin, int Cout, int HW, int B, int bx)
{
    int npos = B * HW;
    int total = Cout * npos;
    int item = bx * 256 + threadIdx.x;
    if (item >= total) return;
    int j = item / npos;
    int pos = item - j * npos;
    int b = pos / HW, hw = pos - b * HW;
    int ju = __builtin_amdgcn_readfirstlane(j);
    const float* ip = in + (size_t)b * Cin * HW + hw;
    const float* wr = w + (size_t)ju * Cin;
    float a0 = 0.f, a1 = 0.f, a2 = 0.f, a3 = 0.f;
    int c = 0;
    #pragma unroll 2
    for (; c + 3 < Cin; c += 4){
        a0 += ip[(size_t)c * HW] * wr[c];
        a1 += ip[(size_t)(c + 1) * HW] * wr[c + 1];
        a2 += ip[(size_t)(c + 2) * HW] * wr[c + 2];
        a3 += ip[(size_t)(c + 3) * HW] * wr[c + 3];
    }
    for (; c < Cin; ++c) a0 += ip[(size_t)c * HW] * wr[c];
    float acc = (a0 + a1) + (a2 + a3);
    out[(size_t)b * Cout * HW + (size_t)j * HW + hw] = acc;
    if (stats){
        float s1 = acc, s2 = acc * acc;
        wave_red2(s1, s2);
        if ((threadIdx.x & 63) == 0){
            atomicAdd(&stats[ju], s1);
            atomicAdd(&stats[Cout + ju], s2);
        }
    }
}

// ---------------------------------------------------------------------------
// Branch-1 conv1x1, 3 OUTPUTS PER THREAD (round 11): Cin=30, Cout=15, HW=225,
// B=64. All 15 j's read the same 30 inputs; a thread computes j = jg*3..+2
// sharing its 30 loads. Per-output 4-partial structure and c-assignment are
// replicated from the original -> bit-exact per output. Waves cover 64
// consecutive pos within one jg (14400%64==0) -> stats partial-sum sets
// identical to the 1-output version.
// Grid: 5 jgroups * 14400 / 256 = 282 blocks (was 844). 3x fewer waves,
// 3x fewer loads per output.
// ---------------------------------------------------------------------------
__device__ __forceinline__
void dev_conv_b1_m3(const float* __restrict__ in, const float* __restrict__ w,
                    float* __restrict__ out, float* __restrict__ stats, int bx)
{
    int item = bx * 256 + threadIdx.x;
    if (item >= 72000) return;
    int jg = item / 14400;
    int pos = item - jg * 14400;
    int b = pos / 225, hw = pos - b * 225;
    int jgu = __builtin_amdgcn_readfirstlane(jg);
    const float* ip = in + (size_t)b * 6750 + hw;
    const float* w0 = w + (size_t)(jgu * 3) * 30;
    const float* w1 = w0 + 30;
    const float* w2 = w0 + 60;

    float a00=0.f,a01=0.f,a02=0.f,a03=0.f;
    float a10=0.f,a11=0.f,a12=0.f,a13=0.f;
    float a20=0.f,a21=0.f,a22=0.f,a23=0.f;
    int c = 0;
    #pragma unroll 2
    for (; c + 3 < 30; c += 4){
        float v0 = ip[(size_t)c * 225];
        float v1 = ip[(size_t)(c + 1) * 225];
        float v2 = ip[(size_t)(c + 2) * 225];
        float v3 = ip[(size_t)(c + 3) * 225];
        a00 += v0 * w0[c];     a01 += v1 * w0[c + 1];
        a02 += v2 * w0[c + 2]; a03 += v3 * w0[c + 3];
        a10 += v0 * w1[c];     a11 += v1 * w1[c + 1];
        a12 += v2 * w1[c + 2]; a13 += v3 * w1[c + 3];
        a20 += v0 * w2[c];     a21 += v1 * w2[c + 1];
        a22 += v2 * w2[c + 2]; a23 += v3 * w2[c + 3];
    }
    for (; c < 30; ++c){
        float v = ip[(size_t)c * 225];
        a00 += v * w0[c];
        a10 += v * w1[c];
        a20 += v * w2[c];
    }
    float acc0 = (a00 + a01) + (a02 + a03);
    float acc1 = (a10 + a11) + (a12 + a13);
    float acc2 = (a20 + a21) + (a22 + a23);

    float* ob = out + (size_t)b * 3375 + (size_t)(jg * 3) * 225 + hw;
    ob[0]   = acc0;
    ob[225] = acc1;
    ob[450] = acc2;

    float accs[3] = {acc0, acc1, acc2};
    #pragma unroll
    for (int q = 0; q < 3; ++q){
        float s1 = accs[q], s2 = accs[q] * accs[q];
        wave_red2(s1, s2);
        if ((threadIdx.x & 63) == 0){
            atomicAdd(&stats[jgu * 3 + q], s1);
            atomicAdd(&stats[15 + jgu * 3 + q], s2);
        }
    }
}

// ---------------------------------------------------------------------------
// Branch-1 fused involution, merged halves (unchanged from round 10).
// ---------------------------------------------------------------------------
template<int K>
__device__ void dev_invol_b1_full(const float* __restrict__ in, const float* __restrict__ t_raw,
                                  const float* __restrict__ tstats,
                                  const float* __restrict__ tg, const float* __restrict__ tb,
                                  const float* __restrict__ w2,
                                  float* __restrict__ o_raw, float* __restrict__ ostats,
                                  float* lds, int b, int g)
{
    constexpr int KK = K * K, P = (K - 1) / 2;
    float* in_s = lds;            // 15*225 = 3375
    float* scb  = lds + 3375;     // 15
    float* shb  = lds + 3390;     // 15
    int tid = threadIdx.x;

    if (tid < 15){
        const float invN = 1.f / 14400.f;
        float mean = tstats[tid] * invN;
        float var  = tstats[15 + tid] * invN - mean * mean;
        float s = tg[tid] * rsqrtf(var + EPS);
        scb[tid] = s; shb[tid] = tb[tid] - mean * s;
    }
    const float* w2g = w2 + (size_t)g * KK * 15;   // block-uniform base
    const float* inb = in + (size_t)b * 6750 + (size_t)g * 15 * 225;
    for (int i = tid; i < 3375; i += 256) in_s[i] = inb[i];
    __syncthreads();

    bool act = tid < 225;
    int p = act ? tid : 224;
    int h = p / 15, w = p - h * 15;

    float treg[15];
    const float* trb = t_raw + (size_t)b * 3375 + p;
    #pragma unroll
    for (int j = 0; j < 15; ++j){
        float v = trb[j * 225] * scb[j] + shb[j];
        treg[j] = v > 0.f ? v : 0.f;
    }

    float acc[15];
    #pragma unroll
    for (int cc = 0; cc < 15; ++cc) acc[cc] = 0.f;

    for (int ki = 0; ki < K; ++ki){
        int hh = h + ki - P;
        bool hok = (unsigned)hh < 15u;
        const float* w2row = w2g + ki * K * 15;
        #pragma unroll
        for (int kj0 = 0; kj0 < K; kj0 += 3){
            const float* wr = w2row + kj0 * 15;
            float a0 = 0.f, a1 = 0.f, a2 = 0.f;
            #pragma unroll
            for (int j = 0; j < 15; ++j){
                float tv = treg[j];
                a0 += tv * wr[j];
                if (kj0 + 1 < K) a1 += tv * wr[15 + j];
                if (kj0 + 2 < K) a2 += tv * wr[30 + j];
            }
            float wv[3] = {a0, a1, a2};
            #pragma unroll
            for (int t = 0; t < 3; ++t){
                int kj = kj0 + t;
                if (kj >= K) break;
                int ww = w + kj - P;
                bool ok = hok && ((unsigned)ww < 15u);
                float sc2 = ok ? wv[t] : 0.f;
                int offr = ok ? hh * 15 + ww : 0;
                #pragma unroll
                for (int cc = 0; cc < 15; ++cc) acc[cc] += sc2 * in_s[cc * 225 + offr];
            }
        }
    }

    float* ob = o_raw + (size_t)b * 6750 + (size_t)g * 15 * 225;
    #pragma unroll
    for (int cc = 0; cc < 15; ++cc){
        float val = act ? acc[cc] : 0.f;
        if (act) ob[cc * 225 + p] = val;
        float s1 = val, s2 = val * val;
        wave_red2(s1, s2);
        if ((tid & 63) == 0){
            atomicAdd(&ostats[g * 15 + cc], s1);
            atomicAdd(&ostats[30 + g * 15 + cc], s2);
        }
    }
}

__global__ __launch_bounds__(256)
void invol_b1m(const float* __restrict__ in, const float* __restrict__ t_raw3,
               const float* __restrict__ tstats3,
               const float* __restrict__ tg3, const float* __restrict__ tb3,
               const float* __restrict__ w2_5, const float* __restrict__ w2_7,
               const float* __restrict__ w2_9,
               float* __restrict__ o_raw3, float* __restrict__ ostats3)
{
    __shared__ float lds[3405];
    int b = blockIdx.x, g = blockIdx.y, ii = blockIdx.z;
    if (ii == 0)
        dev_invol_b1_full<5>(in, t_raw3,          tstats3,      tg3,      tb3,      w2_5, o_raw3,          ostats3,       lds, b, g);
    else if (ii == 1)
        dev_invol_b1_full<7>(in, t_raw3 + 216000, tstats3 + 30, tg3 + 15, tb3 + 15, w2_7, o_raw3 + 432000, ostats3 + 60,  lds, b, g);
    else
        dev_invol_b1_full<9>(in, t_raw3 + 432000, tstats3 + 60, tg3 + 30, tb3 + 30, w2_9, o_raw3 + 864000, ostats3 + 120, lds, b, g);
}

// ---------------------------------------------------------------------------
// blockend, 3 OUTPUTS PER THREAD (round 11): the 90 BN'd values v are
// identical for all 30 output channels; a thread computes c = cg*3..+2
// sharing the 90 loads + BN/ReLU. Per-output (sA,sB) pairing and ii order
// replicated exactly -> bit-exact. Grid: 10 cgroups * 14400 / 256 = 563
// blocks (was 1688).
// ---------------------------------------------------------------------------
__device__ __forceinline__
void dev_blockend_m3(const float* __restrict__ o0, const float* __restrict__ o1,
                     const float* __restrict__ o2,
                     const float* __restrict__ s0, const float* __restrict__ s1,
                     const float* __restrict__ s2,
                     const float* __restrict__ g, const float* __restrict__ bb,
                     const float* __restrict__ conv,
                     const float* __restrict__ oldout, float* __restrict__ newout, int bx)
{
    __shared__ float sc[90], sh[90];
    int tid = threadIdx.x;
    if (tid < 90){
        int ii = tid / 30, cc = tid - ii * 30;
        const float* st = ii == 0 ? s0 : (ii == 1 ? s1 : s2);
        const float invN = 1.f / 14400.f;
        float mean = st[cc] * invN;
        float var = st[30 + cc] * invN - mean * mean;
        float s = g[tid] * rsqrtf(var + EPS);
        sc[tid] = s; sh[tid] = bb[tid] - mean * s;
    }
    __syncthreads();
    int item = bx * 256 + tid;
    if (item >= 144000) return;
    int cg = item / 14400, pos = item - cg * 14400;
    int b = pos / 225, hw = pos - b * 225;
    int cgu = __builtin_amdgcn_readfirstlane(cg);
    const float* cr0 = conv + (size_t)(cgu * 3) * 90;
    const float* cr1 = cr0 + 90;
    const float* cr2 = cr0 + 180;
    const float* ol = oldout + (size_t)b * 6750 + (size_t)(cg * 3) * 225 + hw;
    float acc0 = ol[0], acc1 = ol[225], acc2 = ol[450];
    const float* bases[3] = {o0, o1, o2};
    #pragma unroll
    for (int ii = 0; ii < 3; ++ii){
        const float* op = bases[ii] + (size_t)b * 6750 + hw;
        float sA0 = 0.f, sB0 = 0.f, sA1 = 0.f, sB1 = 0.f, sA2 = 0.f, sB2 = 0.f;
        #pragma unroll 5
        for (int cc = 0; cc < 30; cc += 2){
            float v = op[cc * 225] * sc[ii * 30 + cc] + sh[ii * 30 + cc];
            v = v > 0.f ? v : 0.f;
            float v2 = op[(cc + 1) * 225] * sc[ii * 30 + cc + 1] + sh[ii * 30 + cc + 1];
            v2 = v2 > 0.f ? v2 : 0.f;
            sA0 += v * cr0[ii * 30 + cc];  sB0 += v2 * cr0[ii * 30 + cc + 1];
            sA1 += v * cr1[ii * 30 + cc];  sB1 += v2 * cr1[ii * 30 + cc + 1];
            sA2 += v * cr2[ii * 30 + cc];  sB2 += v2 * cr2[ii * 30 + cc + 1];
        }
        acc0 += sA0 + sB0;
        acc1 += sA1 + sB1;
        acc2 += sA2 + sB2;
    }
    float* nb = newout + (size_t)b * 6750 + (size_t)(cg * 3) * 225 + hw;
    nb[0]   = acc0;
    nb[225] = acc1;
    nb[450] = acc2;
}

// ---------------------------------------------------------------------------
// cross-attention front (device form, unchanged).
// ---------------------------------------------------------------------------
__device__ __forceinline__
void dev_crossatt(const float* __restrict__ y,
                  const float* __restrict__ t_loc, const float* __restrict__ t_glb,
                  const float* __restrict__ s_tloc, const float* __restrict__ s_tglb,
                  const float* __restrict__ lg, const float* __restrict__ lb,
                  const float* __restrict__ gg, const float* __restrict__ gb,
                  const float* __restrict__ loc_w2, const float* __restrict__ glb_w2,
                  float* __restrict__ out, int bx)
{
    __shared__ float lsc[102], lsh[102], gsc[102], gsh[102];
    const float invN = 1.f / 576.f;
    for (int j = threadIdx.x; j < 102; j += 256){
        float m1 = s_tloc[j] * invN;
        float v1 = s_tloc[102 + j] * invN - m1 * m1;
        float a1 = lg[j] * rsqrtf(v1 + EPS);
        lsc[j] = a1; lsh[j] = lb[j] - m1 * a1;
        float m2 = s_tglb[j] * invN;
        float v2 = s_tglb[102 + j] * invN - m2 * m2;
        float a2 = gg[j] * rsqrtf(v2 + EPS);
        gsc[j] = a2; gsh[j] = gb[j] - m2 * a2;
    }
    __syncthreads();
    int item = bx * 256 + threadIdx.x;
    if (item >= 204 * 576) return;
    int c = item / 576, pos = item - c * 576;
    int b = pos / 9, hw = pos - b * 9;
    int h = hw / 3, w = hw - h * 3;
    int cu = __builtin_amdgcn_readfirstlane(c);

    const float* tl = t_loc + (size_t)b * 918 + hw;
    const float* tg_ = t_glb + (size_t)b * 918 + hw;
    const float* wl = loc_w2 + (size_t)cu * 918;
    float wk[9];
    #pragma unroll
    for (int kk = 0; kk < 9; ++kk) wk[kk] = 0.f;
    for (int j = 0; j < 102; ++j){
        float a = tl[j * 9] * lsc[j] + lsh[j];
        a = a > 0.f ? a : 0.f;
        float g2 = tg_[j * 9] * gsc[j] + gsh[j];
        g2 = g2 > 0.f ? g2 : 0.f;
        #pragma unroll
        for (int kk = 0; kk < 9; ++kk)
            wk[kk] += a * wl[kk * 102 + j] + g2 * glb_w2[kk * 102 + j];
    }
    const float* pb = y + (size_t)b * 1836 + c * 9;
    float acc = 0.f;
    #pragma unroll
    for (int ki = 0; ki < 3; ++ki){
        int hh = h + ki - 1;
        bool hok = (unsigned)hh < 3u;
        #pragma unroll
        for (int kj = 0; kj < 3; ++kj){
            int ww = w + kj - 1;
            bool ok = hok && ((unsigned)ww < 3u);
            float v = ok ? pb[hh * 3 + ww] : 0.f;
            acc += wk[ki * 3 + kj] * v;
        }
    }
    out[(size_t)b * 1836 + c * 9 + hw] = pb[hw] * acc;
}

__global__ __launch_bounds__(256)
void crossatt_g(const float* y, const float* t_loc, const float* t_glb,
                const float* s_tloc, const float* s_tglb,
                const float* lg, const float* lb, const float* gg, const float* gb,
                const float* loc_w2, const float* glb_w2, float* out)
{
    dev_crossatt(y, t_loc, t_glb, s_tloc, s_tglb, lg, lb, gg, gb,
                 loc_w2, glb_w2, out, blockIdx.x);
}

// ---------------------------------------------------------------------------
// groups==1 involution (device form, unchanged).
// ---------------------------------------------------------------------------
__device__ __forceinline__
void dev_invol3(const float* __restrict__ pin, const float* __restrict__ t_raw,
                const float* __restrict__ tstats,
                const float* __restrict__ tg, const float* __restrict__ tb,
                const float* __restrict__ w2,
                float* __restrict__ out, float* __restrict__ ostats,
                int C, int Ct, int bx)
{
    __shared__ float tsc[102], tsh[102];
    const float invN = 1.f / 576.f;
    for (int j = threadIdx.x; j < Ct; j += 256){
        float mean = tstats[j] * invN;
        float var  = tstats[Ct + j] * invN - mean * mean;
        float s = tg[j] * rsqrtf(var + EPS);
        tsc[j] = s; tsh[j] = tb[j] - mean * s;
    }
    __syncthreads();
    int item = bx * 256 + threadIdx.x;
    if (item >= C * 576) return;
    int c = item / 576, pos = item - c * 576;
    int b = pos / 9, hw = pos - b * 9;
    int h = hw / 3, w = hw - h * 3;

    const float* tp = t_raw + (size_t)b * Ct * 9 + hw;
    float wk[9];
    #pragma unroll
    for (int kk = 0; kk < 9; ++kk) wk[kk] = 0.f;
    for (int j = 0; j < Ct; ++j){
        float t = tp[j * 9] * tsc[j] + tsh[j];
        t = t > 0.f ? t : 0.f;
        #pragma unroll
        for (int kk = 0; kk < 9; ++kk) wk[kk] += t * w2[kk * Ct + j];
    }
    const float* pb = pin + (size_t)b * C * 9 + c * 9;
    float acc = 0.f;
    #pragma unroll
    for (int ki = 0; ki < 3; ++ki){
        int hh = h + ki - 1;
        bool hok = (unsigned)hh < 3u;
        #pragma unroll
        for (int kj = 0; kj < 3; ++kj){
            int ww = w + kj - 1;
            bool ok = hok && ((unsigned)ww < 3u);
            float v = ok ? pb[hh * 3 + ww] : 0.f;
            acc += wk[ki * 3 + kj] * v;
        }
    }
    out[(size_t)b * C * 9 + c * 9 + hw] = acc;
    float s1 = acc, s2 = acc * acc;
    wave_red2(s1, s2);
    if ((threadIdx.x & 63) == 0){
        int cu = __builtin_amdgcn_readfirstlane(c);
        atomicAdd(&ostats[cu], s1);
        atomicAdd(&ostats[C + cu], s2);
    }
}

// ---------------------------------------------------------------------------
// BN+ReLU(+residual)->conv1x1 (device form, unchanged).
// ---------------------------------------------------------------------------
__device__ __forceinline__
void dev_bnconv(const float* __restrict__ in, const float* __restrict__ stats,
                const float* __restrict__ g, const float* __restrict__ bta,
                const float* __restrict__ idn, const float* __restrict__ w,
                float* __restrict__ out, int Cin, int Cout, int bx)
{
    __shared__ float sc[204], sh[204];
    for (int j = threadIdx.x; j < Cin; j += 256){
        const float invN = 1.f / 576.f;
        float mean = stats[j] * invN;
        float var = stats[Cin + j] * invN - mean * mean;
        float s = g[j] * rsqrtf(var + EPS);
        sc[j] = s; sh[j] = bta[j] - mean * s;
    }
    __syncthreads();
    int item = bx * 256 + threadIdx.x;
    if (item >= Cout * 576) return;
    int j = item / 576, pos = item - j * 576;
    int b = pos / 9, hw = pos - b * 9;
    int ju = __builtin_amdgcn_readfirstlane(j);
    const float* ip = in + (size_t)b * Cin * 9 + hw;
    const float* ir = idn ? idn + (size_t)b * Cin * 9 + hw : nullptr;
    const float* wr = w + (size_t)ju * Cin;
    float a0 = 0.f, a1 = 0.f, a2 = 0.f, a3 = 0.f;
    int c = 0;
    #pragma unroll 2
    for (; c + 3 < Cin; c += 4){
        float v0 = ip[c * 9] * sc[c] + sh[c];             v0 = v0 > 0.f ? v0 : 0.f;
        float v1 = ip[(c + 1) * 9] * sc[c + 1] + sh[c + 1]; v1 = v1 > 0.f ? v1 : 0.f;
        float v2 = ip[(c + 2) * 9] * sc[c + 2] + sh[c + 2]; v2 = v2 > 0.f ? v2 : 0.f;
        float v3 = ip[(c + 3) * 9] * sc[c + 3] + sh[c + 3]; v3 = v3 > 0.f ? v3 : 0.f;
        if (ir){
            v0 += ir[c * 9]; v1 += ir[(c + 1) * 9];
            v2 += ir[(c + 2) * 9]; v3 += ir[(c + 3) * 9];
        }
        a0 += v0 * wr[c];
        a1 += v1 * wr[c + 1];
        a2 += v2 * wr[c + 2];
        a3 += v3 * wr[c + 3];
    }
    for (; c < Cin; ++c){
        float v = ip[c * 9] * sc[c] + sh[c];
        v = v > 0.f ? v : 0.f;
        if (ir) v += ir[c * 9];
        a0 += v * wr[c];
    }
    out[(size_t)b * Cout * 9 + j * 9 + hw] = (a0 + a1) + (a2 + a3);
}

// ---------------------------------------------------------------------------
// GlobalCovPooling (device form; unchanged).
// ---------------------------------------------------------------------------
template<int C, int N, int TB>
__device__ void dev_covpool(const float* __restrict__ in, float* __restrict__ feat, int b)
{
    __shared__ float X[N * C];
    __shared__ float Ybuf[C * C], Mbuf[C * C], Zbuf[C * C], Z2buf[C * C];
    __shared__ float mu[C];
    __shared__ float scal[2];
    int tid = threadIdx.x;
    const float* ib = in + (size_t)b * C * N;
    for (int i = tid; i < N * C; i += TB){
        int n = i / C, c = i - n * C;
        X[i] = ib[(size_t)c * N + n];
    }
    __syncthreads();
    if (tid < C){
        float s0 = 0.f, s1 = 0.f, s2 = 0.f, s3 = 0.f;
        int n = 0;
        for (; n + 3 < N; n += 4){
            s0 += X[n * C + tid];
            s1 += X[(n + 1) * C + tid];
            s2 += X[(n + 2) * C + tid];
            s3 += X[(n + 3) * C + tid];
        }
        for (; n < N; ++n) s0 += X[n * C + tid];
        mu[tid] = ((s0 + s1) + (s2 + s3)) / (float)N;
    }
    __syncthreads();
    constexpr int CC = C * C;
    for (int i = tid; i < CC; i += TB){
        int c = i / C, d = i - c * C;
        float s0 = 0.f, s1 = 0.f, s2 = 0.f, s3 = 0.f;
        int n = 0;
        for (; n + 3 < N; n += 4){
            s0 += X[n * C + c] * X[n * C + d];
            s1 += X[(n + 1) * C + c] * X[(n + 1) * C + d];
            s2 += X[(n + 2) * C + c] * X[(n + 2) * C + d];
            s3 += X[(n + 3) * C + c] * X[(n + 3) * C + d];
        }
        for (; n < N; ++n) s0 += X[n * C + c] * X[n * C + d];
        Ybuf[i] = ((s0 + s1) + (s2 + s3)) / (float)N - mu[c] * mu[d];
    }
    __syncthreads();
    if (tid == 0){
        float tr = 0.f;
        for (int c = 0; c < C; ++c) tr += Ybuf[c * C + c];
        scal[0] = 1.f / tr;
    }
    __syncthreads();
    for (int i = tid; i < CC; i += TB){
        int c = i / C, d = i - c * C;
        Ybuf[i] *= scal[0];
        Zbuf[i] = (c == d) ? 1.f : 0.f;
    }
    __syncthreads();
    float* zs = Zbuf; float* zd = Z2buf;
    for (int it = 0; it < 6; ++it){
        for (int i = tid; i < CC; i += TB){
            int c = i / C, d = i - c * C;
            float sA = 0.f, sB = 0.f;
            #pragma unroll 3
            for (int e = 0; e < C; e += 2){
                sA += zs[c * C + e] * Ybuf[e * C + d];
                sB += zs[c * C + e + 1] * Ybuf[(e + 1) * C + d];
            }
            Mbuf[i] = ((c == d) ? 3.f : 0.f) - (sA + sB);
        }
        __syncthreads();
        for (int i = tid; i < CC; i += TB){
            int c = i / C, d = i - c * C;
            float sA = 0.f, sB = 0.f;
            #pragma unroll 3
            for (int e = 0; e < C; e += 2){
                sA += Mbuf[c * C + e] * zs[e * C + d];
                sB += Mbuf[c * C + e + 1] * zs[(e + 1) * C + d];
            }
            zd[i] = 0.5f * (sA + sB);
        }
        for (int i = tid; i < CC; i += TB) Ybuf[i] *= 0.5f * Mbuf[i];
        __syncthreads();
        float* t = zs; zs = zd; zd = t;
    }
    if (tid == 0){
        float tr = 0.f;
        for (int c = 0; c < C; ++c) tr += Ybuf[c * C + c];
        scal[1] = sqrtf(tr);
    }
    __syncthreads();
    if (tid < C){
        float s = 0.f;
        #pragma unroll 6
        for (int c = 0; c < C; ++c) s += Ybuf[c * C + tid];
        feat[(size_t)b * C + tid] = scal[1] * s / (float)C;
    }
}

// ===========================================================================
// Paired-step wrappers.
// ===========================================================================

// L1: A = branch1 conv m3 (z=0..2, 282 blocks)  ||  B = conv_dual (z=3)
__global__ __launch_bounds__(256)
void step_conv_convdual(const float* xin, const float* w1, float* t_raw, float* st_t,
                        const float* yin, const float* locw1, const float* glbw1,
                        float* t_loc, float* t_glb, float* s_tloc, float* s_tglb)
{
    int z = blockIdx.z, bx = blockIdx.x;
    if (z < 3){
        if (bx >= 282) return;
        dev_conv_b1_m3(xin, w1 + z * 450, t_raw + (size_t)z * 216000, st_t + z * 30, bx);
    } else {
        int f = bx;
        if (f >= 460) return;
        int zz = f / 230, b2 = f - zz * 230;
        dev_conv1x1(yin, zz ? glbw1 : locw1, zz ? t_glb : t_loc,
                    zz ? s_tglb : s_tloc, 204, 102, 9, 64, b2);
    }
}

// L3/L6/L9: A = blockend m3 (563 blocks)  ||  B = branch2 conv1x1 (nB blocks)
__global__ __launch_bounds__(256)
void step_be_conv(const float* o0, const float* o1, const float* o2,
                  const float* s0, const float* s1, const float* s2,
                  const float* g, const float* bb, const float* conv,
                  const float* oldout, float* newout,
                  const float* bin, const float* bw, float* bout, float* bstats,
                  int bCin, int bCout, int nB)
{
    if (blockIdx.z == 0){
        dev_blockend_m3(o0, o1, o2, s0, s1, s2, g, bb, conv, oldout, newout, blockIdx.x);
    } else {
        if ((int)blockIdx.x >= nB) return;
        dev_conv1x1(bin, bw, bout, bstats, bCin, bCout, 9, 64, blockIdx.x);
    }
}

// L4/L7: A = branch1 conv m3 (z=0..2, 282 blocks)  ||  B = invol3 (z=3)
__global__ __launch_bounds__(256)
void step_conv_inv3(const float* cur, const float* w1, float* t_raw, float* st_t,
                    const float* pin, const float* traw2, const float* tst2,
                    const float* tg2, const float* tb2, const float* w2,
                    float* out2, float* ost2, int C, int Ct, int nB)
{
    int z = blockIdx.z, bx = blockIdx.x;
    if (z < 3){
        if (bx >= 282) return;
        dev_conv_b1_m3(cur, w1 + z * 450, t_raw + (size_t)z * 216000, st_t + z * 30, bx);
    } else {
        if (bx >= nB) return;
        dev_invol3(pin, traw2, tst2, tg2, tb2, w2, out2, ost2, C, Ct, bx);
    }
}

// L10: A = covpool30 (z=0)  ||  B = invol3 c5 (z=1)
__global__ __launch_bounds__(256)
void step_cov_inv3(const float* cin, float* feat,
                   const float* pin, const float* traw2, const float* tst2,
                   const float* tg2, const float* tb2, const float* w2,
                   float* out2, float* ost2, int C, int Ct, int nB)
{
    if (blockIdx.z == 0){
        if (blockIdx.x >= 64) return;
        dev_covpool<30, 225, 256>(cin, feat, blockIdx.x);
    } else {
        if ((int)blockIdx.x >= nB) return;
        dev_invol3(pin, traw2, tst2, tg2, tb2, w2, out2, ost2, C, Ct, blockIdx.x);
    }
}

// Standalone wrappers
__global__ __launch_bounds__(256)
void bnconv_g(const float* in, const float* stats, const float* g, const float* bta,
              const float* idn, const float* w, float* out, int Cin, int Cout)
{
    dev_bnconv(in, stats, g, bta, idn, w, out, Cin, Cout, blockIdx.x);
}

template<int C, int N, int TB>
__global__ __launch_bounds__(TB)
void covpool_g(const float* __restrict__ in, float* __restrict__ feat)
{
    dev_covpool<C, N, TB>(in, feat, blockIdx.x);
}

// ---------------------------------------------------------------------------
// Head (unchanged).
// ---------------------------------------------------------------------------
__global__ __launch_bounds__(256)
void head_k(const float* __restrict__ feat1, const float* __restrict__ feat2,
            const float* __restrict__ hg, const float* __restrict__ hb,
            const float* __restrict__ lw, const float* __restrict__ lb,
            float* __restrict__ out)
{
    __shared__ float f[46 * 64];
    int tid = threadIdx.x;
    for (int i = tid; i < 46 * 64; i += 256){
        int ch = i / 64, b = i - ch * 64;
        f[i] = ch < 30 ? feat1[b * 30 + ch] : feat2[b * 16 + (ch - 30)];
    }
    __syncthreads();
    if (tid < 46){
        float s = 0.f, s2 = 0.f;
        for (int b = 0; b < 64; ++b){ float v = f[tid * 64 + b]; s += v; s2 += v * v; }
        float mean = s / 64.f, var = s2 / 64.f - mean * mean;
        float sc = hg[tid] * rsqrtf(var + EPS), sh = hb[tid] - mean * sc;
        for (int b = 0; b < 64; ++b){
            float v = f[tid * 64 + b] * sc + sh;
            f[tid * 64 + b] = v > 0.f ? v : 0.f;
        }
    }
    __syncthreads();
    if (tid < 64){
        int b = tid;
        float l[16];
        float m = -1e30f;
        for (int o = 0; o < 16; ++o){
            float a = lb[o];
            for (int ch = 0; ch < 46; ++ch) a += f[ch * 64 + b] * lw[o * 46 + ch];
            l[o] = a; m = fmaxf(m, a);
        }
        float se = 0.f;
        for (int o = 0; o < 16; ++o){ l[o] = expf(l[o] - m); se += l[o]; }
        float inv = 1.f / se;
        for (int o = 0; o < 16; ++o) out[b * 16 + o] = l[o] * inv;
    }
}

extern "C" void kernel_launch(void* const* d_in, const int* in_sizes, int n_in,
                              void* d_out, int out_size, void* d_ws, size_t ws_size,
                              hipStream_t stream)
{
    (void)in_sizes; (void)n_in; (void)out_size; (void)ws_size;
    const float* x        = (const float*)d_in[0];
    const float* y        = (const float*)d_in[1];
    const float* blk_w1   = (const float*)d_in[2];
    const float* blk_ig   = (const float*)d_in[3];
    const float* blk_ib   = (const float*)d_in[4];
    const float* blk_w2_5 = (const float*)d_in[5];
    const float* blk_w2_7 = (const float*)d_in[6];
    const float* blk_w2_9 = (const float*)d_in[7];
    const float* blk_g    = (const float*)d_in[8];
    const float* blk_b    = (const float*)d_in[9];
    const float* blk_conv = (const float*)d_in[10];
    const float* loc_w1 = (const float*)d_in[11];
    const float* loc_g  = (const float*)d_in[12];
    const float* loc_b  = (const float*)d_in[13];
    const float* loc_w2 = (const float*)d_in[14];
    const float* glb_w1 = (const float*)d_in[15];
    const float* glb_g  = (const float*)d_in[16];
    const float* glb_b  = (const float*)d_in[17];
    const float* glb_w2 = (const float*)d_in[18];
    const float* c3_w1 = (const float*)d_in[19];
    const float* c3_g  = (const float*)d_in[20];
    const float* c3_b  = (const float*)d_in[21];
    const float* c3_w2 = (const float*)d_in[22];
    const float* c4_w1 = (const float*)d_in[23];
    const float* c4_g  = (const float*)d_in[24];
    const float* c4_b  = (const float*)d_in[25];
    const float* c4_w2 = (const float*)d_in[26];
    const float* c5_w1 = (const float*)d_in[27];
    const float* c5_g  = (const float*)d_in[28];
    const float* c5_b  = (const float*)d_in[29];
    const float* c5_w2 = (const float*)d_in[30];
    const float* p1 = (const float*)d_in[31];
    const float* p2 = (const float*)d_in[32];
    const float* p3 = (const float*)d_in[33];
    const float* bn1g = (const float*)d_in[34];
    const float* bn1b = (const float*)d_in[35];
    const float* bn2g = (const float*)d_in[36];
    const float* bn2b = (const float*)d_in[37];
    const float* bn3g = (const float*)d_in[38];
    const float* bn3b = (const float*)d_in[39];
    const float* hg = (const float*)d_in[40];
    const float* hb = (const float*)d_in[41];
    const float* lw = (const float*)d_in[42];
    const float* lb = (const float*)d_in[43];

    float* ws = (float*)d_ws;
    size_t off = 0;
    auto alloc = [&](size_t n){ float* p = ws + off; off += n; return p; };
    float* bufA    = alloc(432000);
    float* bufB    = alloc(432000);
    float* scratch = alloc(1944000);   // branch1 only: t_raw(3) + o_raw(3)
    float* b2ws    = alloc(650000);    // branch2 DEDICATED region
    float* feat1   = alloc(64 * 30);
    float* feat2   = alloc(64 * 16);
    float* stats   = alloc(2288);

    float* t_raw = scratch;            // 3 x 216000
    float* o_raw = scratch + 648000;   // 3 x 432000

    // branch2 buffers inside b2ws
    float* t_loc = b2ws;               // 58752
    float* t_glb = t_loc + 58752;      // 58752
    float* o_idn = t_glb + 58752;      // 117504
    float* t3    = o_idn + 117504;     // 58752
    float* o3    = t3 + 58752;         // 117504
    float* o5    = o3 + 117504;        // 58752
    float* t4    = o5 + 58752;         // 29376
    float* o6    = t4 + 29376;         // 58752
    float* o8    = o6 + 58752;         // 29376
    float* t5    = o8 + 29376;         // 14400
    float* o9    = t5 + 14400;         // 29376
    float* o11   = o9 + 29376;         // 9216

    float* s_tloc = stats + 810;
    float* s_tglb = s_tloc + 204;
    float* s_t3   = s_tglb + 204;
    float* s_o3   = s_t3 + 204;
    float* s_t4   = s_o3 + 408;
    float* s_o6   = s_t4 + 102;
    float* s_t5   = s_o6 + 204;
    float* s_o9   = s_t5 + 50;

    hipMemsetAsync(stats, 0, 2288 * sizeof(float), stream);

    // L1: conv_m3(b0) || conv_dual
    step_conv_convdual<<<dim3(460, 1, 4), 256, 0, stream>>>(
        x, blk_w1, t_raw, stats, y, loc_w1, glb_w1, t_loc, t_glb, s_tloc, s_tglb);
    // L2a: merged invol (b0)
    invol_b1m<<<dim3(64, 2, 3), 256, 0, stream>>>(
        x, t_raw, stats, blk_ig, blk_ib, blk_w2_5, blk_w2_7, blk_w2_9,
        o_raw, stats + 270);
    // L2b: crossatt
    crossatt_g<<<459, 256, 0, stream>>>(
        y, t_loc, t_glb, s_tloc, s_tglb, loc_g, loc_b, glb_g, glb_b,
        loc_w2, glb_w2, o_idn);
    // L3: blockend_m3(b0: x->bufA) || conv(c3)
    step_be_conv<<<dim3(563, 1, 2), 256, 0, stream>>>(
        o_raw, o_raw + 432000, o_raw + 864000,
        stats + 270, stats + 330, stats + 390,
        blk_g, blk_b, blk_conv, x, bufA,
        o_idn, c3_w1, t3, s_t3, 204, 102, 230);
    // L4: conv_m3(b1) || invol3(c3)
    step_conv_inv3<<<dim3(459, 1, 4), 256, 0, stream>>>(
        bufA, blk_w1 + 1350, t_raw, stats + 90,
        o_idn, t3, s_t3, c3_g, c3_b, c3_w2, o3, s_o3, 204, 102, 459);
    // L5a: merged invol (b1)
    invol_b1m<<<dim3(64, 2, 3), 256, 0, stream>>>(
        bufA, t_raw, stats + 90, blk_ig + 45, blk_ib + 45,
        blk_w2_5 + 750, blk_w2_7 + 1470, blk_w2_9 + 2430,
        o_raw, stats + 450);
    // L5b: bnconv(c3)
    bnconv_g<<<230, 256, 0, stream>>>(o3, s_o3, bn1g, bn1b, o_idn, p1, o5, 204, 102);
    // L6: blockend_m3(b1: bufA->bufB) || conv(c4)
    step_be_conv<<<dim3(563, 1, 2), 256, 0, stream>>>(
        o_raw, o_raw + 432000, o_raw + 864000,
        stats + 450, stats + 510, stats + 570,
        blk_g + 90, blk_b + 90, blk_conv + 2700, bufA, bufB,
        o5, c4_w1, t4, s_t4, 102, 51, 115);
    // L7: conv_m3(b2) || invol3(c4)
    step_conv_inv3<<<dim3(282, 1, 4), 256, 0, stream>>>(
        bufB, blk_w1 + 2700, t_raw, stats + 180,
        o5, t4, s_t4, c4_g, c4_b, c4_w2, o6, s_o6, 102, 51, 230);
    // L8a: merged invol (b2)
    invol_b1m<<<dim3(64, 2, 3), 256, 0, stream>>>(
        bufB, t_raw, stats + 180, blk_ig + 90, blk_ib + 90,
        blk_w2_5 + 1500, blk_w2_7 + 2940, blk_w2_9 + 4860,
        o_raw, stats + 630);
    // L8b: bnconv(c4)
    bnconv_g<<<115, 256, 0, stream>>>(o6, s_o6, bn2g, bn2b, nullptr, p2, o8, 102, 51);
    // L9: blockend_m3(b2: bufB->bufA) || conv(c5)
    step_be_conv<<<dim3(563, 1, 2), 256, 0, stream>>>(
        o_raw, o_raw + 432000, o_raw + 864000,
        stats + 630, stats + 690, stats + 750,
        blk_g + 180, blk_b + 180, blk_conv + 5400, bufB, bufA,
        o8, c5_w1, t5, s_t5, 51, 25, 57);
    // L10: covpool1(bufA) || invol3(c5)
    step_cov_inv3<<<dim3(115, 1, 2), 256, 0, stream>>>(
        bufA, feat1,
        o8, t5, s_t5, c5_g, c5_b, c5_w2, o9, s_o9, 51, 25, 115);
    // L11: bnconv(c5)
    bnconv_g<<<36, 256, 0, stream>>>(o9, s_o9, bn3g, bn3b, o8, p3, o11, 51, 16);
    // L12: covpool2
    covpool_g<16, 9, 256><<<64, 256, 0, stream>>>(o11, feat2);
    // L13: head
    head_k<<<1, 256, 0, stream>>>(feat1, feat2, hg, hb, lw, lb, (float*)d_out);
}

// Round 12
// 527.409 us; speedup vs baseline: 2.5524x; 1.9983x over previous
//
#include <hip/hip_runtime.h>
#include <math.h>

#define EPS 1e-5f

__device__ inline void wave_red2(float& s1, float& s2){
    for (int off = 32; off; off >>= 1){
        s1 += __shfl_down(s1, off, 64);
        s2 += __shfl_down(s2, off, 64);
    }
}

// ---------------------------------------------------------------------------
// conv1x1 + optional stats (generic device form — branch-2 users; stats
// contention here is <=9 waves/address so single-slot atomics stay).
// ---------------------------------------------------------------------------
__device__ __forceinline__
void dev_conv1x1(const float* __restrict__ in, const float* __restrict__ w,
                 float* __restrict__ out, float* __restrict__ stats,
                 int Cin, int Cout, int HW, int B, int bx)
{
    int npos = B * HW;
    int total = Cout * npos;
    int item = bx * 256 + threadIdx.x;
    if (item >= total) return;
    int j = item / npos;
    int pos = item - j * npos;
    int b = pos / HW, hw = pos - b * HW;
    int ju = __builtin_amdgcn_readfirstlane(j);
    const float* ip = in + (size_t)b * Cin * HW + hw;
    const float* wr = w + (size_t)ju * Cin;
    float a0 = 0.f, a1 = 0.f, a2 = 0.f, a3 = 0.f;
    int c = 0;
    #pragma unroll 2
    for (; c + 3 < Cin; c += 4){
        a0 += ip[(size_t)c * HW] * wr[c];
        a1 += ip[(size_t)(c + 1) * HW] * wr[c + 1];
        a2 += ip[(size_t)(c + 2) * HW] * wr[c + 2];
        a3 += ip[(size_t)(c + 3) * HW] * wr[c + 3];
    }
    for (; c < Cin; ++c) a0 += ip[(size_t)c * HW] * wr[c];
    float acc = (a0 + a1) + (a2 + a3);
    out[(size_t)b * Cout * HW + (size_t)j * HW + hw] = acc;
    if (stats){
        float s1 = acc, s2 = acc * acc;
        wave_red2(s1, s2);
        if ((threadIdx.x & 63) == 0){
            atomicAdd(&stats[ju], s1);
            atomicAdd(&stats[Cout + ju], s2);
        }
    }
}

// ---------------------------------------------------------------------------
// Branch-1 conv1x1, 3 outputs/thread. ROUND-12 CHANGE: stats atomics were
// 225 waves serializing on ONE address (the session's hidden ~140us cost);
// now spread over 32 slots (slot = waveIdx & 31) -> ~7 contenders/address.
// Layout: sums at st[j*32+slot], sumsq at st[480 + j*32+slot].
// ---------------------------------------------------------------------------
__device__ __forceinline__
void dev_conv_b1_m3(const float* __restrict__ in, const float* __restrict__ w,
                    float* __restrict__ out, float* __restrict__ stats, int bx)
{
    int item = bx * 256 + threadIdx.x;
    if (item >= 72000) return;
    int jg = item / 14400;
    int pos = item - jg * 14400;
    int b = pos / 225, hw = pos - b * 225;
    int jgu = __builtin_amdgcn_readfirstlane(jg);
    int slot = __builtin_amdgcn_readfirstlane((item >> 6) & 31);
    const float* ip = in + (size_t)b * 6750 + hw;
    const float* w0 = w + (size_t)(jgu * 3) * 30;
    const float* w1 = w0 + 30;
    const float* w2 = w0 + 60;

    float a00=0.f,a01=0.f,a02=0.f,a03=0.f;
    float a10=0.f,a11=0.f,a12=0.f,a13=0.f;
    float a20=0.f,a21=0.f,a22=0.f,a23=0.f;
    int c = 0;
    #pragma unroll 2
    for (; c + 3 < 30; c += 4){
        float v0 = ip[(size_t)c * 225];
        float v1 = ip[(size_t)(c + 1) * 225];
        float v2 = ip[(size_t)(c + 2) * 225];
        float v3 = ip[(size_t)(c + 3) * 225];
        a00 += v0 * w0[c];     a01 += v1 * w0[c + 1];
        a02 += v2 * w0[c + 2]; a03 += v3 * w0[c + 3];
        a10 += v0 * w1[c];     a11 += v1 * w1[c + 1];
        a12 += v2 * w1[c + 2]; a13 += v3 * w1[c + 3];
        a20 += v0 * w2[c];     a21 += v1 * w2[c + 1];
        a22 += v2 * w2[c + 2]; a23 += v3 * w2[c + 3];
    }
    for (; c < 30; ++c){
        float v = ip[(size_t)c * 225];
        a00 += v * w0[c];
        a10 += v * w1[c];
        a20 += v * w2[c];
    }
    float acc0 = (a00 + a01) + (a02 + a03);
    float acc1 = (a10 + a11) + (a12 + a13);
    float acc2 = (a20 + a21) + (a22 + a23);

    float* ob = out + (size_t)b * 3375 + (size_t)(jg * 3) * 225 + hw;
    ob[0]   = acc0;
    ob[225] = acc1;
    ob[450] = acc2;

    float accs[3] = {acc0, acc1, acc2};
    #pragma unroll
    for (int q = 0; q < 3; ++q){
        float s1 = accs[q], s2 = accs[q] * accs[q];
        wave_red2(s1, s2);
        if ((threadIdx.x & 63) == 0){
            atomicAdd(&stats[(jgu * 3 + q) * 32 + slot], s1);
            atomicAdd(&stats[480 + (jgu * 3 + q) * 32 + slot], s2);
        }
    }
}

// ---------------------------------------------------------------------------
// Branch-1 fused involution, merged halves. ROUND-12: BN-prep sums the 32
// t-stat slots; output stats spread over 32 slots (slot = b & 31) -> 8
// contenders/address (was 256). ostats layout: sums (g*15+cc)*32+slot,
// sumsq 960 + same.
// ---------------------------------------------------------------------------
template<int K>
__device__ void dev_invol_b1_full(const float* __restrict__ in, const float* __restrict__ t_raw,
                                  const float* __restrict__ tstats,
                                  const float* __restrict__ tg, const float* __restrict__ tb,
                                  const float* __restrict__ w2,
                                  float* __restrict__ o_raw, float* __restrict__ ostats,
                                  float* lds, int b, int g)
{
    constexpr int KK = K * K, P = (K - 1) / 2;
    float* in_s = lds;            // 15*225 = 3375
    float* scb  = lds + 3375;     // 15
    float* shb  = lds + 3390;     // 15
    int tid = threadIdx.x;

    if (tid < 15){
        const float invN = 1.f / 14400.f;
        float s1v = 0.f, s2v = 0.f;
        #pragma unroll 8
        for (int s = 0; s < 32; ++s){
            s1v += tstats[tid * 32 + s];
            s2v += tstats[480 + tid * 32 + s];
        }
        float mean = s1v * invN;
        float var  = s2v * invN - mean * mean;
        float s = tg[tid] * rsqrtf(var + EPS);
        scb[tid] = s; shb[tid] = tb[tid] - mean * s;
    }
    const float* w2g = w2 + (size_t)g * KK * 15;   // block-uniform base
    const float* inb = in + (size_t)b * 6750 + (size_t)g * 15 * 225;
    for (int i = tid; i < 3375; i += 256) in_s[i] = inb[i];
    __syncthreads();

    bool act = tid < 225;
    int p = act ? tid : 224;
    int h = p / 15, w = p - h * 15;

    float treg[15];
    const float* trb = t_raw + (size_t)b * 3375 + p;
    #pragma unroll
    for (int j = 0; j < 15; ++j){
        float v = trb[j * 225] * scb[j] + shb[j];
        treg[j] = v > 0.f ? v : 0.f;
    }

    float acc[15];
    #pragma unroll
    for (int cc = 0; cc < 15; ++cc) acc[cc] = 0.f;

    for (int ki = 0; ki < K; ++ki){
        int hh = h + ki - P;
        bool hok = (unsigned)hh < 15u;
        const float* w2row = w2g + ki * K * 15;
        #pragma unroll
        for (int kj0 = 0; kj0 < K; kj0 += 3){
            const float* wr = w2row + kj0 * 15;
            float a0 = 0.f, a1 = 0.f, a2 = 0.f;
            #pragma unroll
            for (int j = 0; j < 15; ++j){
                float tv = treg[j];
                a0 += tv * wr[j];
                if (kj0 + 1 < K) a1 += tv * wr[15 + j];
                if (kj0 + 2 < K) a2 += tv * wr[30 + j];
            }
            float wv[3] = {a0, a1, a2};
            #pragma unroll
            for (int t = 0; t < 3; ++t){
                int kj = kj0 + t;
                if (kj >= K) break;
                int ww = w + kj - P;
                bool ok = hok && ((unsigned)ww < 15u);
                float sc2 = ok ? wv[t] : 0.f;
                int offr = ok ? hh * 15 + ww : 0;
                #pragma unroll
                for (int cc = 0; cc < 15; ++cc) acc[cc] += sc2 * in_s[cc * 225 + offr];
            }
        }
    }

    int slot = b & 31;
    float* ob = o_raw + (size_t)b * 6750 + (size_t)g * 15 * 225;
    #pragma unroll
    for (int cc = 0; cc < 15; ++cc){
        float val = act ? acc[cc] : 0.f;
        if (act) ob[cc * 225 + p] = val;
        float s1 = val, s2 = val * val;
        wave_red2(s1, s2);
        if ((tid & 63) == 0){
            atomicAdd(&ostats[(g * 15 + cc) * 32 + slot], s1);
            atomicAdd(&ostats[960 + (g * 15 + cc) * 32 + slot], s2);
        }
    }
}

__global__ __launch_bounds__(256)
void invol_b1m(const float* __restrict__ in, const float* __restrict__ t_raw3,
               const float* __restrict__ tstats3,
               const float* __restrict__ tg3, const float* __restrict__ tb3,
               const float* __restrict__ w2_5, const float* __restrict__ w2_7,
               const float* __restrict__ w2_9,
               float* __restrict__ o_raw3, float* __restrict__ ostats3)
{
    __shared__ float lds[3405];
    int b = blockIdx.x, g = blockIdx.y, ii = blockIdx.z;
    if (ii == 0)
        dev_invol_b1_full<5>(in, t_raw3,          tstats3,        tg3,      tb3,      w2_5, o_raw3,          ostats3,        lds, b, g);
    else if (ii == 1)
        dev_invol_b1_full<7>(in, t_raw3 + 216000, tstats3 + 960,  tg3 + 15, tb3 + 15, w2_7, o_raw3 + 432000, ostats3 + 1920, lds, b, g);
    else
        dev_invol_b1_full<9>(in, t_raw3 + 432000, tstats3 + 1920, tg3 + 30, tb3 + 30, w2_9, o_raw3 + 864000, ostats3 + 3840, lds, b, g);
}

// ---------------------------------------------------------------------------
// blockend, 3 outputs/thread. ROUND-12: BN-prep sums 32 o-stat slots.
// ---------------------------------------------------------------------------
__device__ __forceinline__
void dev_blockend_m3(const float* __restrict__ o0, const float* __restrict__ o1,
                     const float* __restrict__ o2,
                     const float* __restrict__ s0, const float* __restrict__ s1,
                     const float* __restrict__ s2,
                     const float* __restrict__ g, const float* __restrict__ bb,
                     const float* __restrict__ conv,
                     const float* __restrict__ oldout, float* __restrict__ newout, int bx)
{
    __shared__ float sc[90], sh[90];
    int tid = threadIdx.x;
    if (tid < 90){
        int ii = tid / 30, cc = tid - ii * 30;
        const float* st = ii == 0 ? s0 : (ii == 1 ? s1 : s2);
        const float invN = 1.f / 14400.f;
        float s1v = 0.f, s2v = 0.f;
        #pragma unroll 8
        for (int s = 0; s < 32; ++s){
            s1v += st[cc * 32 + s];
            s2v += st[960 + cc * 32 + s];
        }
        float mean = s1v * invN;
        float var = s2v * invN - mean * mean;
        float s = g[tid] * rsqrtf(var + EPS);
        sc[tid] = s; sh[tid] = bb[tid] - mean * s;
    }
    __syncthreads();
    int item = bx * 256 + tid;
    if (item >= 144000) return;
    int cg = item / 14400, pos = item - cg * 14400;
    int b = pos / 225, hw = pos - b * 225;
    int cgu = __builtin_amdgcn_readfirstlane(cg);
    const float* cr0 = conv + (size_t)(cgu * 3) * 90;
    const float* cr1 = cr0 + 90;
    const float* cr2 = cr0 + 180;
    const float* ol = oldout + (size_t)b * 6750 + (size_t)(cg * 3) * 225 + hw;
    float acc0 = ol[0], acc1 = ol[225], acc2 = ol[450];
    const float* bases[3] = {o0, o1, o2};
    #pragma unroll
    for (int ii = 0; ii < 3; ++ii){
        const float* op = bases[ii] + (size_t)b * 6750 + hw;
        float sA0 = 0.f, sB0 = 0.f, sA1 = 0.f, sB1 = 0.f, sA2 = 0.f, sB2 = 0.f;
        #pragma unroll 5
        for (int cc = 0; cc < 30; cc += 2){
            float v = op[cc * 225] * sc[ii * 30 + cc] + sh[ii * 30 + cc];
            v = v > 0.f ? v : 0.f;
            float v2 = op[(cc + 1) * 225] * sc[ii * 30 + cc + 1] + sh[ii * 30 + cc + 1];
            v2 = v2 > 0.f ? v2 : 0.f;
            sA0 += v * cr0[ii * 30 + cc];  sB0 += v2 * cr0[ii * 30 + cc + 1];
            sA1 += v * cr1[ii * 30 + cc];  sB1 += v2 * cr1[ii * 30 + cc + 1];
            sA2 += v * cr2[ii * 30 + cc];  sB2 += v2 * cr2[ii * 30 + cc + 1];
        }
        acc0 += sA0 + sB0;
        acc1 += sA1 + sB1;
        acc2 += sA2 + sB2;
    }
    float* nb = newout + (size_t)b * 6750 + (size_t)(cg * 3) * 225 + hw;
    nb[0]   = acc0;
    nb[225] = acc1;
    nb[450] = acc2;
}

// ---------------------------------------------------------------------------
// cross-attention front (unchanged).
// ---------------------------------------------------------------------------
__device__ __forceinline__
void dev_crossatt(const float* __restrict__ y,
                  const float* __restrict__ t_loc, const float* __restrict__ t_glb,
                  const float* __restrict__ s_tloc, const float* __restrict__ s_tglb,
                  const float* __restrict__ lg, const float* __restrict__ lb,
                  const float* __restrict__ gg, const float* __restrict__ gb,
                  const float* __restrict__ loc_w2, const float* __restrict__ glb_w2,
                  float* __restrict__ out, int bx)
{
    __shared__ float lsc[102], lsh[102], gsc[102], gsh[102];
    const float invN = 1.f / 576.f;
    for (int j = threadIdx.x; j < 102; j += 256){
        float m1 = s_tloc[j] * invN;
        float v1 = s_tloc[102 + j] * invN - m1 * m1;
        float a1 = lg[j] * rsqrtf(v1 + EPS);
        lsc[j] = a1; lsh[j] = lb[j] - m1 * a1;
        float m2 = s_tglb[j] * invN;
        float v2 = s_tglb[102 + j] * invN - m2 * m2;
        float a2 = gg[j] * rsqrtf(v2 + EPS);
        gsc[j] = a2; gsh[j] = gb[j] - m2 * a2;
    }
    __syncthreads();
    int item = bx * 256 + threadIdx.x;
    if (item >= 204 * 576) return;
    int c = item / 576, pos = item - c * 576;
    int b = pos / 9, hw = pos - b * 9;
    int h = hw / 3, w = hw - h * 3;
    int cu = __builtin_amdgcn_readfirstlane(c);

    const float* tl = t_loc + (size_t)b * 918 + hw;
    const float* tg_ = t_glb + (size_t)b * 918 + hw;
    const float* wl = loc_w2 + (size_t)cu * 918;
    float wk[9];
    #pragma unroll
    for (int kk = 0; kk < 9; ++kk) wk[kk] = 0.f;
    for (int j = 0; j < 102; ++j){
        float a = tl[j * 9] * lsc[j] + lsh[j];
        a = a > 0.f ? a : 0.f;
        float g2 = tg_[j * 9] * gsc[j] + gsh[j];
        g2 = g2 > 0.f ? g2 : 0.f;
        #pragma unroll
        for (int kk = 0; kk < 9; ++kk)
            wk[kk] += a * wl[kk * 102 + j] + g2 * glb_w2[kk * 102 + j];
    }
    const float* pb = y + (size_t)b * 1836 + c * 9;
    float acc = 0.f;
    #pragma unroll
    for (int ki = 0; ki < 3; ++ki){
        int hh = h + ki - 1;
        bool hok = (unsigned)hh < 3u;
        #pragma unroll
        for (int kj = 0; kj < 3; ++kj){
            int ww = w + kj - 1;
            bool ok = hok && ((unsigned)ww < 3u);
            float v = ok ? pb[hh * 3 + ww] : 0.f;
            acc += wk[ki * 3 + kj] * v;
        }
    }
    out[(size_t)b * 1836 + c * 9 + hw] = pb[hw] * acc;
}

__global__ __launch_bounds__(256)
void crossatt_g(const float* y, const float* t_loc, const float* t_glb,
                const float* s_tloc, const float* s_tglb,
                const float* lg, const float* lb, const float* gg, const float* gb,
                const float* loc_w2, const float* glb_w2, float* out)
{
    dev_crossatt(y, t_loc, t_glb, s_tloc, s_tglb, lg, lb, gg, gb,
                 loc_w2, glb_w2, out, blockIdx.x);
}

// ---------------------------------------------------------------------------
// groups==1 involution (unchanged — <=9 contenders/address).
// ---------------------------------------------------------------------------
__device__ __forceinline__
void dev_invol3(const float* __restrict__ pin, const float* __restrict__ t_raw,
                const float* __restrict__ tstats,
                const float* __restrict__ tg, const float* __restrict__ tb,
                const float* __restrict__ w2,
                float* __restrict__ out, float* __restrict__ ostats,
                int C, int Ct, int bx)
{
    __shared__ float tsc[102], tsh[102];
    const float invN = 1.f / 576.f;
    for (int j = threadIdx.x; j < Ct; j += 256){
        float mean = tstats[j] * invN;
        float var  = tstats[Ct + j] * invN - mean * mean;
        float s = tg[j] * rsqrtf(var + EPS);
        tsc[j] = s; tsh[j] = tb[j] - mean * s;
    }
    __syncthreads();
    int item = bx * 256 + threadIdx.x;
    if (item >= C * 576) return;
    int c = item / 576, pos = item - c * 576;
    int b = pos / 9, hw = pos - b * 9;
    int h = hw / 3, w = hw - h * 3;

    const float* tp = t_raw + (size_t)b * Ct * 9 + hw;
    float wk[9];
    #pragma unroll
    for (int kk = 0; kk < 9; ++kk) wk[kk] = 0.f;
    for (int j = 0; j < Ct; ++j){
        float t = tp[j * 9] * tsc[j] + tsh[j];
        t = t > 0.f ? t : 0.f;
        #pragma unroll
        for (int kk = 0; kk < 9; ++kk) wk[kk] += t * w2[kk * Ct + j];
    }
    const float* pb = pin + (size_t)b * C * 9 + c * 9;
    float acc = 0.f;
    #pragma unroll
    for (int ki = 0; ki < 3; ++ki){
        int hh = h + ki - 1;
        bool hok = (unsigned)hh < 3u;
        #pragma unroll
        for (int kj = 0; kj < 3; ++kj){
            int ww = w + kj - 1;
            bool ok = hok && ((unsigned)ww < 3u);
            float v = ok ? pb[hh * 3 + ww] : 0.f;
            acc += wk[ki * 3 + kj] * v;
        }
    }
    out[(size_t)b * C * 9 + c * 9 + hw] = acc;
    float s1 = acc, s2 = acc * acc;
    wave_red2(s1, s2);
    if ((threadIdx.x & 63) == 0){
        int cu = __builtin_amdgcn_readfirstlane(c);
        atomicAdd(&ostats[cu], s1);
        atomicAdd(&ostats[C + cu], s2);
    }
}

// ---------------------------------------------------------------------------
// BN+ReLU(+residual)->conv1x1 (unchanged).
// ---------------------------------------------------------------------------
__device__ __forceinline__
void dev_bnconv(const float* __restrict__ in, const float* __restrict__ stats,
                const float* __restrict__ g, const float* __restrict__ bta,
                const float* __restrict__ idn, const float* __restrict__ w,
                float* __restrict__ out, int Cin, int Cout, int bx)
{
    __shared__ float sc[204], sh[204];
    for (int j = threadIdx.x; j < Cin; j += 256){
        const float invN = 1.f / 576.f;
        float mean = stats[j] * invN;
        float var = stats[Cin + j] * invN - mean * mean;
        float s = g[j] * rsqrtf(var + EPS);
        sc[j] = s; sh[j] = bta[j] - mean * s;
    }
    __syncthreads();
    int item = bx * 256 + threadIdx.x;
    if (item >= Cout * 576) return;
    int j = item / 576, pos = item - j * 576;
    int b = pos / 9, hw = pos - b * 9;
    int ju = __builtin_amdgcn_readfirstlane(j);
    const float* ip = in + (size_t)b * Cin * 9 + hw;
    const float* ir = idn ? idn + (size_t)b * Cin * 9 + hw : nullptr;
    const float* wr = w + (size_t)ju * Cin;
    float a0 = 0.f, a1 = 0.f, a2 = 0.f, a3 = 0.f;
    int c = 0;
    #pragma unroll 2
    for (; c + 3 < Cin; c += 4){
        float v0 = ip[c * 9] * sc[c] + sh[c];             v0 = v0 > 0.f ? v0 : 0.f;
        float v1 = ip[(c + 1) * 9] * sc[c + 1] + sh[c + 1]; v1 = v1 > 0.f ? v1 : 0.f;
        float v2 = ip[(c + 2) * 9] * sc[c + 2] + sh[c + 2]; v2 = v2 > 0.f ? v2 : 0.f;
        float v3 = ip[(c + 3) * 9] * sc[c + 3] + sh[c + 3]; v3 = v3 > 0.f ? v3 : 0.f;
        if (ir){
            v0 += ir[c * 9]; v1 += ir[(c + 1) * 9];
            v2 += ir[(c + 2) * 9]; v3 += ir[(c + 3) * 9];
        }
        a0 += v0 * wr[c];
        a1 += v1 * wr[c + 1];
        a2 += v2 * wr[c + 2];
        a3 += v3 * wr[c + 3];
    }
    for (; c < Cin; ++c){
        float v = ip[c * 9] * sc[c] + sh[c];
        v = v > 0.f ? v : 0.f;
        if (ir) v += ir[c * 9];
        a0 += v * wr[c];
    }
    out[(size_t)b * Cout * 9 + j * 9 + hw] = (a0 + a1) + (a2 + a3);
}

// ---------------------------------------------------------------------------
// GlobalCovPooling (unchanged).
// ---------------------------------------------------------------------------
template<int C, int N, int TB>
__device__ void dev_covpool(const float* __restrict__ in, float* __restrict__ feat, int b)
{
    __shared__ float X[N * C];
    __shared__ float Ybuf[C * C], Mbuf[C * C], Zbuf[C * C], Z2buf[C * C];
    __shared__ float mu[C];
    __shared__ float scal[2];
    int tid = threadIdx.x;
    const float* ib = in + (size_t)b * C * N;
    for (int i = tid; i < N * C; i += TB){
        int n = i / C, c = i - n * C;
        X[i] = ib[(size_t)c * N + n];
    }
    __syncthreads();
    if (tid < C){
        float s0 = 0.f, s1 = 0.f, s2 = 0.f, s3 = 0.f;
        int n = 0;
        for (; n + 3 < N; n += 4){
            s0 += X[n * C + tid];
            s1 += X[(n + 1) * C + tid];
            s2 += X[(n + 2) * C + tid];
            s3 += X[(n + 3) * C + tid];
        }
        for (; n < N; ++n) s0 += X[n * C + tid];
        mu[tid] = ((s0 + s1) + (s2 + s3)) / (float)N;
    }
    __syncthreads();
    constexpr int CC = C * C;
    for (int i = tid; i < CC; i += TB){
        int c = i / C, d = i - c * C;
        float s0 = 0.f, s1 = 0.f, s2 = 0.f, s3 = 0.f;
        int n = 0;
        for (; n + 3 < N; n += 4){
            s0 += X[n * C + c] * X[n * C + d];
            s1 += X[(n + 1) * C + c] * X[(n + 1) * C + d];
            s2 += X[(n + 2) * C + c] * X[(n + 2) * C + d];
            s3 += X[(n + 3) * C + c] * X[(n + 3) * C + d];
        }
        for (; n < N; ++n) s0 += X[n * C + c] * X[n * C + d];
        Ybuf[i] = ((s0 + s1) + (s2 + s3)) / (float)N - mu[c] * mu[d];
    }
    __syncthreads();
    if (tid == 0){
        float tr = 0.f;
        for (int c = 0; c < C; ++c) tr += Ybuf[c * C + c];
        scal[0] = 1.f / tr;
    }
    __syncthreads();
    for (int i = tid; i < CC; i += TB){
        int c = i / C, d = i - c * C;
        Ybuf[i] *= scal[0];
        Zbuf[i] = (c == d) ? 1.f : 0.f;
    }
    __syncthreads();
    float* zs = Zbuf; float* zd = Z2buf;
    for (int it = 0; it < 6; ++it){
        for (int i = tid; i < CC; i += TB){
            int c = i / C, d = i - c * C;
            float sA = 0.f, sB = 0.f;
            #pragma unroll 3
            for (int e = 0; e < C; e += 2){
                sA += zs[c * C + e] * Ybuf[e * C + d];
                sB += zs[c * C + e + 1] * Ybuf[(e + 1) * C + d];
            }
            Mbuf[i] = ((c == d) ? 3.f : 0.f) - (sA + sB);
        }
        __syncthreads();
        for (int i = tid; i < CC; i += TB){
            int c = i / C, d = i - c * C;
            float sA = 0.f, sB = 0.f;
            #pragma unroll 3
            for (int e = 0; e < C; e += 2){
                sA += Mbuf[c * C + e] * zs[e * C + d];
                sB += Mbuf[c * C + e + 1] * zs[(e + 1) * C + d];
            }
            zd[i] = 0.5f * (sA + sB);
        }
        for (int i = tid; i < CC; i += TB) Ybuf[i] *= 0.5f * Mbuf[i];
        __syncthreads();
        float* t = zs; zs = zd; zd = t;
    }
    if (tid == 0){
        float tr = 0.f;
        for (int c = 0; c < C; ++c) tr += Ybuf[c * C + c];
        scal[1] = sqrtf(tr);
    }
    __syncthreads();
    if (tid < C){
        float s = 0.f;
        #pragma unroll 6
        for (int c = 0; c < C; ++c) s += Ybuf[c * C + tid];
        feat[(size_t)b * C + tid] = scal[1] * s / (float)C;
    }
}

// ===========================================================================
// Paired-step wrappers.
// ===========================================================================

// L1: A = branch1 conv m3 (z=0..2)  ||  B = conv_dual (z=3)
__global__ __launch_bounds__(256)
void step_conv_convdual(const float* xin, const float* w1, float* t_raw, float* st_t,
                        const float* yin, const float* locw1, const float* glbw1,
                        float* t_loc, float* t_glb, float* s_tloc, float* s_tglb)
{
    int z = blockIdx.z, bx = blockIdx.x;
    if (z < 3){
        if (bx >= 282) return;
        dev_conv_b1_m3(xin, w1 + z * 450, t_raw + (size_t)z * 216000, st_t + z * 960, bx);
    } else {
        int f = bx;
        if (f >= 460) return;
        int zz = f / 230, b2 = f - zz * 230;
        dev_conv1x1(yin, zz ? glbw1 : locw1, zz ? t_glb : t_loc,
                    zz ? s_tglb : s_tloc, 204, 102, 9, 64, b2);
    }
}

// L3/L6/L9: A = blockend m3 (563 blocks)  ||  B = branch2 conv1x1 (nB blocks)
__global__ __launch_bounds__(256)
void step_be_conv(const float* o0, const float* o1, const float* o2,
                  const float* s0, const float* s1, const float* s2,
                  const float* g, const float* bb, const float* conv,
                  const float* oldout, float* newout,
                  const float* bin, const float* bw, float* bout, float* bstats,
                  int bCin, int bCout, int nB)
{
    if (blockIdx.z == 0){
        dev_blockend_m3(o0, o1, o2, s0, s1, s2, g, bb, conv, oldout, newout, blockIdx.x);
    } else {
        if ((int)blockIdx.x >= nB) return;
        dev_conv1x1(bin, bw, bout, bstats, bCin, bCout, 9, 64, blockIdx.x);
    }
}

// L4/L7: A = branch1 conv m3 (z=0..2)  ||  B = invol3 (z=3)
__global__ __launch_bounds__(256)
void step_conv_inv3(const float* cur, const float* w1, float* t_raw, float* st_t,
                    const float* pin, const float* traw2, const float* tst2,
                    const float* tg2, const float* tb2, const float* w2,
                    float* out2, float* ost2, int C, int Ct, int nB)
{
    int z = blockIdx.z, bx = blockIdx.x;
    if (z < 3){
        if (bx >= 282) return;
        dev_conv_b1_m3(cur, w1 + z * 450, t_raw + (size_t)z * 216000, st_t + z * 960, bx);
    } else {
        if (bx >= nB) return;
        dev_invol3(pin, traw2, tst2, tg2, tb2, w2, out2, ost2, C, Ct, bx);
    }
}

// L10: A = covpool30 (z=0)  ||  B = invol3 c5 (z=1)
__global__ __launch_bounds__(256)
void step_cov_inv3(const float* cin, float* feat,
                   const float* pin, const float* traw2, const float* tst2,
                   const float* tg2, const float* tb2, const float* w2,
                   float* out2, float* ost2, int C, int Ct, int nB)
{
    if (blockIdx.z == 0){
        if (blockIdx.x >= 64) return;
        dev_covpool<30, 225, 256>(cin, feat, blockIdx.x);
    } else {
        if ((int)blockIdx.x >= nB) return;
        dev_invol3(pin, traw2, tst2, tg2, tb2, w2, out2, ost2, C, Ct, blockIdx.x);
    }
}

// Standalone wrappers
__global__ __launch_bounds__(256)
void bnconv_g(const float* in, const float* stats, const float* g, const float* bta,
              const float* idn, const float* w, float* out, int Cin, int Cout)
{
    dev_bnconv(in, stats, g, bta, idn, w, out, Cin, Cout, blockIdx.x);
}

template<int C, int N, int TB>
__global__ __launch_bounds__(TB)
void covpool_g(const float* __restrict__ in, float* __restrict__ feat)
{
    dev_covpool<C, N, TB>(in, feat, blockIdx.x);
}

// ---------------------------------------------------------------------------
// Head (unchanged).
// ---------------------------------------------------------------------------
__global__ __launch_bounds__(256)
void head_k(const float* __restrict__ feat1, const float* __restrict__ feat2,
            const float* __restrict__ hg, const float* __restrict__ hb,
            const float* __restrict__ lw, const float* __restrict__ lb,
            float* __restrict__ out)
{
    __shared__ float f[46 * 64];
    int tid = threadIdx.x;
    for (int i = tid; i < 46 * 64; i += 256){
        int ch = i / 64, b = i - ch * 64;
        f[i] = ch < 30 ? feat1[b * 30 + ch] : feat2[b * 16 + (ch - 30)];
    }
    __syncthreads();
    if (tid < 46){
        float s = 0.f, s2 = 0.f;
        for (int b = 0; b < 64; ++b){ float v = f[tid * 64 + b]; s += v; s2 += v * v; }
        float mean = s / 64.f, var = s2 / 64.f - mean * mean;
        float sc = hg[tid] * rsqrtf(var + EPS), sh = hb[tid] - mean * sc;
        for (int b = 0; b < 64; ++b){
            float v = f[tid * 64 + b] * sc + sh;
            f[tid * 64 + b] = v > 0.f ? v : 0.f;
        }
    }
    __syncthreads();
    if (tid < 64){
        int b = tid;
        float l[16];
        float m = -1e30f;
        for (int o = 0; o < 16; ++o){
            float a = lb[o];
            for (int ch = 0; ch < 46; ++ch) a += f[ch * 64 + b] * lw[o * 46 + ch];
            l[o] = a; m = fmaxf(m, a);
        }
        float se = 0.f;
        for (int o = 0; o < 16; ++o){ l[o] = expf(l[o] - m); se += l[o]; }
        float inv = 1.f / se;
        for (int o = 0; o < 16; ++o) out[b * 16 + o] = l[o] * inv;
    }
}

extern "C" void kernel_launch(void* const* d_in, const int* in_sizes, int n_in,
                              void* d_out, int out_size, void* d_ws, size_t ws_size,
                              hipStream_t stream)
{
    (void)in_sizes; (void)n_in; (void)out_size; (void)ws_size;
    const float* x        = (const float*)d_in[0];
    const float* y        = (const float*)d_in[1];
    const float* blk_w1   = (const float*)d_in[2];
    const float* blk_ig   = (const float*)d_in[3];
    const float* blk_ib   = (const float*)d_in[4];
    const float* blk_w2_5 = (const float*)d_in[5];
    const float* blk_w2_7 = (const float*)d_in[6];
    const float* blk_w2_9 = (const float*)d_in[7];
    const float* blk_g    = (const float*)d_in[8];
    const float* blk_b    = (const float*)d_in[9];
    const float* blk_conv = (const float*)d_in[10];
    const float* loc_w1 = (const float*)d_in[11];
    const float* loc_g  = (const float*)d_in[12];
    const float* loc_b  = (const float*)d_in[13];
    const float* loc_w2 = (const float*)d_in[14];
    const float* glb_w1 = (const float*)d_in[15];
    const float* glb_g  = (const float*)d_in[16];
    const float* glb_b  = (const float*)d_in[17];
    const float* glb_w2 = (const float*)d_in[18];
    const float* c3_w1 = (const float*)d_in[19];
    const float* c3_g  = (const float*)d_in[20];
    const float* c3_b  = (const float*)d_in[21];
    const float* c3_w2 = (const float*)d_in[22];
    const float* c4_w1 = (const float*)d_in[23];
    const float* c4_g  = (const float*)d_in[24];
    const float* c4_b  = (const float*)d_in[25];
    const float* c4_w2 = (const float*)d_in[26];
    const float* c5_w1 = (const float*)d_in[27];
    const float* c5_g  = (const float*)d_in[28];
    const float* c5_b  = (const float*)d_in[29];
    const float* c5_w2 = (const float*)d_in[30];
    const float* p1 = (const float*)d_in[31];
    const float* p2 = (const float*)d_in[32];
    const float* p3 = (const float*)d_in[33];
    const float* bn1g = (const float*)d_in[34];
    const float* bn1b = (const float*)d_in[35];
    const float* bn2g = (const float*)d_in[36];
    const float* bn2b = (const float*)d_in[37];
    const float* bn3g = (const float*)d_in[38];
    const float* bn3b = (const float*)d_in[39];
    const float* hg = (const float*)d_in[40];
    const float* hb = (const float*)d_in[41];
    const float* lw = (const float*)d_in[42];
    const float* lb = (const float*)d_in[43];

    float* ws = (float*)d_ws;
    size_t off = 0;
    auto alloc = [&](size_t n){ float* p = ws + off; off += n; return p; };
    float* bufA    = alloc(432000);
    float* bufB    = alloc(432000);
    float* scratch = alloc(1944000);   // branch1 only: t_raw(3) + o_raw(3)
    float* b2ws    = alloc(650000);    // branch2 DEDICATED region
    float* feat1   = alloc(64 * 30);
    float* feat2   = alloc(64 * 16);
    float* stats   = alloc(28000);     // spread-slot stats (see layout below)

    float* t_raw = scratch;            // 3 x 216000
    float* o_raw = scratch + 648000;   // 3 x 432000

    // stats layout:
    //   [0, 8640)   branch1 t-stats: bi*2880 + ii*960; per ii: sums j*32+slot,
    //               sumsq 480 + j*32+slot (j<15, 32 slots)
    //   [8640,25920) branch1 o-stats: 8640 + bi*5760 + ii*1920; per ii:
    //               sums (g*15+cc)*32+slot, sumsq 960 + same (30 ch, 32 slots)
    //   [25920,...)  branch2 stats (single-slot, low contention)
    float* b1t = stats;
    float* b1o = stats + 8640;
    float* s_tloc = stats + 25920;
    float* s_tglb = s_tloc + 204;
    float* s_t3   = s_tglb + 204;
    float* s_o3   = s_t3 + 204;
    float* s_t4   = s_o3 + 408;
    float* s_o6   = s_t4 + 102;
    float* s_t5   = s_o6 + 204;
    float* s_o9   = s_t5 + 50;

    // branch2 buffers inside b2ws
    float* t_loc = b2ws;               // 58752
    float* t_glb = t_loc + 58752;      // 58752
    float* o_idn = t_glb + 58752;      // 117504
    float* t3    = o_idn + 117504;     // 58752
    float* o3    = t3 + 58752;         // 117504
    float* o5    = o3 + 117504;        // 58752
    float* t4    = o5 + 58752;         // 29376
    float* o6    = t4 + 29376;         // 58752
    float* o8    = o6 + 58752;         // 29376
    float* t5    = o8 + 29376;         // 14400
    float* o9    = t5 + 14400;         // 29376
    float* o11   = o9 + 29376;         // 9216

    hipMemsetAsync(stats, 0, 27400 * sizeof(float), stream);

    // L1: conv_m3(b0) || conv_dual
    step_conv_convdual<<<dim3(460, 1, 4), 256, 0, stream>>>(
        x, blk_w1, t_raw, b1t, y, loc_w1, glb_w1, t_loc, t_glb, s_tloc, s_tglb);
    // L2a: merged invol (b0)
    invol_b1m<<<dim3(64, 2, 3), 256, 0, stream>>>(
        x, t_raw, b1t, blk_ig, blk_ib, blk_w2_5, blk_w2_7, blk_w2_9,
        o_raw, b1o);
    // L2b: crossatt
    crossatt_g<<<459, 256, 0, stream>>>(
        y, t_loc, t_glb, s_tloc, s_tglb, loc_g, loc_b, glb_g, glb_b,
        loc_w2, glb_w2, o_idn);
    // L3: blockend_m3(b0: x->bufA) || conv(c3)
    step_be_conv<<<dim3(563, 1, 2), 256, 0, stream>>>(
        o_raw, o_raw + 432000, o_raw + 864000,
        b1o, b1o + 1920, b1o + 3840,
        blk_g, blk_b, blk_conv, x, bufA,
        o_idn, c3_w1, t3, s_t3, 204, 102, 230);
    // L4: conv_m3(b1) || invol3(c3)
    step_conv_inv3<<<dim3(459, 1, 4), 256, 0, stream>>>(
        bufA, blk_w1 + 1350, t_raw, b1t + 2880,
        o_idn, t3, s_t3, c3_g, c3_b, c3_w2, o3, s_o3, 204, 102, 459);
    // L5a: merged invol (b1)
    invol_b1m<<<dim3(64, 2, 3), 256, 0, stream>>>(
        bufA, t_raw, b1t + 2880, blk_ig + 45, blk_ib + 45,
        blk_w2_5 + 750, blk_w2_7 + 1470, blk_w2_9 + 2430,
        o_raw, b1o + 5760);
    // L5b: bnconv(c3)
    bnconv_g<<<230, 256, 0, stream>>>(o3, s_o3, bn1g, bn1b, o_idn, p1, o5, 204, 102);
    // L6: blockend_m3(b1: bufA->bufB) || conv(c4)
    step_be_conv<<<dim3(563, 1, 2), 256, 0, stream>>>(
        o_raw, o_raw + 432000, o_raw + 864000,
        b1o + 5760, b1o + 7680, b1o + 9600,
        blk_g + 90, blk_b + 90, blk_conv + 2700, bufA, bufB,
        o5, c4_w1, t4, s_t4, 102, 51, 115);
    // L7: conv_m3(b2) || invol3(c4)
    step_conv_inv3<<<dim3(282, 1, 4), 256, 0, stream>>>(
        bufB, blk_w1 + 2700, t_raw, b1t + 5760,
        o5, t4, s_t4, c4_g, c4_b, c4_w2, o6, s_o6, 102, 51, 230);
    // L8a: merged invol (b2)
    invol_b1m<<<dim3(64, 2, 3), 256, 0, stream>>>(
        bufB, t_raw, b1t + 5760, blk_ig + 90, blk_ib + 90,
        blk_w2_5 + 1500, blk_w2_7 + 2940, blk_w2_9 + 4860,
        o_raw, b1o + 11520);
    // L8b: bnconv(c4)
    bnconv_g<<<115, 256, 0, stream>>>(o6, s_o6, bn2g, bn2b, nullptr, p2, o8, 102, 51);
    // L9: blockend_m3(b2: bufB->bufA) || conv(c5)
    step_be_conv<<<dim3(563, 1, 2), 256, 0, stream>>>(
        o_raw, o_raw + 432000, o_raw + 864000,
        b1o + 11520, b1o + 13440, b1o + 15360,
        blk_g + 180, blk_b + 180, blk_conv + 5400, bufB, bufA,
        o8, c5_w1, t5, s_t5, 51, 25, 57);
    // L10: covpool1(bufA) || invol3(c5)
    step_cov_inv3<<<dim3(115, 1, 2), 256, 0, stream>>>(
        bufA, feat1,
        o8, t5, s_t5, c5_g, c5_b, c5_w2, o9, s_o9, 51, 25, 115);
    // L11: bnconv(c5)
    bnconv_g<<<36, 256, 0, stream>>>(o9, s_o9, bn3g, bn3b, o8, p3, o11, 51, 16);
    // L12: covpool2
    covpool_g<16, 9, 256><<<64, 256, 0, stream>>>(o11, feat2);
    // L13: head
    head_k<<<1, 256, 0, stream>>>(feat1, feat2, hg, hb, lw, lb, (float*)d_out);
}